// Round 1
// baseline (1370.300 us; speedup 1.0000x reference)
//
#include <hip/hip_runtime.h>

#define N_NODES 50000
#define N_EDGES 800000
#define N_GRAPHS 2000
#define BN_EPS 1e-5f

// ---------------------------------------------------------------- degree
__global__ void deg_kernel(const int* __restrict__ dst, float* __restrict__ deg) {
  for (int e = blockIdx.x * blockDim.x + threadIdx.x; e < N_EDGES;
       e += gridDim.x * blockDim.x)
    atomicAdd(&deg[dst[e]], 1.0f);
}

__global__ void invdeg_kernel(float* __restrict__ deg) {
  int n = blockIdx.x * blockDim.x + threadIdx.x;
  if (n < N_NODES) deg[n] = 1.0f / fmaxf(deg[n], 1.0f);
}

// ---------------------------------------------------------------- scatter-add
// one thread per (edge, feature); consecutive threads cover consecutive
// features of one edge -> coalesced gather reads + coalesced atomics.
template <int K>
__global__ void scatter_add_kernel(const float* __restrict__ X,
                                   const int* __restrict__ src,
                                   const int* __restrict__ dst,
                                   float* __restrict__ agg) {
  const unsigned total = (unsigned)N_EDGES * K;
  for (unsigned idx = blockIdx.x * blockDim.x + threadIdx.x; idx < total;
       idx += gridDim.x * blockDim.x) {
    unsigned e = idx / K;
    unsigned f = idx - e * K;
    atomicAdd(&agg[(unsigned)dst[e] * K + f], X[(unsigned)src[e] * K + f]);
  }
}

// ---------------------------------------------------------------- fused GEMM
// out[row, 0:128] = (agg[row]*invdeg[row]) @ Wl + X[row] @ Wr
// (conv bias omitted: uniform shift is cancelled by the following BN)
// 32 rows/block in LDS (stride 2K+1 to break bank aliasing), 256 threads,
// each thread computes a 4-row x 4-col register tile; W read as float4
// from global (identical addresses across blocks -> L2-hot).
template <int K>
__global__ __launch_bounds__(256) void sage_gemm_kernel(
    const float* __restrict__ agg, const float* __restrict__ invdeg,
    const float* __restrict__ X, const float* __restrict__ Wl,
    const float* __restrict__ Wr, float* __restrict__ out) {
  constexpr int LDA = 2 * K + 1;
  __shared__ float sA[32 * LDA];
  const int tid = threadIdx.x;
  const int row0 = blockIdx.x * 32;

  for (int idx = tid; idx < 32 * K; idx += 256) {
    int r = idx / K;
    int k = idx - r * K;
    int row = row0 + r;
    float a = 0.f, xv = 0.f;
    if (row < N_NODES) {
      a  = agg[row * K + k] * invdeg[row];
      xv = X[row * K + k];
    }
    sA[r * LDA + k]     = a;
    sA[r * LDA + K + k] = xv;
  }
  __syncthreads();

  const int colg = tid & 31;   // 32 col-groups of 4 cols
  const int rowg = tid >> 5;   // 8 row-groups of 4 rows
  const int col = colg * 4;
  float acc[4][4];
#pragma unroll
  for (int j = 0; j < 4; j++)
#pragma unroll
    for (int c = 0; c < 4; c++) acc[j][c] = 0.f;

  for (int k = 0; k < K; k++) {
    float4 w = *(const float4*)(Wl + k * 128 + col);
#pragma unroll
    for (int j = 0; j < 4; j++) {
      float a = sA[(rowg * 4 + j) * LDA + k];
      acc[j][0] += a * w.x; acc[j][1] += a * w.y;
      acc[j][2] += a * w.z; acc[j][3] += a * w.w;
    }
  }
  for (int k = 0; k < K; k++) {
    float4 w = *(const float4*)(Wr + k * 128 + col);
#pragma unroll
    for (int j = 0; j < 4; j++) {
      float a = sA[(rowg * 4 + j) * LDA + K + k];
      acc[j][0] += a * w.x; acc[j][1] += a * w.y;
      acc[j][2] += a * w.z; acc[j][3] += a * w.w;
    }
  }

#pragma unroll
  for (int j = 0; j < 4; j++) {
    int row = row0 + rowg * 4 + j;
    if (row < N_NODES) {
      float4 v = make_float4(acc[j][0], acc[j][1], acc[j][2], acc[j][3]);
      *(float4*)(out + row * 128 + col) = v;
    }
  }
}

// ---------------------------------------------------------------- batchnorm
__global__ void bn_stats_kernel(const float* __restrict__ h,
                                float* __restrict__ stats /* sum[128], sumsq[128] */) {
  const int col = threadIdx.x & 127;
  const int half = threadIdx.x >> 7;  // 0..1
  float s = 0.f, ss = 0.f;
  for (int row = blockIdx.x * 2 + half; row < N_NODES; row += gridDim.x * 2) {
    float v = h[row * 128 + col];
    s += v;
    ss += v * v;
  }
  __shared__ float rs[256], rss[256];
  rs[threadIdx.x] = s;
  rss[threadIdx.x] = ss;
  __syncthreads();
  if (half == 0) {
    s += rs[col + 128];
    ss += rss[col + 128];
    atomicAdd(&stats[col], s);
    atomicAdd(&stats[128 + col], ss);
  }
}

__global__ void bn_finalize_kernel(const float* __restrict__ stats,
                                   const float* __restrict__ gamma,
                                   const float* __restrict__ beta,
                                   float* __restrict__ sc /* scale[128], shift[128] */) {
  int c = threadIdx.x;
  const float invN = 1.0f / (float)N_NODES;
  float mean = stats[c] * invN;
  float var = stats[128 + c] * invN - mean * mean;
  float scale = gamma[c] * rsqrtf(var + BN_EPS);
  sc[c] = scale;
  sc[128 + c] = beta[c] - mean * scale;
}

__global__ void bn_apply_kernel(float* __restrict__ h,
                                const float* __restrict__ sc) {
  const int total4 = N_NODES * 32;  // float4 count
  for (int idx = blockIdx.x * blockDim.x + threadIdx.x; idx < total4;
       idx += gridDim.x * blockDim.x) {
    int c4 = idx & 31;
    float4 v = ((float4*)h)[idx];
    float4 s = ((const float4*)sc)[c4];
    float4 b = ((const float4*)sc)[32 + c4];
    v.x = fmaxf(v.x * s.x + b.x, 0.f);
    v.y = fmaxf(v.y * s.y + b.y, 0.f);
    v.z = fmaxf(v.z * s.z + b.z, 0.f);
    v.w = fmaxf(v.w * s.w + b.w, 0.f);
    ((float4*)h)[idx] = v;
  }
}

// ---------------------------------------------------------------- pooling
__global__ void pool_cnt_kernel(const int* __restrict__ batch,
                                float* __restrict__ cnt) {
  int n = blockIdx.x * blockDim.x + threadIdx.x;
  if (n < N_NODES) atomicAdd(&cnt[batch[n]], 1.0f);
}

__global__ void pool_sum_kernel(const float* __restrict__ h,
                                const int* __restrict__ batch,
                                float* __restrict__ pool) {
  const unsigned total = (unsigned)N_NODES * 128;
  for (unsigned idx = blockIdx.x * blockDim.x + threadIdx.x; idx < total;
       idx += gridDim.x * blockDim.x) {
    unsigned n = idx >> 7;
    unsigned c = idx & 127;
    atomicAdd(&pool[(unsigned)batch[n] * 128 + c], h[idx]);
  }
}

// ---------------------------------------------------------------- readout
// one wave per graph: thread j owns hidden unit j (0..63)
__global__ void readout_kernel(const float* __restrict__ pool,
                               const float* __restrict__ cnt,
                               const float* __restrict__ rW1,
                               const float* __restrict__ rb1,
                               const float* __restrict__ rW2,
                               const float* __restrict__ rb2,
                               float* __restrict__ out) {
  int g = blockIdx.x;
  int j = threadIdx.x;  // 0..63
  float invc = 1.0f / fmaxf(cnt[g], 1.0f);
  float acc = rb1[j];
  for (int k = 0; k < 128; k++)
    acc += pool[g * 128 + k] * invc * rW1[k * 64 + j];
  acc = fmaxf(acc, 0.f) * rW2[j];
#pragma unroll
  for (int off = 32; off > 0; off >>= 1) acc += __shfl_down(acc, off);
  if (j == 0) out[g] = acc + rb2[0];
}

// ---------------------------------------------------------------- launch
extern "C" void kernel_launch(void* const* d_in, const int* in_sizes, int n_in,
                              void* d_out, int out_size, void* d_ws, size_t ws_size,
                              hipStream_t stream) {
  const float* x     = (const float*)d_in[0];
  const int*   ei    = (const int*)d_in[1];
  const int*   src   = ei;
  const int*   dst   = ei + N_EDGES;
  const int*   batch = (const int*)d_in[2];
  const float* Wl0   = (const float*)d_in[3];
  const float* Wr0   = (const float*)d_in[4];
  // d_in[5] = b0 (unused: cancelled by BN), d_in[8] = b (unused)
  const float* Wl    = (const float*)d_in[6];
  const float* Wr    = (const float*)d_in[7];
  const float* gamma = (const float*)d_in[9];
  const float* beta  = (const float*)d_in[10];
  const float* rW1   = (const float*)d_in[11];
  const float* rb1   = (const float*)d_in[12];
  const float* rW2   = (const float*)d_in[13];
  const float* rb2   = (const float*)d_in[14];
  float* out = (float*)d_out;

  char* ws = (char*)d_ws;
  size_t off = 0;
  auto alloc = [&](size_t bytes) -> void* {
    void* p = ws + off;
    off = (off + bytes + 255) & ~(size_t)255;
    return p;
  };
  float* hA    = (float*)alloc((size_t)N_NODES * 128 * 4);
  float* hB    = (float*)alloc((size_t)N_NODES * 128 * 4);
  float* agg   = (float*)alloc((size_t)N_NODES * 128 * 4);
  float* deg   = (float*)alloc((size_t)N_NODES * 4);
  float* stats = (float*)alloc(256 * 4);
  float* sc    = (float*)alloc(256 * 4);
  float* pool  = (float*)alloc((size_t)N_GRAPHS * 128 * 4);
  float* cnt   = (float*)alloc((size_t)N_GRAPHS * 4);

  const int gemm_blocks = (N_NODES + 31) / 32;

  // degree (shared across layers)
  hipMemsetAsync(deg, 0, (size_t)N_NODES * 4, stream);
  deg_kernel<<<1024, 256, 0, stream>>>(dst, deg);
  invdeg_kernel<<<(N_NODES + 255) / 256, 256, 0, stream>>>(deg);

  // ---- layer 0 (K=38)
  hipMemsetAsync(agg, 0, (size_t)N_NODES * 38 * 4, stream);
  scatter_add_kernel<38><<<4096, 256, 0, stream>>>(x, src, dst, agg);
  sage_gemm_kernel<38><<<gemm_blocks, 256, 0, stream>>>(agg, deg, x, Wl0, Wr0, hA);
  hipMemsetAsync(stats, 0, 256 * 4, stream);
  bn_stats_kernel<<<256, 256, 0, stream>>>(hA, stats);
  bn_finalize_kernel<<<1, 128, 0, stream>>>(stats, gamma, beta, sc);
  bn_apply_kernel<<<4096, 256, 0, stream>>>(hA, sc);

  // ---- layers 1..2 (K=128)
  float* cur = hA;
  float* nxt = hB;
  for (int l = 0; l < 2; l++) {
    hipMemsetAsync(agg, 0, (size_t)N_NODES * 128 * 4, stream);
    scatter_add_kernel<128><<<8192, 256, 0, stream>>>(cur, src, dst, agg);
    sage_gemm_kernel<128><<<gemm_blocks, 256, 0, stream>>>(
        agg, deg, cur, Wl + l * 128 * 128, Wr + l * 128 * 128, nxt);
    hipMemsetAsync(stats, 0, 256 * 4, stream);
    bn_stats_kernel<<<256, 256, 0, stream>>>(nxt, stats);
    bn_finalize_kernel<<<1, 128, 0, stream>>>(stats, gamma + (l + 1) * 128,
                                              beta + (l + 1) * 128, sc);
    bn_apply_kernel<<<4096, 256, 0, stream>>>(nxt, sc);
    float* t = cur; cur = nxt; nxt = t;
  }

  // ---- global mean pool + readout
  hipMemsetAsync(pool, 0, (size_t)N_GRAPHS * 128 * 4, stream);
  hipMemsetAsync(cnt, 0, (size_t)N_GRAPHS * 4, stream);
  pool_cnt_kernel<<<(N_NODES + 255) / 256, 256, 0, stream>>>(batch, cnt);
  pool_sum_kernel<<<4096, 256, 0, stream>>>(cur, batch, pool);
  readout_kernel<<<N_GRAPHS, 64, 0, stream>>>(pool, cnt, rW1, rb1, rW2, rb2, out);
}

// Round 2
// 740.351 us; speedup vs baseline: 1.8509x; 1.8509x over previous
//
#include <hip/hip_runtime.h>

#define N_NODES 50000
#define N_EDGES 800000
#define N_GRAPHS 2000
#define BN_EPS 1e-5f

// ================================================================ CSR build
__global__ void hist_kernel(const int* __restrict__ dst, int* __restrict__ degi) {
  for (int e = blockIdx.x * blockDim.x + threadIdx.x; e < N_EDGES;
       e += gridDim.x * blockDim.x)
    atomicAdd(&degi[dst[e]], 1);
}

__global__ void invdeg_kernel(const int* __restrict__ degi, float* __restrict__ invdeg) {
  int n = blockIdx.x * blockDim.x + threadIdx.x;
  if (n < N_NODES) invdeg[n] = 1.0f / fmaxf((float)degi[n], 1.0f);
}

// exclusive scan, two-level (256-chunks)
__global__ void scan_block_kernel(const int* __restrict__ degi,
                                  int* __restrict__ partial,
                                  int* __restrict__ bsum) {
  __shared__ int buf[2][256];
  int i = blockIdx.x * 256 + threadIdx.x;
  int v = (i < N_NODES) ? degi[i] : 0;
  buf[0][threadIdx.x] = v;
  __syncthreads();
  int pi = 0;
  for (int off = 1; off < 256; off <<= 1) {
    int nv = buf[pi][threadIdx.x];
    if (threadIdx.x >= off) nv += buf[pi][threadIdx.x - off];
    buf[pi ^ 1][threadIdx.x] = nv;
    pi ^= 1;
    __syncthreads();
  }
  int incl = buf[pi][threadIdx.x];
  if (i < N_NODES) partial[i] = incl - v;  // exclusive within block
  if (threadIdx.x == 255) bsum[blockIdx.x] = incl;
}

__global__ void scan_bsum_kernel(int* __restrict__ bsum, int nb) {
  __shared__ int buf[2][256];
  int v = (threadIdx.x < nb) ? bsum[threadIdx.x] : 0;
  buf[0][threadIdx.x] = v;
  __syncthreads();
  int pi = 0;
  for (int off = 1; off < 256; off <<= 1) {
    int nv = buf[pi][threadIdx.x];
    if (threadIdx.x >= off) nv += buf[pi][threadIdx.x - off];
    buf[pi ^ 1][threadIdx.x] = nv;
    pi ^= 1;
    __syncthreads();
  }
  int incl = buf[pi][threadIdx.x];
  if (threadIdx.x < nb) bsum[threadIdx.x] = incl - v;  // exclusive
}

__global__ void scan_add_kernel(const int* __restrict__ partial,
                                const int* __restrict__ bsum,
                                int* __restrict__ rowptr,
                                int* __restrict__ cursor) {
  int i = blockIdx.x * 256 + threadIdx.x;
  if (i < N_NODES) {
    int r = partial[i] + bsum[blockIdx.x];
    rowptr[i] = r;
    cursor[i] = r;
  } else if (i == N_NODES) {
    rowptr[N_NODES] = N_EDGES;
  }
}

__global__ void fill_kernel(const int* __restrict__ src,
                            const int* __restrict__ dst,
                            int* __restrict__ cursor,
                            int* __restrict__ col) {
  for (int e = blockIdx.x * blockDim.x + threadIdx.x; e < N_EDGES;
       e += gridDim.x * blockDim.x) {
    int p = atomicAdd(&cursor[dst[e]], 1);
    col[p] = src[e];
  }
}

// ================================================================ aggregate
// one wave per node; lanes own 2 features (float2): gather-sum in-neighbors.
__global__ __launch_bounds__(256) void csr_aggregate_128(
    const float* __restrict__ X, const int* __restrict__ rowptr,
    const int* __restrict__ col, const float* __restrict__ invdeg,
    float* __restrict__ agg) {
  int node = blockIdx.x * 4 + (threadIdx.x >> 6);
  if (node >= N_NODES) return;
  int lane = threadIdx.x & 63;
  int beg = rowptr[node], end = rowptr[node + 1];
  float2 acc = make_float2(0.f, 0.f);
  int e = beg;
  for (; e + 1 < end; e += 2) {
    int s0 = col[e], s1 = col[e + 1];
    float2 v0 = *(const float2*)(X + (size_t)s0 * 128 + lane * 2);
    float2 v1 = *(const float2*)(X + (size_t)s1 * 128 + lane * 2);
    acc.x += v0.x + v1.x;
    acc.y += v0.y + v1.y;
  }
  if (e < end) {
    float2 v = *(const float2*)(X + (size_t)col[e] * 128 + lane * 2);
    acc.x += v.x;
    acc.y += v.y;
  }
  float inv = invdeg[node];
  acc.x *= inv;
  acc.y *= inv;
  *(float2*)(agg + (size_t)node * 128 + lane * 2) = acc;
}

// K=38: lanes 0..37 own one feature each.
__global__ __launch_bounds__(256) void csr_aggregate_38(
    const float* __restrict__ X, const int* __restrict__ rowptr,
    const int* __restrict__ col, const float* __restrict__ invdeg,
    float* __restrict__ agg) {
  int node = blockIdx.x * 4 + (threadIdx.x >> 6);
  if (node >= N_NODES) return;
  int lane = threadIdx.x & 63;
  int beg = rowptr[node], end = rowptr[node + 1];
  float acc = 0.f;
  if (lane < 38) {
    int e = beg;
    for (; e + 1 < end; e += 2) {
      acc += X[(size_t)col[e] * 38 + lane] + X[(size_t)col[e + 1] * 38 + lane];
    }
    if (e < end) acc += X[(size_t)col[e] * 38 + lane];
    agg[(size_t)node * 38 + lane] = acc * invdeg[node];
  }
}

// ================================================================ fused GEMM
// out[row, 0:128] = agg[row] @ Wl + X[row] @ Wr   (agg pre-scaled by invdeg;
// conv bias omitted: uniform shift is cancelled by the following BN)
template <int K>
__global__ __launch_bounds__(256) void sage_gemm_kernel(
    const float* __restrict__ agg, const float* __restrict__ X,
    const float* __restrict__ Wl, const float* __restrict__ Wr,
    float* __restrict__ out) {
  constexpr int LDA = 2 * K + 1;
  __shared__ float sA[32 * LDA];
  const int tid = threadIdx.x;
  const int row0 = blockIdx.x * 32;

  for (int idx = tid; idx < 32 * K; idx += 256) {
    int r = idx / K;
    int k = idx - r * K;
    int row = row0 + r;
    float a = 0.f, xv = 0.f;
    if (row < N_NODES) {
      a  = agg[(size_t)row * K + k];
      xv = X[(size_t)row * K + k];
    }
    sA[r * LDA + k]     = a;
    sA[r * LDA + K + k] = xv;
  }
  __syncthreads();

  const int colg = tid & 31;
  const int rowg = tid >> 5;
  const int col = colg * 4;
  float acc[4][4];
#pragma unroll
  for (int j = 0; j < 4; j++)
#pragma unroll
    for (int c = 0; c < 4; c++) acc[j][c] = 0.f;

  for (int k = 0; k < K; k++) {
    float4 w = *(const float4*)(Wl + k * 128 + col);
#pragma unroll
    for (int j = 0; j < 4; j++) {
      float a = sA[(rowg * 4 + j) * LDA + k];
      acc[j][0] += a * w.x; acc[j][1] += a * w.y;
      acc[j][2] += a * w.z; acc[j][3] += a * w.w;
    }
  }
  for (int k = 0; k < K; k++) {
    float4 w = *(const float4*)(Wr + k * 128 + col);
#pragma unroll
    for (int j = 0; j < 4; j++) {
      float a = sA[(rowg * 4 + j) * LDA + K + k];
      acc[j][0] += a * w.x; acc[j][1] += a * w.y;
      acc[j][2] += a * w.z; acc[j][3] += a * w.w;
    }
  }

#pragma unroll
  for (int j = 0; j < 4; j++) {
    int row = row0 + rowg * 4 + j;
    if (row < N_NODES) {
      float4 v = make_float4(acc[j][0], acc[j][1], acc[j][2], acc[j][3]);
      *(float4*)(out + (size_t)row * 128 + col) = v;
    }
  }
}

// ================================================================ batchnorm
__global__ void bn_stats_kernel(const float* __restrict__ h,
                                float* __restrict__ stats) {
  const int col = threadIdx.x & 127;
  const int half = threadIdx.x >> 7;
  float s = 0.f, ss = 0.f;
  for (int row = blockIdx.x * 2 + half; row < N_NODES; row += gridDim.x * 2) {
    float v = h[(size_t)row * 128 + col];
    s += v;
    ss += v * v;
  }
  __shared__ float rs[256], rss[256];
  rs[threadIdx.x] = s;
  rss[threadIdx.x] = ss;
  __syncthreads();
  if (half == 0) {
    s += rs[col + 128];
    ss += rss[col + 128];
    atomicAdd(&stats[col], s);
    atomicAdd(&stats[128 + col], ss);
  }
}

__global__ void bn_finalize_kernel(const float* __restrict__ stats,
                                   const float* __restrict__ gamma,
                                   const float* __restrict__ beta,
                                   float* __restrict__ sc) {
  int c = threadIdx.x;
  const float invN = 1.0f / (float)N_NODES;
  float mean = stats[c] * invN;
  float var = stats[128 + c] * invN - mean * mean;
  float scale = gamma[c] * rsqrtf(var + BN_EPS);
  sc[c] = scale;
  sc[128 + c] = beta[c] - mean * scale;
}

__global__ void bn_apply_kernel(float* __restrict__ h,
                                const float* __restrict__ sc) {
  const int total4 = N_NODES * 32;
  for (int idx = blockIdx.x * blockDim.x + threadIdx.x; idx < total4;
       idx += gridDim.x * blockDim.x) {
    int c4 = idx & 31;
    float4 v = ((float4*)h)[idx];
    float4 s = ((const float4*)sc)[c4];
    float4 b = ((const float4*)sc)[32 + c4];
    v.x = fmaxf(v.x * s.x + b.x, 0.f);
    v.y = fmaxf(v.y * s.y + b.y, 0.f);
    v.z = fmaxf(v.z * s.z + b.z, 0.f);
    v.w = fmaxf(v.w * s.w + b.w, 0.f);
    ((float4*)h)[idx] = v;
  }
}

// ================================================================ pooling
__global__ void pool_cnt_kernel(const int* __restrict__ batch,
                                float* __restrict__ cnt) {
  int n = blockIdx.x * blockDim.x + threadIdx.x;
  if (n < N_NODES) atomicAdd(&cnt[batch[n]], 1.0f);
}

// batch is sorted: accumulate runs per thread, atomic only at graph change.
__global__ void pool_sum_kernel(const float* __restrict__ h,
                                const int* __restrict__ batch,
                                float* __restrict__ pool) {
  const int ROWS = 64;
  int c = threadIdx.x & 127;
  int half = threadIdx.x >> 7;
  int r0 = blockIdx.x * ROWS;
  int rend = min(r0 + ROWS, N_NODES);
  float acc = 0.f;
  int curg = -1;
  for (int r = r0 + half; r < rend; r += 2) {
    int g = batch[r];
    if (g != curg) {
      if (curg >= 0) atomicAdd(&pool[(size_t)curg * 128 + c], acc);
      acc = 0.f;
      curg = g;
    }
    acc += h[(size_t)r * 128 + c];
  }
  if (curg >= 0) atomicAdd(&pool[(size_t)curg * 128 + c], acc);
}

// ================================================================ readout
__global__ void readout_kernel(const float* __restrict__ pool,
                               const float* __restrict__ cnt,
                               const float* __restrict__ rW1,
                               const float* __restrict__ rb1,
                               const float* __restrict__ rW2,
                               const float* __restrict__ rb2,
                               float* __restrict__ out) {
  int g = blockIdx.x;
  int j = threadIdx.x;  // 0..63
  float invc = 1.0f / fmaxf(cnt[g], 1.0f);
  float acc = rb1[j];
  for (int k = 0; k < 128; k++)
    acc += pool[(size_t)g * 128 + k] * invc * rW1[k * 64 + j];
  acc = fmaxf(acc, 0.f) * rW2[j];
#pragma unroll
  for (int off = 32; off > 0; off >>= 1) acc += __shfl_down(acc, off);
  if (j == 0) out[g] = acc + rb2[0];
}

// ================================================================ launch
extern "C" void kernel_launch(void* const* d_in, const int* in_sizes, int n_in,
                              void* d_out, int out_size, void* d_ws, size_t ws_size,
                              hipStream_t stream) {
  const float* x     = (const float*)d_in[0];
  const int*   ei    = (const int*)d_in[1];
  const int*   src   = ei;
  const int*   dst   = ei + N_EDGES;
  const int*   batch = (const int*)d_in[2];
  const float* Wl0   = (const float*)d_in[3];
  const float* Wr0   = (const float*)d_in[4];
  const float* Wl    = (const float*)d_in[6];
  const float* Wr    = (const float*)d_in[7];
  const float* gamma = (const float*)d_in[9];
  const float* beta  = (const float*)d_in[10];
  const float* rW1   = (const float*)d_in[11];
  const float* rb1   = (const float*)d_in[12];
  const float* rW2   = (const float*)d_in[13];
  const float* rb2   = (const float*)d_in[14];
  float* out = (float*)d_out;

  char* ws = (char*)d_ws;
  size_t off = 0;
  auto alloc = [&](size_t bytes) -> void* {
    void* p = ws + off;
    off = (off + bytes + 255) & ~(size_t)255;
    return p;
  };
  float* hA     = (float*)alloc((size_t)N_NODES * 128 * 4);
  float* hB     = (float*)alloc((size_t)N_NODES * 128 * 4);
  float* agg    = (float*)alloc((size_t)N_NODES * 128 * 4);
  float* invdeg = (float*)alloc((size_t)N_NODES * 4);
  int*   degi   = (int*)alloc((size_t)N_NODES * 4);
  int*   rowptr = (int*)alloc((size_t)(N_NODES + 1) * 4);
  int*   cursor = (int*)alloc((size_t)N_NODES * 4);
  int*   colidx = (int*)alloc((size_t)N_EDGES * 4);
  int*   partial= (int*)alloc((size_t)N_NODES * 4);
  int*   bsum   = (int*)alloc(256 * 4);
  float* stats  = (float*)alloc(256 * 4);
  float* sc     = (float*)alloc(256 * 4);
  float* pool   = (float*)alloc((size_t)N_GRAPHS * 128 * 4);
  float* cnt    = (float*)alloc((size_t)N_GRAPHS * 4);

  const int NB_SCAN = (N_NODES + 255) / 256;  // 196
  const int gemm_blocks = (N_NODES + 31) / 32;
  const int agg_blocks = (N_NODES + 3) / 4;

  // ---- CSR build (once, reused by all 3 layers)
  hipMemsetAsync(degi, 0, (size_t)N_NODES * 4, stream);
  hist_kernel<<<1024, 256, 0, stream>>>(dst, degi);
  invdeg_kernel<<<NB_SCAN, 256, 0, stream>>>(degi, invdeg);
  scan_block_kernel<<<NB_SCAN, 256, 0, stream>>>(degi, partial, bsum);
  scan_bsum_kernel<<<1, 256, 0, stream>>>(bsum, NB_SCAN);
  scan_add_kernel<<<NB_SCAN + 1, 256, 0, stream>>>(partial, bsum, rowptr, cursor);
  fill_kernel<<<1024, 256, 0, stream>>>(src, dst, cursor, colidx);

  // ---- layer 0 (K=38)
  csr_aggregate_38<<<agg_blocks, 256, 0, stream>>>(x, rowptr, colidx, invdeg, agg);
  sage_gemm_kernel<38><<<gemm_blocks, 256, 0, stream>>>(agg, x, Wl0, Wr0, hA);
  hipMemsetAsync(stats, 0, 256 * 4, stream);
  bn_stats_kernel<<<256, 256, 0, stream>>>(hA, stats);
  bn_finalize_kernel<<<1, 128, 0, stream>>>(stats, gamma, beta, sc);
  bn_apply_kernel<<<4096, 256, 0, stream>>>(hA, sc);

  // ---- layers 1..2 (K=128)
  float* cur = hA;
  float* nxt = hB;
  for (int l = 0; l < 2; l++) {
    csr_aggregate_128<<<agg_blocks, 256, 0, stream>>>(cur, rowptr, colidx, invdeg, agg);
    sage_gemm_kernel<128><<<gemm_blocks, 256, 0, stream>>>(
        agg, cur, Wl + l * 128 * 128, Wr + l * 128 * 128, nxt);
    hipMemsetAsync(stats, 0, 256 * 4, stream);
    bn_stats_kernel<<<256, 256, 0, stream>>>(nxt, stats);
    bn_finalize_kernel<<<1, 128, 0, stream>>>(stats, gamma + (l + 1) * 128,
                                              beta + (l + 1) * 128, sc);
    bn_apply_kernel<<<4096, 256, 0, stream>>>(nxt, sc);
    float* t = cur; cur = nxt; nxt = t;
  }

  // ---- global mean pool + readout
  hipMemsetAsync(pool, 0, (size_t)N_GRAPHS * 128 * 4, stream);
  hipMemsetAsync(cnt, 0, (size_t)N_GRAPHS * 4, stream);
  pool_cnt_kernel<<<NB_SCAN, 256, 0, stream>>>(batch, cnt);
  pool_sum_kernel<<<(N_NODES + 63) / 64, 256, 0, stream>>>(cur, batch, pool);
  readout_kernel<<<N_GRAPHS, 64, 0, stream>>>(pool, cnt, rW1, rb1, rW2, rb2, out);
}

// Round 3
// 642.839 us; speedup vs baseline: 2.1316x; 1.1517x over previous
//
#include <hip/hip_runtime.h>

#define N_NODES 50000
#define N_EDGES 800000
#define N_GRAPHS 2000
#define BN_EPS 1e-5f

// ================================================================ CSR build
__global__ void hist_kernel(const int* __restrict__ dst, int* __restrict__ degi) {
  for (int e = blockIdx.x * blockDim.x + threadIdx.x; e < N_EDGES;
       e += gridDim.x * blockDim.x)
    atomicAdd(&degi[dst[e]], 1);
}

__global__ void invdeg_kernel(const int* __restrict__ degi, float* __restrict__ invdeg) {
  int n = blockIdx.x * blockDim.x + threadIdx.x;
  if (n < N_NODES) invdeg[n] = 1.0f / fmaxf((float)degi[n], 1.0f);
}

__global__ void scan_block_kernel(const int* __restrict__ degi,
                                  int* __restrict__ partial,
                                  int* __restrict__ bsum) {
  __shared__ int buf[2][256];
  int i = blockIdx.x * 256 + threadIdx.x;
  int v = (i < N_NODES) ? degi[i] : 0;
  buf[0][threadIdx.x] = v;
  __syncthreads();
  int pi = 0;
  for (int off = 1; off < 256; off <<= 1) {
    int nv = buf[pi][threadIdx.x];
    if (threadIdx.x >= off) nv += buf[pi][threadIdx.x - off];
    buf[pi ^ 1][threadIdx.x] = nv;
    pi ^= 1;
    __syncthreads();
  }
  int incl = buf[pi][threadIdx.x];
  if (i < N_NODES) partial[i] = incl - v;
  if (threadIdx.x == 255) bsum[blockIdx.x] = incl;
}

__global__ void scan_bsum_kernel(int* __restrict__ bsum, int nb) {
  __shared__ int buf[2][256];
  int v = (threadIdx.x < nb) ? bsum[threadIdx.x] : 0;
  buf[0][threadIdx.x] = v;
  __syncthreads();
  int pi = 0;
  for (int off = 1; off < 256; off <<= 1) {
    int nv = buf[pi][threadIdx.x];
    if (threadIdx.x >= off) nv += buf[pi][threadIdx.x - off];
    buf[pi ^ 1][threadIdx.x] = nv;
    pi ^= 1;
    __syncthreads();
  }
  int incl = buf[pi][threadIdx.x];
  if (threadIdx.x < nb) bsum[threadIdx.x] = incl - v;
}

__global__ void scan_add_kernel(const int* __restrict__ partial,
                                const int* __restrict__ bsum,
                                int* __restrict__ rowptr,
                                int* __restrict__ cursor) {
  int i = blockIdx.x * 256 + threadIdx.x;
  if (i < N_NODES) {
    int r = partial[i] + bsum[blockIdx.x];
    rowptr[i] = r;
    cursor[i] = r;
  } else if (i == N_NODES) {
    rowptr[N_NODES] = N_EDGES;
  }
}

__global__ void fill_kernel(const int* __restrict__ src,
                            const int* __restrict__ dst,
                            int* __restrict__ cursor,
                            int* __restrict__ col) {
  for (int e = blockIdx.x * blockDim.x + threadIdx.x; e < N_EDGES;
       e += gridDim.x * blockDim.x) {
    int p = atomicAdd(&cursor[dst[e]], 1);
    col[p] = src[e];
  }
}

// ================================================================ aggregate
// 2 nodes per wave; 32 lanes x float4 cover 128 features.
__global__ __launch_bounds__(256) void csr_aggregate_128(
    const float* __restrict__ X, const int* __restrict__ rowptr,
    const int* __restrict__ col, const float* __restrict__ invdeg,
    float* __restrict__ agg) {
  int node = blockIdx.x * 8 + (threadIdx.x >> 5);
  if (node >= N_NODES) return;
  int l = threadIdx.x & 31;
  int beg = rowptr[node], end = rowptr[node + 1];
  float4 acc = make_float4(0.f, 0.f, 0.f, 0.f);
  int e = beg;
  for (; e + 1 < end; e += 2) {
    int s0 = col[e], s1 = col[e + 1];
    float4 v0 = *(const float4*)(X + (size_t)s0 * 128 + l * 4);
    float4 v1 = *(const float4*)(X + (size_t)s1 * 128 + l * 4);
    acc.x += v0.x + v1.x; acc.y += v0.y + v1.y;
    acc.z += v0.z + v1.z; acc.w += v0.w + v1.w;
  }
  if (e < end) {
    float4 v = *(const float4*)(X + (size_t)col[e] * 128 + l * 4);
    acc.x += v.x; acc.y += v.y; acc.z += v.z; acc.w += v.w;
  }
  float inv = invdeg[node];
  acc.x *= inv; acc.y *= inv; acc.z *= inv; acc.w *= inv;
  *(float4*)(agg + (size_t)node * 128 + l * 4) = acc;
}

// K=38: lanes 0..37 own one feature each.
__global__ __launch_bounds__(256) void csr_aggregate_38(
    const float* __restrict__ X, const int* __restrict__ rowptr,
    const int* __restrict__ col, const float* __restrict__ invdeg,
    float* __restrict__ agg) {
  int node = blockIdx.x * 4 + (threadIdx.x >> 6);
  if (node >= N_NODES) return;
  int lane = threadIdx.x & 63;
  int beg = rowptr[node], end = rowptr[node + 1];
  float acc = 0.f;
  if (lane < 38) {
    int e = beg;
    for (; e + 1 < end; e += 2) {
      acc += X[(size_t)col[e] * 38 + lane] + X[(size_t)col[e + 1] * 38 + lane];
    }
    if (e < end) acc += X[(size_t)col[e] * 38 + lane];
    agg[(size_t)node * 38 + lane] = acc * invdeg[node];
  }
}

// ================================================================ fused GEMM + BN stats
// out[row, 0:128] = agg[row] @ Wl + X[row] @ Wr   (bias cancelled by BN)
// Epilogue block-reduces per-column sum/sumsq and atomically accumulates
// into stats[0:128] (sum) / stats[128:256] (sumsq).
template <int K>
__global__ __launch_bounds__(256, 4) void sage_gemm_kernel(
    const float* __restrict__ agg, const float* __restrict__ X,
    const float* __restrict__ Wl, const float* __restrict__ Wr,
    float* __restrict__ out, float* __restrict__ stats) {
  constexpr int LDA = 2 * K + 1;
  __shared__ float sA[32 * LDA];
  const int tid = threadIdx.x;
  const int row0 = blockIdx.x * 32;

  for (int idx = tid; idx < 32 * K; idx += 256) {
    int r = idx / K;
    int k = idx - r * K;
    int row = row0 + r;
    float a = 0.f, xv = 0.f;
    if (row < N_NODES) {
      a  = agg[(size_t)row * K + k];
      xv = X[(size_t)row * K + k];
    }
    sA[r * LDA + k]     = a;
    sA[r * LDA + K + k] = xv;
  }
  __syncthreads();

  const int colg = tid & 31;
  const int rowg = tid >> 5;
  const int col = colg * 4;
  float acc[4][4];
#pragma unroll
  for (int j = 0; j < 4; j++)
#pragma unroll
    for (int c = 0; c < 4; c++) acc[j][c] = 0.f;

#pragma unroll 4
  for (int k = 0; k < K; k++) {
    float4 w = *(const float4*)(Wl + k * 128 + col);
#pragma unroll
    for (int j = 0; j < 4; j++) {
      float a = sA[(rowg * 4 + j) * LDA + k];
      acc[j][0] += a * w.x; acc[j][1] += a * w.y;
      acc[j][2] += a * w.z; acc[j][3] += a * w.w;
    }
  }
#pragma unroll 4
  for (int k = 0; k < K; k++) {
    float4 w = *(const float4*)(Wr + k * 128 + col);
#pragma unroll
    for (int j = 0; j < 4; j++) {
      float a = sA[(rowg * 4 + j) * LDA + K + k];
      acc[j][0] += a * w.x; acc[j][1] += a * w.y;
      acc[j][2] += a * w.z; acc[j][3] += a * w.w;
    }
  }

#pragma unroll
  for (int j = 0; j < 4; j++) {
    int row = row0 + rowg * 4 + j;
    if (row < N_NODES) {
      float4 v = make_float4(acc[j][0], acc[j][1], acc[j][2], acc[j][3]);
      *(float4*)(out + (size_t)row * 128 + col) = v;
    }
  }

  // ---- BN stats epilogue (rows >= N_NODES contribute exact zeros)
  __syncthreads();  // done reading sA; reuse as reduction buffer [2][8][128]
  float* red = sA;
#pragma unroll
  for (int c = 0; c < 4; c++) {
    float s = 0.f, q = 0.f;
#pragma unroll
    for (int j = 0; j < 4; j++) {
      s += acc[j][c];
      q += acc[j][c] * acc[j][c];
    }
    red[rowg * 128 + col + c] = s;
    red[1024 + rowg * 128 + col + c] = q;
  }
  __syncthreads();
  if (tid < 128) {
    float s = 0.f, q = 0.f;
#pragma unroll
    for (int r = 0; r < 8; r++) {
      s += red[r * 128 + tid];
      q += red[1024 + r * 128 + tid];
    }
    atomicAdd(&stats[tid], s);
    atomicAdd(&stats[128 + tid], q);
  }
}

// ================================================================ batchnorm
__global__ void bn_finalize_kernel(const float* __restrict__ stats,
                                   const float* __restrict__ gamma,
                                   const float* __restrict__ beta,
                                   float* __restrict__ sc) {
  int c = threadIdx.x;
  const float invN = 1.0f / (float)N_NODES;
  float mean = stats[c] * invN;
  float var = stats[128 + c] * invN - mean * mean;
  float scale = gamma[c] * rsqrtf(var + BN_EPS);
  sc[c] = scale;
  sc[128 + c] = beta[c] - mean * scale;
}

__global__ void bn_apply_kernel(float* __restrict__ h,
                                const float* __restrict__ sc) {
  const int total4 = N_NODES * 32;
  for (int idx = blockIdx.x * blockDim.x + threadIdx.x; idx < total4;
       idx += gridDim.x * blockDim.x) {
    int c4 = idx & 31;
    float4 v = ((float4*)h)[idx];
    float4 s = ((const float4*)sc)[c4];
    float4 b = ((const float4*)sc)[32 + c4];
    v.x = fmaxf(v.x * s.x + b.x, 0.f);
    v.y = fmaxf(v.y * s.y + b.y, 0.f);
    v.z = fmaxf(v.z * s.z + b.z, 0.f);
    v.w = fmaxf(v.w * s.w + b.w, 0.f);
    ((float4*)h)[idx] = v;
  }
}

// ================================================================ pooling
__global__ void pool_cnt_kernel(const int* __restrict__ batch,
                                float* __restrict__ cnt) {
  int n = blockIdx.x * blockDim.x + threadIdx.x;
  if (n < N_NODES) atomicAdd(&cnt[batch[n]], 1.0f);
}

__global__ void pool_sum_kernel(const float* __restrict__ h,
                                const int* __restrict__ batch,
                                float* __restrict__ pool) {
  const int ROWS = 64;
  int c = threadIdx.x & 127;
  int half = threadIdx.x >> 7;
  int r0 = blockIdx.x * ROWS;
  int rend = min(r0 + ROWS, N_NODES);
  float acc = 0.f;
  int curg = -1;
  for (int r = r0 + half; r < rend; r += 2) {
    int g = batch[r];
    if (g != curg) {
      if (curg >= 0) atomicAdd(&pool[(size_t)curg * 128 + c], acc);
      acc = 0.f;
      curg = g;
    }
    acc += h[(size_t)r * 128 + c];
  }
  if (curg >= 0) atomicAdd(&pool[(size_t)curg * 128 + c], acc);
}

// ================================================================ readout
__global__ void readout_kernel(const float* __restrict__ pool,
                               const float* __restrict__ cnt,
                               const float* __restrict__ rW1,
                               const float* __restrict__ rb1,
                               const float* __restrict__ rW2,
                               const float* __restrict__ rb2,
                               float* __restrict__ out) {
  int g = blockIdx.x;
  int j = threadIdx.x;  // 0..63
  float invc = 1.0f / fmaxf(cnt[g], 1.0f);
  float acc = rb1[j];
  for (int k = 0; k < 128; k++)
    acc += pool[(size_t)g * 128 + k] * invc * rW1[k * 64 + j];
  acc = fmaxf(acc, 0.f) * rW2[j];
#pragma unroll
  for (int off = 32; off > 0; off >>= 1) acc += __shfl_down(acc, off);
  if (j == 0) out[g] = acc + rb2[0];
}

// ================================================================ launch
extern "C" void kernel_launch(void* const* d_in, const int* in_sizes, int n_in,
                              void* d_out, int out_size, void* d_ws, size_t ws_size,
                              hipStream_t stream) {
  const float* x     = (const float*)d_in[0];
  const int*   ei    = (const int*)d_in[1];
  const int*   src   = ei;
  const int*   dst   = ei + N_EDGES;
  const int*   batch = (const int*)d_in[2];
  const float* Wl0   = (const float*)d_in[3];
  const float* Wr0   = (const float*)d_in[4];
  const float* Wl    = (const float*)d_in[6];
  const float* Wr    = (const float*)d_in[7];
  const float* gamma = (const float*)d_in[9];
  const float* beta  = (const float*)d_in[10];
  const float* rW1   = (const float*)d_in[11];
  const float* rb1   = (const float*)d_in[12];
  const float* rW2   = (const float*)d_in[13];
  const float* rb2   = (const float*)d_in[14];
  float* out = (float*)d_out;

  char* ws = (char*)d_ws;
  size_t off = 0;
  auto alloc = [&](size_t bytes) -> void* {
    void* p = ws + off;
    off = (off + bytes + 255) & ~(size_t)255;
    return p;
  };
  float* hA     = (float*)alloc((size_t)N_NODES * 128 * 4);
  float* hB     = (float*)alloc((size_t)N_NODES * 128 * 4);
  float* agg    = (float*)alloc((size_t)N_NODES * 128 * 4);
  float* invdeg = (float*)alloc((size_t)N_NODES * 4);
  int*   degi   = (int*)alloc((size_t)N_NODES * 4);
  int*   rowptr = (int*)alloc((size_t)(N_NODES + 1) * 4);
  int*   cursor = (int*)alloc((size_t)N_NODES * 4);
  int*   colidx = (int*)alloc((size_t)N_EDGES * 4);
  int*   partial= (int*)alloc((size_t)N_NODES * 4);
  int*   bsum   = (int*)alloc(256 * 4);
  float* stats  = (float*)alloc(256 * 4);
  float* sc     = (float*)alloc(256 * 4);
  float* pool   = (float*)alloc((size_t)N_GRAPHS * 128 * 4);
  float* cnt    = (float*)alloc((size_t)N_GRAPHS * 4);

  const int NB_SCAN = (N_NODES + 255) / 256;
  const int gemm_blocks = (N_NODES + 31) / 32;

  // ---- CSR build (once, reused by all 3 layers)
  hipMemsetAsync(degi, 0, (size_t)N_NODES * 4, stream);
  hist_kernel<<<1024, 256, 0, stream>>>(dst, degi);
  invdeg_kernel<<<NB_SCAN, 256, 0, stream>>>(degi, invdeg);
  scan_block_kernel<<<NB_SCAN, 256, 0, stream>>>(degi, partial, bsum);
  scan_bsum_kernel<<<1, 256, 0, stream>>>(bsum, NB_SCAN);
  scan_add_kernel<<<NB_SCAN + 1, 256, 0, stream>>>(partial, bsum, rowptr, cursor);
  fill_kernel<<<1024, 256, 0, stream>>>(src, dst, cursor, colidx);

  // ---- layer 0 (K=38)
  csr_aggregate_38<<<(N_NODES + 3) / 4, 256, 0, stream>>>(x, rowptr, colidx, invdeg, agg);
  hipMemsetAsync(stats, 0, 256 * 4, stream);
  sage_gemm_kernel<38><<<gemm_blocks, 256, 0, stream>>>(agg, x, Wl0, Wr0, hA, stats);
  bn_finalize_kernel<<<1, 128, 0, stream>>>(stats, gamma, beta, sc);
  bn_apply_kernel<<<4096, 256, 0, stream>>>(hA, sc);

  // ---- layers 1..2 (K=128)
  float* cur = hA;
  float* nxt = hB;
  for (int l = 0; l < 2; l++) {
    csr_aggregate_128<<<(N_NODES + 7) / 8, 256, 0, stream>>>(cur, rowptr, colidx,
                                                             invdeg, agg);
    hipMemsetAsync(stats, 0, 256 * 4, stream);
    sage_gemm_kernel<128><<<gemm_blocks, 256, 0, stream>>>(
        agg, cur, Wl + l * 128 * 128, Wr + l * 128 * 128, nxt, stats);
    bn_finalize_kernel<<<1, 128, 0, stream>>>(stats, gamma + (l + 1) * 128,
                                              beta + (l + 1) * 128, sc);
    bn_apply_kernel<<<4096, 256, 0, stream>>>(nxt, sc);
    float* t = cur; cur = nxt; nxt = t;
  }

  // ---- global mean pool + readout
  hipMemsetAsync(pool, 0, (size_t)N_GRAPHS * 128 * 4, stream);
  hipMemsetAsync(cnt, 0, (size_t)N_GRAPHS * 4, stream);
  pool_cnt_kernel<<<NB_SCAN, 256, 0, stream>>>(batch, cnt);
  pool_sum_kernel<<<(N_NODES + 63) / 64, 256, 0, stream>>>(cur, batch, pool);
  readout_kernel<<<N_GRAPHS, 64, 0, stream>>>(pool, cnt, rW1, rb1, rW2, rb2, out);
}

// Round 4
// 505.862 us; speedup vs baseline: 2.7088x; 1.2708x over previous
//
#include <hip/hip_runtime.h>

#define N_NODES 50000
#define N_EDGES 800000
#define N_GRAPHS 2000
#define BN_EPS 1e-5f

typedef unsigned short ushort_t;
typedef unsigned int uint_t;
using bf16x8 = __attribute__((ext_vector_type(8))) short;
using f32x4  = __attribute__((ext_vector_type(4))) float;

__device__ inline float bf_lo(uint_t u) { return __uint_as_float(u << 16); }
__device__ inline float bf_hi(uint_t u) { return __uint_as_float(u & 0xffff0000u); }
__device__ inline ushort_t f2bf(float f) {  // round-to-nearest-even
  uint_t u = __float_as_uint(f);
  return (ushort_t)((u + 0x7fffu + ((u >> 16) & 1u)) >> 16);
}

// ================================================================ CSR build
__global__ void hist_kernel(const int* __restrict__ dst, int* __restrict__ degi) {
  for (int e = blockIdx.x * blockDim.x + threadIdx.x; e < N_EDGES;
       e += gridDim.x * blockDim.x)
    atomicAdd(&degi[dst[e]], 1);
}

__global__ void invdeg_kernel(const int* __restrict__ degi, float* __restrict__ invdeg) {
  int n = blockIdx.x * blockDim.x + threadIdx.x;
  if (n < N_NODES) invdeg[n] = 1.0f / fmaxf((float)degi[n], 1.0f);
}

__global__ void scan_block_kernel(const int* __restrict__ degi,
                                  int* __restrict__ partial,
                                  int* __restrict__ bsum) {
  __shared__ int buf[2][256];
  int i = blockIdx.x * 256 + threadIdx.x;
  int v = (i < N_NODES) ? degi[i] : 0;
  buf[0][threadIdx.x] = v;
  __syncthreads();
  int pi = 0;
  for (int off = 1; off < 256; off <<= 1) {
    int nv = buf[pi][threadIdx.x];
    if (threadIdx.x >= off) nv += buf[pi][threadIdx.x - off];
    buf[pi ^ 1][threadIdx.x] = nv;
    pi ^= 1;
    __syncthreads();
  }
  int incl = buf[pi][threadIdx.x];
  if (i < N_NODES) partial[i] = incl - v;
  if (threadIdx.x == 255) bsum[blockIdx.x] = incl;
}

__global__ void scan_bsum_kernel(int* __restrict__ bsum, int nb) {
  __shared__ int buf[2][256];
  int v = (threadIdx.x < nb) ? bsum[threadIdx.x] : 0;
  buf[0][threadIdx.x] = v;
  __syncthreads();
  int pi = 0;
  for (int off = 1; off < 256; off <<= 1) {
    int nv = buf[pi][threadIdx.x];
    if (threadIdx.x >= off) nv += buf[pi][threadIdx.x - off];
    buf[pi ^ 1][threadIdx.x] = nv;
    pi ^= 1;
    __syncthreads();
  }
  int incl = buf[pi][threadIdx.x];
  if (threadIdx.x < nb) bsum[threadIdx.x] = incl - v;
}

__global__ void scan_add_kernel(const int* __restrict__ partial,
                                const int* __restrict__ bsum,
                                int* __restrict__ rowptr,
                                int* __restrict__ cursor) {
  int i = blockIdx.x * 256 + threadIdx.x;
  if (i < N_NODES) {
    int r = partial[i] + bsum[blockIdx.x];
    rowptr[i] = r;
    cursor[i] = r;
  } else if (i == N_NODES) {
    rowptr[N_NODES] = N_EDGES;
  }
}

__global__ void fill_kernel(const int* __restrict__ src,
                            const int* __restrict__ dst,
                            int* __restrict__ cursor,
                            int* __restrict__ col) {
  for (int e = blockIdx.x * blockDim.x + threadIdx.x; e < N_EDGES;
       e += gridDim.x * blockDim.x) {
    int p = atomicAdd(&cursor[dst[e]], 1);
    col[p] = src[e];
  }
}

// ================================================================ weight prep
// WT[col][k] bf16, k-concat of Wl (k<Kin) and Wr (Kin<=k<2Kin), zero-padded.
__global__ void wprep_kernel(const float* __restrict__ Wl,
                             const float* __restrict__ Wr,
                             ushort_t* __restrict__ WT, int Kin, int Kc) {
  int idx = blockIdx.x * blockDim.x + threadIdx.x;
  if (idx >= 128 * Kc) return;
  int c = idx / Kc, k = idx - c * Kc;
  float v = 0.f;
  if (k < Kin) v = Wl[k * 128 + c];
  else if (k < 2 * Kin) v = Wr[(k - Kin) * 128 + c];
  WT[c * Kc + k] = f2bf(v);
}

// ================================================================ layer-0 inputs
// Acat0[row][96] bf16 : cols 0..37 = agg (written by csr_aggregate_38),
// cols 38..75 = x, 76..95 = 0 (written here).
__global__ void xpack0_kernel(const float* __restrict__ x,
                              ushort_t* __restrict__ A0) {
  int idx = blockIdx.x * blockDim.x + threadIdx.x;
  if (idx >= N_NODES * 58) return;
  int row = idx / 58, c = idx - row * 58 + 38;
  float v = (c < 76) ? x[row * 38 + (c - 38)] : 0.f;
  A0[(size_t)row * 96 + c] = f2bf(v);
}

// one wave per node; lanes 0..37 own one feature (x is fp32 input).
__global__ __launch_bounds__(256) void csr_aggregate_38(
    const float* __restrict__ X, const int* __restrict__ rowptr,
    const int* __restrict__ col, const float* __restrict__ invdeg,
    ushort_t* __restrict__ A0) {
  int node = blockIdx.x * 4 + (threadIdx.x >> 6);
  if (node >= N_NODES) return;
  int lane = threadIdx.x & 63;
  int beg = rowptr[node], end = rowptr[node + 1];
  if (lane < 38) {
    float acc = 0.f;
    int e = beg;
    for (; e + 1 < end; e += 2)
      acc += X[(size_t)col[e] * 38 + lane] + X[(size_t)col[e + 1] * 38 + lane];
    if (e < end) acc += X[(size_t)col[e] * 38 + lane];
    A0[(size_t)node * 96 + lane] = f2bf(acc * invdeg[node]);
  }
}

// ================================================================ aggregate (bf16)
// Acat[row][256] bf16: cols 0..127 = agg (written), 128..255 = h (read).
// one wave per node; lane owns 2 features via packed uint.
__global__ __launch_bounds__(256) void csr_aggregate_128_bf16(
    ushort_t* __restrict__ Acat, const int* __restrict__ rowptr,
    const int* __restrict__ col, const float* __restrict__ invdeg) {
  int node = blockIdx.x * 4 + (threadIdx.x >> 6);
  if (node >= N_NODES) return;
  int lane = threadIdx.x & 63;
  const uint_t* base = (const uint_t*)Acat;  // row stride 128 uints; h at +64
  int beg = rowptr[node], end = rowptr[node + 1];
  float ax = 0.f, ay = 0.f;
  int e = beg;
  for (; e + 1 < end; e += 2) {
    uint_t u0 = base[(size_t)col[e] * 128 + 64 + lane];
    uint_t u1 = base[(size_t)col[e + 1] * 128 + 64 + lane];
    ax += bf_lo(u0) + bf_lo(u1);
    ay += bf_hi(u0) + bf_hi(u1);
  }
  if (e < end) {
    uint_t u = base[(size_t)col[e] * 128 + 64 + lane];
    ax += bf_lo(u);
    ay += bf_hi(u);
  }
  float inv = invdeg[node];
  uint_t packed = (uint_t)f2bf(ax * inv) | ((uint_t)f2bf(ay * inv) << 16);
  ((uint_t*)Acat)[(size_t)node * 128 + lane] = packed;
}

// ================================================================ MFMA GEMM + BN stats
// P[row][128] (bf16, pre-BN) = Acat[row][0:Kc] @ Wcat[Kc][128]
// WT is Wcat transposed: WT[col][k]. Bias dropped (cancelled by BN).
// 64 rows x 128 cols per block, 4 waves (wave w = rows w*16..w*16+15).
template <int Kc>
__global__ __launch_bounds__(256) void gemm_mfma_kernel(
    const ushort_t* __restrict__ A, const ushort_t* __restrict__ WT,
    ushort_t* __restrict__ P, float* __restrict__ stats) {
  constexpr int KP = Kc + 8;  // pad: col stride 2*KP bytes, 16B-aligned, 2-way banks
  __shared__ __align__(16) ushort_t sB[128 * KP];
  __shared__ __align__(16) ushort_t sA[64 * 40];  // 64 rows x 32 k, stride 40
  const int tid = threadIdx.x;
  const int row0 = blockIdx.x * 64;

  // stage full B once (L2-hot, identical across blocks)
  for (int idx = tid; idx < 128 * (Kc / 8); idx += 256) {
    int c = idx / (Kc / 8), kc = idx - c * (Kc / 8);
    uint4 w = ((const uint4*)WT)[c * (Kc / 8) + kc];
    *((uint4*)&sB[c * KP + kc * 8]) = w;
  }

  const int w = tid >> 6;        // wave id 0..3
  const int l = tid & 63;
  const int m = l & 15;          // MFMA row (A) / col (B) index
  const int quad = l >> 4;
  f32x4 acc[8];
#pragma unroll
  for (int ct = 0; ct < 8; ct++) acc[ct] = (f32x4){0.f, 0.f, 0.f, 0.f};

  for (int kk = 0; kk < Kc; kk += 32) {
    __syncthreads();  // first iter: covers sB staging; later: sA reuse
    {
      int r = tid >> 2, c = tid & 3;
      int row = row0 + r;
      uint4 v = make_uint4(0, 0, 0, 0);
      if (row < N_NODES)
        v = ((const uint4*)(A + (size_t)row * Kc))[(kk >> 3) + c];
      *((uint4*)&sA[r * 40 + c * 8]) = v;
    }
    __syncthreads();
    bf16x8 a = *(const bf16x8*)&sA[(w * 16 + m) * 40 + quad * 8];
#pragma unroll
    for (int ct = 0; ct < 8; ct++) {
      bf16x8 b = *(const bf16x8*)&sB[(ct * 16 + m) * KP + kk + quad * 8];
      acc[ct] = __builtin_amdgcn_mfma_f32_16x16x32_bf16(a, b, acc[ct], 0, 0, 0);
    }
  }

  // ---- store pre-BN h as bf16 (D layout: row = quad*4+v, col = ct*16+m)
#pragma unroll
  for (int ct = 0; ct < 8; ct++) {
#pragma unroll
    for (int v = 0; v < 4; v++) {
      int row = row0 + w * 16 + quad * 4 + v;
      if (row < N_NODES) P[(size_t)row * 128 + ct * 16 + m] = f2bf(acc[ct][v]);
    }
  }

  // ---- BN stats epilogue (pad rows contribute exact zeros)
  float* red = (float*)sA;  // [4 waves][2][128]
  __syncthreads();
#pragma unroll
  for (int ct = 0; ct < 8; ct++) {
    float s = 0.f, q = 0.f;
#pragma unroll
    for (int v = 0; v < 4; v++) {
      s += acc[ct][v];
      q += acc[ct][v] * acc[ct][v];
    }
    float t;
    t = __shfl_xor(s, 16); s += t;
    t = __shfl_xor(s, 32); s += t;
    t = __shfl_xor(q, 16); q += t;
    t = __shfl_xor(q, 32); q += t;
    if (l < 16) {
      red[w * 256 + ct * 16 + l] = s;
      red[w * 256 + 128 + ct * 16 + l] = q;
    }
  }
  __syncthreads();
  if (tid < 128) {
    float s = 0.f, q = 0.f;
#pragma unroll
    for (int wv = 0; wv < 4; wv++) {
      s += red[wv * 256 + tid];
      q += red[wv * 256 + 128 + tid];
    }
    atomicAdd(&stats[tid], s);
    atomicAdd(&stats[128 + tid], q);
  }
}

// ================================================================ batchnorm
__global__ void bn_finalize_kernel(const float* __restrict__ stats,
                                   const float* __restrict__ gamma,
                                   const float* __restrict__ beta,
                                   float* __restrict__ sc) {
  int c = threadIdx.x;
  const float invN = 1.0f / (float)N_NODES;
  float mean = stats[c] * invN;
  float var = stats[128 + c] * invN - mean * mean;
  float scale = gamma[c] * rsqrtf(var + BN_EPS);
  sc[c] = scale;
  sc[128 + c] = beta[c] - mean * scale;
}

// h = relu(scale*v + shift), bf16 in/out; dst row stride in ushorts
// (256 -> Acat[:,128:256]; 128 -> in-place / dense).
__global__ void bn_apply_bf16_kernel(const ushort_t* __restrict__ P,
                                     const float* __restrict__ sc,
                                     ushort_t* __restrict__ dst, int dstride) {
  int idx = blockIdx.x * blockDim.x + threadIdx.x;  // uint4 chunks (8 bf16)
  if (idx >= N_NODES * 16) return;
  int row = idx >> 4, c8 = idx & 15;
  uint4 v = ((const uint4*)P)[idx];
  int col = c8 * 8;
  uint_t r[4];
  uint_t in[4] = {v.x, v.y, v.z, v.w};
#pragma unroll
  for (int p = 0; p < 4; p++) {
    float f0 = bf_lo(in[p]), f1 = bf_hi(in[p]);
    float g0 = fmaxf(f0 * sc[col + 2 * p] + sc[128 + col + 2 * p], 0.f);
    float g1 = fmaxf(f1 * sc[col + 2 * p + 1] + sc[128 + col + 2 * p + 1], 0.f);
    r[p] = (uint_t)f2bf(g0) | ((uint_t)f2bf(g1) << 16);
  }
  uint4 o = make_uint4(r[0], r[1], r[2], r[3]);
  *((uint4*)(dst + (size_t)row * dstride + col)) = o;
}

// ================================================================ pooling
__global__ void pool_cnt_kernel(const int* __restrict__ batch,
                                float* __restrict__ cnt) {
  int n = blockIdx.x * blockDim.x + threadIdx.x;
  if (n < N_NODES) atomicAdd(&cnt[batch[n]], 1.0f);
}

// h bf16 [N][128]; batch sorted: run-accumulate, atomic at graph change.
__global__ void pool_sum_bf16_kernel(const ushort_t* __restrict__ h,
                                     const int* __restrict__ batch,
                                     float* __restrict__ pool) {
  const int ROWS = 64;
  int c2 = threadIdx.x & 63;        // uint index (2 cols)
  int half = threadIdx.x >> 6;      // 0..3
  int r0 = blockIdx.x * ROWS;
  int rend = min(r0 + ROWS, N_NODES);
  const uint_t* hu = (const uint_t*)h;  // row stride 64 uints
  float ax = 0.f, ay = 0.f;
  int curg = -1;
  for (int r = r0 + half; r < rend; r += 4) {
    int g = batch[r];
    if (g != curg) {
      if (curg >= 0) {
        atomicAdd(&pool[(size_t)curg * 128 + 2 * c2], ax);
        atomicAdd(&pool[(size_t)curg * 128 + 2 * c2 + 1], ay);
      }
      ax = ay = 0.f;
      curg = g;
    }
    uint_t u = hu[(size_t)r * 64 + c2];
    ax += bf_lo(u);
    ay += bf_hi(u);
  }
  if (curg >= 0) {
    atomicAdd(&pool[(size_t)curg * 128 + 2 * c2], ax);
    atomicAdd(&pool[(size_t)curg * 128 + 2 * c2 + 1], ay);
  }
}

// ================================================================ readout
__global__ void readout_kernel(const float* __restrict__ pool,
                               const float* __restrict__ cnt,
                               const float* __restrict__ rW1,
                               const float* __restrict__ rb1,
                               const float* __restrict__ rW2,
                               const float* __restrict__ rb2,
                               float* __restrict__ out) {
  int g = blockIdx.x;
  int j = threadIdx.x;  // 0..63
  float invc = 1.0f / fmaxf(cnt[g], 1.0f);
  float acc = rb1[j];
  for (int k = 0; k < 128; k++)
    acc += pool[(size_t)g * 128 + k] * invc * rW1[k * 64 + j];
  acc = fmaxf(acc, 0.f) * rW2[j];
#pragma unroll
  for (int off = 32; off > 0; off >>= 1) acc += __shfl_down(acc, off);
  if (j == 0) out[g] = acc + rb2[0];
}

// ================================================================ launch
extern "C" void kernel_launch(void* const* d_in, const int* in_sizes, int n_in,
                              void* d_out, int out_size, void* d_ws, size_t ws_size,
                              hipStream_t stream) {
  const float* x     = (const float*)d_in[0];
  const int*   ei    = (const int*)d_in[1];
  const int*   src   = ei;
  const int*   dst   = ei + N_EDGES;
  const int*   batch = (const int*)d_in[2];
  const float* Wl0   = (const float*)d_in[3];
  const float* Wr0   = (const float*)d_in[4];
  const float* Wl    = (const float*)d_in[6];
  const float* Wr    = (const float*)d_in[7];
  const float* gamma = (const float*)d_in[9];
  const float* beta  = (const float*)d_in[10];
  const float* rW1   = (const float*)d_in[11];
  const float* rb1   = (const float*)d_in[12];
  const float* rW2   = (const float*)d_in[13];
  const float* rb2   = (const float*)d_in[14];
  float* out = (float*)d_out;

  char* ws = (char*)d_ws;
  size_t off = 0;
  auto alloc = [&](size_t bytes) -> void* {
    void* p = ws + off;
    off = (off + bytes + 255) & ~(size_t)255;
    return p;
  };
  ushort_t* Acat0 = (ushort_t*)alloc((size_t)N_NODES * 96 * 2);
  ushort_t* Acat  = (ushort_t*)alloc((size_t)N_NODES * 256 * 2);
  ushort_t* P     = (ushort_t*)alloc((size_t)N_NODES * 128 * 2);
  ushort_t* WT0   = (ushort_t*)alloc((size_t)128 * 96 * 2);
  ushort_t* WT1   = (ushort_t*)alloc((size_t)128 * 256 * 2);
  ushort_t* WT2   = (ushort_t*)alloc((size_t)128 * 256 * 2);
  float* invdeg = (float*)alloc((size_t)N_NODES * 4);
  int*   degi   = (int*)alloc((size_t)N_NODES * 4);
  int*   rowptr = (int*)alloc((size_t)(N_NODES + 1) * 4);
  int*   cursor = (int*)alloc((size_t)N_NODES * 4);
  int*   colidx = (int*)alloc((size_t)N_EDGES * 4);
  int*   partial= (int*)alloc((size_t)N_NODES * 4);
  int*   bsum   = (int*)alloc(256 * 4);
  float* stats  = (float*)alloc(256 * 4);
  float* sc     = (float*)alloc(256 * 4);
  float* pool   = (float*)alloc((size_t)N_GRAPHS * 128 * 4);
  float* cnt    = (float*)alloc((size_t)N_GRAPHS * 4);

  const int NB_SCAN = (N_NODES + 255) / 256;
  const int gemm_blocks = (N_NODES + 63) / 64;   // 782
  const int agg_blocks  = (N_NODES + 3) / 4;

  // ---- CSR build (once)
  hipMemsetAsync(degi, 0, (size_t)N_NODES * 4, stream);
  hist_kernel<<<1024, 256, 0, stream>>>(dst, degi);
  invdeg_kernel<<<NB_SCAN, 256, 0, stream>>>(degi, invdeg);
  scan_block_kernel<<<NB_SCAN, 256, 0, stream>>>(degi, partial, bsum);
  scan_bsum_kernel<<<1, 256, 0, stream>>>(bsum, NB_SCAN);
  scan_add_kernel<<<NB_SCAN + 1, 256, 0, stream>>>(partial, bsum, rowptr, cursor);
  fill_kernel<<<1024, 256, 0, stream>>>(src, dst, cursor, colidx);

  // ---- weights -> bf16 transposed-concat
  wprep_kernel<<<(128 * 96 + 255) / 256, 256, 0, stream>>>(Wl0, Wr0, WT0, 38, 96);
  wprep_kernel<<<(128 * 256 + 255) / 256, 256, 0, stream>>>(Wl, Wr, WT1, 128, 256);
  wprep_kernel<<<(128 * 256 + 255) / 256, 256, 0, stream>>>(Wl + 16384, Wr + 16384,
                                                            WT2, 128, 256);

  // ---- layer 0 (Kc = 96)
  csr_aggregate_38<<<agg_blocks, 256, 0, stream>>>(x, rowptr, colidx, invdeg, Acat0);
  xpack0_kernel<<<(N_NODES * 58 + 255) / 256, 256, 0, stream>>>(x, Acat0);
  hipMemsetAsync(stats, 0, 256 * 4, stream);
  gemm_mfma_kernel<96><<<gemm_blocks, 256, 0, stream>>>(Acat0, WT0, P, stats);
  bn_finalize_kernel<<<1, 128, 0, stream>>>(stats, gamma, beta, sc);
  bn_apply_bf16_kernel<<<(N_NODES * 16 + 255) / 256, 256, 0, stream>>>(
      P, sc, Acat + 128, 256);  // h1 -> Acat[:,128:256]

  // ---- layers 1..2 (Kc = 256)
  for (int l = 0; l < 2; l++) {
    csr_aggregate_128_bf16<<<agg_blocks, 256, 0, stream>>>(Acat, rowptr, colidx,
                                                           invdeg);
    hipMemsetAsync(stats, 0, 256 * 4, stream);
    gemm_mfma_kernel<256><<<gemm_blocks, 256, 0, stream>>>(
        Acat, (l == 0) ? WT1 : WT2, P, stats);
    bn_finalize_kernel<<<1, 128, 0, stream>>>(stats, gamma + (l + 1) * 128,
                                              beta + (l + 1) * 128, sc);
    if (l == 0)
      bn_apply_bf16_kernel<<<(N_NODES * 16 + 255) / 256, 256, 0, stream>>>(
          P, sc, Acat + 128, 256);  // h2 -> Acat[:,128:256]
    else
      bn_apply_bf16_kernel<<<(N_NODES * 16 + 255) / 256, 256, 0, stream>>>(
          P, sc, P, 128);  // h3 in-place (elementwise-safe)
  }

  // ---- global mean pool + readout
  hipMemsetAsync(pool, 0, (size_t)N_GRAPHS * 128 * 4, stream);
  hipMemsetAsync(cnt, 0, (size_t)N_GRAPHS * 4, stream);
  pool_cnt_kernel<<<NB_SCAN, 256, 0, stream>>>(batch, cnt);
  pool_sum_bf16_kernel<<<(N_NODES + 63) / 64, 256, 0, stream>>>(P, batch, pool);
  readout_kernel<<<N_GRAPHS, 64, 0, stream>>>(pool, cnt, rW1, rb1, rW2, rb2, out);
}

// Round 5
// 441.446 us; speedup vs baseline: 3.1041x; 1.1459x over previous
//
#include <hip/hip_runtime.h>

#define N_NODES 50000
#define N_EDGES 800000
#define N_GRAPHS 2000
#define BN_EPS 1e-5f
#define SHARD_SZ 6250  // N_NODES / 8

typedef unsigned short ushort_t;
typedef unsigned int uint_t;
using bf16x8 = __attribute__((ext_vector_type(8))) short;
using f32x4  = __attribute__((ext_vector_type(4))) float;

__device__ inline float bf_lo(uint_t u) { return __uint_as_float(u << 16); }
__device__ inline float bf_hi(uint_t u) { return __uint_as_float(u & 0xffff0000u); }
__device__ inline ushort_t f2bf(float f) {  // round-to-nearest-even
  uint_t u = __float_as_uint(f);
  return (ushort_t)((u + 0x7fffu + ((u >> 16) & 1u)) >> 16);
}

// ================================================================ CSR build
// XCD-sharded histogram/fill: blockIdx&7 ~ XCD (round-robin dispatch
// heuristic; correctness independent of mapping). Each shard owns a
// contiguous 6250-node dst range so its degi/colidx region stays hot in
// one XCD's L2 and lines merge fully before eviction.
__global__ void hist_sharded_kernel(const int* __restrict__ dst,
                                    int* __restrict__ degi) {
  const int shard = blockIdx.x & 7;
  const int lo = shard * SHARD_SZ, hi = lo + SHARD_SZ;
  const int nb = gridDim.x >> 3, blk = blockIdx.x >> 3;
  for (int e = blk * blockDim.x + threadIdx.x; e < N_EDGES;
       e += nb * blockDim.x) {
    int d = dst[e];
    if (d >= lo && d < hi) atomicAdd(&degi[d], 1);
  }
}

__global__ void fill_sharded_kernel(const int* __restrict__ src,
                                    const int* __restrict__ dst,
                                    int* __restrict__ cursor,
                                    ushort_t* __restrict__ col) {
  const int shard = blockIdx.x & 7;
  const int lo = shard * SHARD_SZ, hi = lo + SHARD_SZ;
  const int nb = gridDim.x >> 3, blk = blockIdx.x >> 3;
  for (int e = blk * blockDim.x + threadIdx.x; e < N_EDGES;
       e += nb * blockDim.x) {
    int d = dst[e];
    if (d >= lo && d < hi) {
      int p = atomicAdd(&cursor[d], 1);
      col[p] = (ushort_t)src[e];
    }
  }
}

__global__ void invdeg_kernel(const int* __restrict__ degi, float* __restrict__ invdeg) {
  int n = blockIdx.x * blockDim.x + threadIdx.x;
  if (n < N_NODES) invdeg[n] = 1.0f / fmaxf((float)degi[n], 1.0f);
}

__global__ void scan_block_kernel(const int* __restrict__ degi,
                                  int* __restrict__ partial,
                                  int* __restrict__ bsum) {
  __shared__ int buf[2][256];
  int i = blockIdx.x * 256 + threadIdx.x;
  int v = (i < N_NODES) ? degi[i] : 0;
  buf[0][threadIdx.x] = v;
  __syncthreads();
  int pi = 0;
  for (int off = 1; off < 256; off <<= 1) {
    int nv = buf[pi][threadIdx.x];
    if (threadIdx.x >= off) nv += buf[pi][threadIdx.x - off];
    buf[pi ^ 1][threadIdx.x] = nv;
    pi ^= 1;
    __syncthreads();
  }
  int incl = buf[pi][threadIdx.x];
  if (i < N_NODES) partial[i] = incl - v;
  if (threadIdx.x == 255) bsum[blockIdx.x] = incl;
}

__global__ void scan_bsum_kernel(int* __restrict__ bsum, int nb) {
  __shared__ int buf[2][256];
  int v = (threadIdx.x < nb) ? bsum[threadIdx.x] : 0;
  buf[0][threadIdx.x] = v;
  __syncthreads();
  int pi = 0;
  for (int off = 1; off < 256; off <<= 1) {
    int nv = buf[pi][threadIdx.x];
    if (threadIdx.x >= off) nv += buf[pi][threadIdx.x - off];
    buf[pi ^ 1][threadIdx.x] = nv;
    pi ^= 1;
    __syncthreads();
  }
  int incl = buf[pi][threadIdx.x];
  if (threadIdx.x < nb) bsum[threadIdx.x] = incl - v;
}

__global__ void scan_add_kernel(const int* __restrict__ partial,
                                const int* __restrict__ bsum,
                                int* __restrict__ rowptr,
                                int* __restrict__ cursor) {
  int i = blockIdx.x * 256 + threadIdx.x;
  if (i < N_NODES) {
    int r = partial[i] + bsum[blockIdx.x];
    rowptr[i] = r;
    cursor[i] = r;
  } else if (i == N_NODES) {
    rowptr[N_NODES] = N_EDGES;
  }
}

// ================================================================ weight prep
__global__ void wprep_kernel(const float* __restrict__ Wl,
                             const float* __restrict__ Wr,
                             ushort_t* __restrict__ WT, int Kin, int Kc) {
  int idx = blockIdx.x * blockDim.x + threadIdx.x;
  if (idx >= 128 * Kc) return;
  int c = idx / Kc, k = idx - c * Kc;
  float v = 0.f;
  if (k < Kin) v = Wl[k * 128 + c];
  else if (k < 2 * Kin) v = Wr[(k - Kin) * 128 + c];
  WT[c * Kc + k] = f2bf(v);
}

// ================================================================ layer-0 inputs
__global__ void xpack0_kernel(const float* __restrict__ x,
                              ushort_t* __restrict__ A0) {
  int idx = blockIdx.x * blockDim.x + threadIdx.x;
  if (idx >= N_NODES * 58) return;
  int row = idx / 58, c = idx - row * 58 + 38;
  float v = (c < 76) ? x[row * 38 + (c - 38)] : 0.f;
  A0[(size_t)row * 96 + c] = f2bf(v);
}

__global__ __launch_bounds__(256) void csr_aggregate_38(
    const float* __restrict__ X, const int* __restrict__ rowptr,
    const ushort_t* __restrict__ col, const float* __restrict__ invdeg,
    ushort_t* __restrict__ A0) {
  int node = blockIdx.x * 4 + (threadIdx.x >> 6);
  if (node >= N_NODES) return;
  int lane = threadIdx.x & 63;
  int beg = rowptr[node], end = rowptr[node + 1];
  if (lane < 38) {
    float acc = 0.f;
    int e = beg;
    for (; e + 3 < end; e += 4) {
      int s0 = col[e], s1 = col[e + 1], s2 = col[e + 2], s3 = col[e + 3];
      acc += X[(size_t)s0 * 38 + lane] + X[(size_t)s1 * 38 + lane] +
             X[(size_t)s2 * 38 + lane] + X[(size_t)s3 * 38 + lane];
    }
    for (; e < end; e++) acc += X[(size_t)col[e] * 38 + lane];
    A0[(size_t)node * 96 + lane] = f2bf(acc * invdeg[node]);
  }
}

// ================================================================ aggregate (bf16)
// Acat[row][256] bf16: cols 0..127 = agg (written), 128..255 = h (read).
__global__ __launch_bounds__(256) void csr_aggregate_128_bf16(
    ushort_t* __restrict__ Acat, const int* __restrict__ rowptr,
    const ushort_t* __restrict__ col, const float* __restrict__ invdeg) {
  int node = blockIdx.x * 4 + (threadIdx.x >> 6);
  if (node >= N_NODES) return;
  int lane = threadIdx.x & 63;
  const uint_t* base = (const uint_t*)Acat;  // row stride 128 uints; h at +64
  int beg = rowptr[node], end = rowptr[node + 1];
  float ax = 0.f, ay = 0.f;
  int e = beg;
  for (; e + 3 < end; e += 4) {
    int s0 = col[e], s1 = col[e + 1], s2 = col[e + 2], s3 = col[e + 3];
    uint_t u0 = base[(size_t)s0 * 128 + 64 + lane];
    uint_t u1 = base[(size_t)s1 * 128 + 64 + lane];
    uint_t u2 = base[(size_t)s2 * 128 + 64 + lane];
    uint_t u3 = base[(size_t)s3 * 128 + 64 + lane];
    ax += (bf_lo(u0) + bf_lo(u1)) + (bf_lo(u2) + bf_lo(u3));
    ay += (bf_hi(u0) + bf_hi(u1)) + (bf_hi(u2) + bf_hi(u3));
  }
  for (; e < end; e++) {
    uint_t u = base[(size_t)col[e] * 128 + 64 + lane];
    ax += bf_lo(u);
    ay += bf_hi(u);
  }
  float inv = invdeg[node];
  uint_t packed = (uint_t)f2bf(ax * inv) | ((uint_t)f2bf(ay * inv) << 16);
  ((uint_t*)Acat)[(size_t)node * 128 + lane] = packed;
}

// ================================================================ MFMA GEMM + BN stats
template <int Kc>
__global__ __launch_bounds__(256) void gemm_mfma_kernel(
    const ushort_t* __restrict__ A, const ushort_t* __restrict__ WT,
    ushort_t* __restrict__ P, float* __restrict__ stats) {
  constexpr int KP = Kc + 8;
  __shared__ __align__(16) ushort_t sB[128 * KP];
  __shared__ __align__(16) ushort_t sA[64 * 40];
  const int tid = threadIdx.x;
  const int row0 = blockIdx.x * 64;

  for (int idx = tid; idx < 128 * (Kc / 8); idx += 256) {
    int c = idx / (Kc / 8), kc = idx - c * (Kc / 8);
    uint4 w = ((const uint4*)WT)[c * (Kc / 8) + kc];
    *((uint4*)&sB[c * KP + kc * 8]) = w;
  }

  const int w = tid >> 6;
  const int l = tid & 63;
  const int m = l & 15;
  const int quad = l >> 4;
  f32x4 acc[8];
#pragma unroll
  for (int ct = 0; ct < 8; ct++) acc[ct] = (f32x4){0.f, 0.f, 0.f, 0.f};

  for (int kk = 0; kk < Kc; kk += 32) {
    __syncthreads();
    {
      int r = tid >> 2, c = tid & 3;
      int row = row0 + r;
      uint4 v = make_uint4(0, 0, 0, 0);
      if (row < N_NODES)
        v = ((const uint4*)(A + (size_t)row * Kc))[(kk >> 3) + c];
      *((uint4*)&sA[r * 40 + c * 8]) = v;
    }
    __syncthreads();
    bf16x8 a = *(const bf16x8*)&sA[(w * 16 + m) * 40 + quad * 8];
#pragma unroll
    for (int ct = 0; ct < 8; ct++) {
      bf16x8 b = *(const bf16x8*)&sB[(ct * 16 + m) * KP + kk + quad * 8];
      acc[ct] = __builtin_amdgcn_mfma_f32_16x16x32_bf16(a, b, acc[ct], 0, 0, 0);
    }
  }

#pragma unroll
  for (int ct = 0; ct < 8; ct++) {
#pragma unroll
    for (int v = 0; v < 4; v++) {
      int row = row0 + w * 16 + quad * 4 + v;
      if (row < N_NODES) P[(size_t)row * 128 + ct * 16 + m] = f2bf(acc[ct][v]);
    }
  }

  float* red = (float*)sA;
  __syncthreads();
#pragma unroll
  for (int ct = 0; ct < 8; ct++) {
    float s = 0.f, q = 0.f;
#pragma unroll
    for (int v = 0; v < 4; v++) {
      s += acc[ct][v];
      q += acc[ct][v] * acc[ct][v];
    }
    float t;
    t = __shfl_xor(s, 16); s += t;
    t = __shfl_xor(s, 32); s += t;
    t = __shfl_xor(q, 16); q += t;
    t = __shfl_xor(q, 32); q += t;
    if (l < 16) {
      red[w * 256 + ct * 16 + l] = s;
      red[w * 256 + 128 + ct * 16 + l] = q;
    }
  }
  __syncthreads();
  if (tid < 128) {
    float s = 0.f, q = 0.f;
#pragma unroll
    for (int wv = 0; wv < 4; wv++) {
      s += red[wv * 256 + tid];
      q += red[wv * 256 + 128 + tid];
    }
    atomicAdd(&stats[tid], s);
    atomicAdd(&stats[128 + tid], q);
  }
}

// ================================================================ batchnorm
__global__ void bn_finalize_kernel(const float* __restrict__ stats,
                                   const float* __restrict__ gamma,
                                   const float* __restrict__ beta,
                                   float* __restrict__ sc) {
  int c = threadIdx.x;
  const float invN = 1.0f / (float)N_NODES;
  float mean = stats[c] * invN;
  float var = stats[128 + c] * invN - mean * mean;
  float scale = gamma[c] * rsqrtf(var + BN_EPS);
  sc[c] = scale;
  sc[128 + c] = beta[c] - mean * scale;
}

__global__ void bn_apply_bf16_kernel(const ushort_t* __restrict__ P,
                                     const float* __restrict__ sc,
                                     ushort_t* __restrict__ dst, int dstride) {
  int idx = blockIdx.x * blockDim.x + threadIdx.x;
  if (idx >= N_NODES * 16) return;
  int row = idx >> 4, c8 = idx & 15;
  uint4 v = ((const uint4*)P)[idx];
  int col = c8 * 8;
  uint_t r[4];
  uint_t in[4] = {v.x, v.y, v.z, v.w};
#pragma unroll
  for (int p = 0; p < 4; p++) {
    float f0 = bf_lo(in[p]), f1 = bf_hi(in[p]);
    float g0 = fmaxf(f0 * sc[col + 2 * p] + sc[128 + col + 2 * p], 0.f);
    float g1 = fmaxf(f1 * sc[col + 2 * p + 1] + sc[128 + col + 2 * p + 1], 0.f);
    r[p] = (uint_t)f2bf(g0) | ((uint_t)f2bf(g1) << 16);
  }
  uint4 o = make_uint4(r[0], r[1], r[2], r[3]);
  *((uint4*)(dst + (size_t)row * dstride + col)) = o;
}

// ================================================================ pooling
__global__ void pool_cnt_kernel(const int* __restrict__ batch,
                                float* __restrict__ cnt) {
  int n = blockIdx.x * blockDim.x + threadIdx.x;
  if (n < N_NODES) atomicAdd(&cnt[batch[n]], 1.0f);
}

// fused: pool += relu(scale*P + shift)   (layer-3 BN applied inline)
__global__ void pool_sum_fused_kernel(const ushort_t* __restrict__ P,
                                      const float* __restrict__ sc,
                                      const int* __restrict__ batch,
                                      float* __restrict__ pool) {
  const int ROWS = 64;
  int c2 = threadIdx.x & 63;
  int half = threadIdx.x >> 6;
  int r0 = blockIdx.x * ROWS;
  int rend = min(r0 + ROWS, N_NODES);
  const uint_t* Pu = (const uint_t*)P;
  float s0 = sc[2 * c2], s1 = sc[2 * c2 + 1];
  float b0 = sc[128 + 2 * c2], b1 = sc[128 + 2 * c2 + 1];
  float ax = 0.f, ay = 0.f;
  int curg = -1;
  for (int r = r0 + half; r < rend; r += 4) {
    int g = batch[r];
    if (g != curg) {
      if (curg >= 0) {
        atomicAdd(&pool[(size_t)curg * 128 + 2 * c2], ax);
        atomicAdd(&pool[(size_t)curg * 128 + 2 * c2 + 1], ay);
      }
      ax = ay = 0.f;
      curg = g;
    }
    uint_t u = Pu[(size_t)r * 64 + c2];
    ax += fmaxf(bf_lo(u) * s0 + b0, 0.f);
    ay += fmaxf(bf_hi(u) * s1 + b1, 0.f);
  }
  if (curg >= 0) {
    atomicAdd(&pool[(size_t)curg * 128 + 2 * c2], ax);
    atomicAdd(&pool[(size_t)curg * 128 + 2 * c2 + 1], ay);
  }
}

// ================================================================ readout
__global__ void readout_kernel(const float* __restrict__ pool,
                               const float* __restrict__ cnt,
                               const float* __restrict__ rW1,
                               const float* __restrict__ rb1,
                               const float* __restrict__ rW2,
                               const float* __restrict__ rb2,
                               float* __restrict__ out) {
  int g = blockIdx.x;
  int j = threadIdx.x;  // 0..63
  float invc = 1.0f / fmaxf(cnt[g], 1.0f);
  float acc = rb1[j];
  for (int k = 0; k < 128; k++)
    acc += pool[(size_t)g * 128 + k] * invc * rW1[k * 64 + j];
  acc = fmaxf(acc, 0.f) * rW2[j];
#pragma unroll
  for (int off = 32; off > 0; off >>= 1) acc += __shfl_down(acc, off);
  if (j == 0) out[g] = acc + rb2[0];
}

// ================================================================ launch
extern "C" void kernel_launch(void* const* d_in, const int* in_sizes, int n_in,
                              void* d_out, int out_size, void* d_ws, size_t ws_size,
                              hipStream_t stream) {
  const float* x     = (const float*)d_in[0];
  const int*   ei    = (const int*)d_in[1];
  const int*   src   = ei;
  const int*   dst   = ei + N_EDGES;
  const int*   batch = (const int*)d_in[2];
  const float* Wl0   = (const float*)d_in[3];
  const float* Wr0   = (const float*)d_in[4];
  const float* Wl    = (const float*)d_in[6];
  const float* Wr    = (const float*)d_in[7];
  const float* gamma = (const float*)d_in[9];
  const float* beta  = (const float*)d_in[10];
  const float* rW1   = (const float*)d_in[11];
  const float* rb1   = (const float*)d_in[12];
  const float* rW2   = (const float*)d_in[13];
  const float* rb2   = (const float*)d_in[14];
  float* out = (float*)d_out;

  char* ws = (char*)d_ws;
  size_t off = 0;
  auto alloc = [&](size_t bytes) -> void* {
    void* p = ws + off;
    off = (off + bytes + 255) & ~(size_t)255;
    return p;
  };
  ushort_t* Acat0 = (ushort_t*)alloc((size_t)N_NODES * 96 * 2);
  ushort_t* Acat  = (ushort_t*)alloc((size_t)N_NODES * 256 * 2);
  ushort_t* P     = (ushort_t*)alloc((size_t)N_NODES * 128 * 2);
  ushort_t* WT0   = (ushort_t*)alloc((size_t)128 * 96 * 2);
  ushort_t* WT1   = (ushort_t*)alloc((size_t)128 * 256 * 2);
  ushort_t* WT2   = (ushort_t*)alloc((size_t)128 * 256 * 2);
  float* invdeg = (float*)alloc((size_t)N_NODES * 4);
  int*   degi   = (int*)alloc((size_t)N_NODES * 4);
  int*   rowptr = (int*)alloc((size_t)(N_NODES + 1) * 4);
  int*   cursor = (int*)alloc((size_t)N_NODES * 4);
  ushort_t* colidx = (ushort_t*)alloc((size_t)N_EDGES * 2);
  int*   partial= (int*)alloc((size_t)N_NODES * 4);
  int*   bsum   = (int*)alloc(256 * 4);
  float* stats  = (float*)alloc(256 * 4);
  float* sc     = (float*)alloc(256 * 4);
  float* pool   = (float*)alloc((size_t)N_GRAPHS * 128 * 4);
  float* cnt    = (float*)alloc((size_t)N_GRAPHS * 4);

  const int NB_SCAN = (N_NODES + 255) / 256;
  const int gemm_blocks = (N_NODES + 63) / 64;
  const int agg_blocks  = (N_NODES + 3) / 4;

  // ---- CSR build (once)
  hipMemsetAsync(degi, 0, (size_t)N_NODES * 4, stream);
  hist_sharded_kernel<<<2048, 256, 0, stream>>>(dst, degi);
  invdeg_kernel<<<NB_SCAN, 256, 0, stream>>>(degi, invdeg);
  scan_block_kernel<<<NB_SCAN, 256, 0, stream>>>(degi, partial, bsum);
  scan_bsum_kernel<<<1, 256, 0, stream>>>(bsum, NB_SCAN);
  scan_add_kernel<<<NB_SCAN + 1, 256, 0, stream>>>(partial, bsum, rowptr, cursor);
  fill_sharded_kernel<<<2048, 256, 0, stream>>>(src, dst, cursor, colidx);

  // ---- weights -> bf16 transposed-concat
  wprep_kernel<<<(128 * 96 + 255) / 256, 256, 0, stream>>>(Wl0, Wr0, WT0, 38, 96);
  wprep_kernel<<<(128 * 256 + 255) / 256, 256, 0, stream>>>(Wl, Wr, WT1, 128, 256);
  wprep_kernel<<<(128 * 256 + 255) / 256, 256, 0, stream>>>(Wl + 16384, Wr + 16384,
                                                            WT2, 128, 256);

  // ---- layer 0 (Kc = 96)
  csr_aggregate_38<<<agg_blocks, 256, 0, stream>>>(x, rowptr, colidx, invdeg, Acat0);
  xpack0_kernel<<<(N_NODES * 58 + 255) / 256, 256, 0, stream>>>(x, Acat0);
  hipMemsetAsync(stats, 0, 256 * 4, stream);
  gemm_mfma_kernel<96><<<gemm_blocks, 256, 0, stream>>>(Acat0, WT0, P, stats);
  bn_finalize_kernel<<<1, 128, 0, stream>>>(stats, gamma, beta, sc);
  bn_apply_bf16_kernel<<<(N_NODES * 16 + 255) / 256, 256, 0, stream>>>(
      P, sc, Acat + 128, 256);  // h1 -> Acat[:,128:256]

  // ---- layers 1..2 (Kc = 256)
  for (int l = 0; l < 2; l++) {
    csr_aggregate_128_bf16<<<agg_blocks, 256, 0, stream>>>(Acat, rowptr, colidx,
                                                           invdeg);
    hipMemsetAsync(stats, 0, 256 * 4, stream);
    gemm_mfma_kernel<256><<<gemm_blocks, 256, 0, stream>>>(
        Acat, (l == 0) ? WT1 : WT2, P, stats);
    bn_finalize_kernel<<<1, 128, 0, stream>>>(stats, gamma + (l + 1) * 128,
                                              beta + (l + 1) * 128, sc);
    if (l == 0)
      bn_apply_bf16_kernel<<<(N_NODES * 16 + 255) / 256, 256, 0, stream>>>(
          P, sc, Acat + 128, 256);  // h2 -> Acat[:,128:256]
    // l == 1: BN+ReLU fused into pool_sum below
  }

  // ---- global mean pool + readout (layer-3 BN fused into pooling)
  hipMemsetAsync(pool, 0, (size_t)N_GRAPHS * 128 * 4, stream);
  hipMemsetAsync(cnt, 0, (size_t)N_GRAPHS * 4, stream);
  pool_cnt_kernel<<<NB_SCAN, 256, 0, stream>>>(batch, cnt);
  pool_sum_fused_kernel<<<(N_NODES + 63) / 64, 256, 0, stream>>>(P, sc, batch, pool);
  readout_kernel<<<N_GRAPHS, 64, 0, stream>>>(pool, cnt, rW1, rb1, rW2, rb2, out);
}

// Round 7
// 416.510 us; speedup vs baseline: 3.2900x; 1.0599x over previous
//
#include <hip/hip_runtime.h>

#define N_NODES 50000
#define N_EDGES 800000
#define N_GRAPHS 2000
#define BN_EPS 1e-5f
#define SHARD_SZ 6250  // N_NODES / 8

typedef unsigned short ushort_t;
typedef unsigned int uint_t;
using bf16x8 = __attribute__((ext_vector_type(8))) short;
using f32x4  = __attribute__((ext_vector_type(4))) float;

__device__ inline float bf_lo(uint_t u) { return __uint_as_float(u << 16); }
__device__ inline float bf_hi(uint_t u) { return __uint_as_float(u & 0xffff0000u); }
__device__ inline ushort_t f2bf(float f) {  // round-to-nearest-even
  uint_t u = __float_as_uint(f);
  return (ushort_t)((u + 0x7fffu + ((u >> 16) & 1u)) >> 16);
}

// ================================================================ CSR build
// XCD-sharded histogram/fill (blockIdx&7 ~ XCD round-robin heuristic;
// correctness independent of mapping): each shard owns a contiguous
// 6250-node dst range so its degi/colidx region stays hot in one XCD L2.
__global__ void hist_sharded_kernel(const int* __restrict__ dst,
                                    int* __restrict__ degi) {
  const int shard = blockIdx.x & 7;
  const int lo = shard * SHARD_SZ, hi = lo + SHARD_SZ;
  const int nb = gridDim.x >> 3, blk = blockIdx.x >> 3;
  for (int e = blk * blockDim.x + threadIdx.x; e < N_EDGES;
       e += nb * blockDim.x) {
    int d = dst[e];
    if (d >= lo && d < hi) atomicAdd(&degi[d], 1);
  }
}

__global__ void fill_sharded_kernel(const int* __restrict__ src,
                                    const int* __restrict__ dst,
                                    int* __restrict__ cursor,
                                    ushort_t* __restrict__ col) {
  const int shard = blockIdx.x & 7;
  const int lo = shard * SHARD_SZ, hi = lo + SHARD_SZ;
  const int nb = gridDim.x >> 3, blk = blockIdx.x >> 3;
  for (int e = blk * blockDim.x + threadIdx.x; e < N_EDGES;
       e += nb * blockDim.x) {
    int d = dst[e];
    if (d >= lo && d < hi) {
      int p = atomicAdd(&cursor[d], 1);
      col[p] = (ushort_t)src[e];
    }
  }
}

// exclusive scan step 1 (+ invdeg fused: reads degi anyway)
__global__ void scan_block_kernel(const int* __restrict__ degi,
                                  int* __restrict__ partial,
                                  int* __restrict__ bsum,
                                  float* __restrict__ invdeg) {
  __shared__ int buf[2][256];
  int i = blockIdx.x * 256 + threadIdx.x;
  int v = (i < N_NODES) ? degi[i] : 0;
  buf[0][threadIdx.x] = v;
  __syncthreads();
  int pi = 0;
  for (int off = 1; off < 256; off <<= 1) {
    int nv = buf[pi][threadIdx.x];
    if (threadIdx.x >= off) nv += buf[pi][threadIdx.x - off];
    buf[pi ^ 1][threadIdx.x] = nv;
    pi ^= 1;
    __syncthreads();
  }
  int incl = buf[pi][threadIdx.x];
  if (i < N_NODES) {
    partial[i] = incl - v;
    invdeg[i] = 1.0f / fmaxf((float)v, 1.0f);
  }
  if (threadIdx.x == 255) bsum[blockIdx.x] = incl;
}

__global__ void scan_bsum_kernel(int* __restrict__ bsum, int nb) {
  __shared__ int buf[2][256];
  int v = (threadIdx.x < nb) ? bsum[threadIdx.x] : 0;
  buf[0][threadIdx.x] = v;
  __syncthreads();
  int pi = 0;
  for (int off = 1; off < 256; off <<= 1) {
    int nv = buf[pi][threadIdx.x];
    if (threadIdx.x >= off) nv += buf[pi][threadIdx.x - off];
    buf[pi ^ 1][threadIdx.x] = nv;
    pi ^= 1;
    __syncthreads();
  }
  int incl = buf[pi][threadIdx.x];
  if (threadIdx.x < nb) bsum[threadIdx.x] = incl - v;
}

__global__ void scan_add_kernel(const int* __restrict__ partial,
                                const int* __restrict__ bsum,
                                int* __restrict__ rowptr,
                                int* __restrict__ cursor) {
  int i = blockIdx.x * 256 + threadIdx.x;
  if (i < N_NODES) {
    int r = partial[i] + bsum[blockIdx.x];
    rowptr[i] = r;
    cursor[i] = r;
  } else if (i == N_NODES) {
    rowptr[N_NODES] = N_EDGES;
  }
}

// ================================================================ weight prep
// all three layers' WT in one launch; also zeroes stats for layer-0 gemm.
#define WP0 (128 * 96)
#define WP1 (128 * 256)
__global__ void wprep_all_kernel(const float* __restrict__ Wl0,
                                 const float* __restrict__ Wr0,
                                 const float* __restrict__ Wl,
                                 const float* __restrict__ Wr,
                                 ushort_t* __restrict__ WT0,
                                 ushort_t* __restrict__ WT1,
                                 ushort_t* __restrict__ WT2,
                                 float* __restrict__ stats) {
  int idx = blockIdx.x * blockDim.x + threadIdx.x;
  if (idx < 256) stats[idx] = 0.f;
  if (idx < WP0) {
    int c = idx / 96, k = idx - c * 96;
    float v = 0.f;
    if (k < 38) v = Wl0[k * 128 + c];
    else if (k < 76) v = Wr0[(k - 38) * 128 + c];
    WT0[c * 96 + k] = f2bf(v);
  } else if (idx < WP0 + 2 * WP1) {
    int i2 = idx - WP0;
    int layer = i2 / WP1;  // 0 or 1
    int j = i2 - layer * WP1;
    int c = j / 256, k = j - c * 256;
    const float* L = Wl + layer * 16384;
    const float* R = Wr + layer * 16384;
    float v = (k < 128) ? L[k * 128 + c] : R[(k - 128) * 128 + c];
    ushort_t* W = layer ? WT2 : WT1;
    W[c * 256 + k] = f2bf(v);
  }
}

// ================================================================ layer-0 prep
// one wave per node: lanes<38 gather-mean x into A0 cols 0..37;
// lanes 0..57 pack x into cols 38..75, zeros into 76..95.
__global__ __launch_bounds__(256) void layer0_prep_kernel(
    const float* __restrict__ x, const int* __restrict__ rowptr,
    const ushort_t* __restrict__ col, const float* __restrict__ invdeg,
    ushort_t* __restrict__ A0) {
  int node = blockIdx.x * 4 + (threadIdx.x >> 6);
  if (node >= N_NODES) return;
  int lane = threadIdx.x & 63;
  int beg = rowptr[node], end = rowptr[node + 1];
  if (lane < 38) {
    float acc = 0.f;
    int e = beg;
    for (; e + 3 < end; e += 4) {
      int s0 = col[e], s1 = col[e + 1], s2 = col[e + 2], s3 = col[e + 3];
      acc += (x[(size_t)s0 * 38 + lane] + x[(size_t)s1 * 38 + lane]) +
             (x[(size_t)s2 * 38 + lane] + x[(size_t)s3 * 38 + lane]);
    }
    for (; e < end; e++) acc += x[(size_t)col[e] * 38 + lane];
    A0[(size_t)node * 96 + lane] = f2bf(acc * invdeg[node]);
  }
  int c = 38 + lane;
  if (c < 96) {
    float v = (c < 76) ? x[(size_t)node * 38 + (c - 38)] : 0.f;
    A0[(size_t)node * 96 + c] = f2bf(v);
  }
}

// ================================================================ aggregate + BN
// agg[node][0:128] = invdeg * sum_{src} relu(P[src]*scale + shift)
// (BN of previous layer applied on the fly; h never materialized)
__global__ __launch_bounds__(256) void csr_aggregate_bn_kernel(
    const ushort_t* __restrict__ Pin, const float* __restrict__ sc,
    const int* __restrict__ rowptr, const ushort_t* __restrict__ col,
    const float* __restrict__ invdeg, ushort_t* __restrict__ agg) {
  int node = blockIdx.x * 4 + (threadIdx.x >> 6);
  if (node >= N_NODES) return;
  int lane = threadIdx.x & 63;
  const uint_t* Pu = (const uint_t*)Pin;  // row stride 64 uints
  float s0 = sc[2 * lane], s1 = sc[2 * lane + 1];
  float b0 = sc[128 + 2 * lane], b1 = sc[128 + 2 * lane + 1];
  int beg = rowptr[node], end = rowptr[node + 1];
  float ax = 0.f, ay = 0.f;
  int e = beg;
  for (; e + 3 < end; e += 4) {
    int c0 = col[e], c1 = col[e + 1], c2 = col[e + 2], c3 = col[e + 3];
    uint_t u0 = Pu[(size_t)c0 * 64 + lane];
    uint_t u1 = Pu[(size_t)c1 * 64 + lane];
    uint_t u2 = Pu[(size_t)c2 * 64 + lane];
    uint_t u3 = Pu[(size_t)c3 * 64 + lane];
    ax += (fmaxf(bf_lo(u0) * s0 + b0, 0.f) + fmaxf(bf_lo(u1) * s0 + b0, 0.f)) +
          (fmaxf(bf_lo(u2) * s0 + b0, 0.f) + fmaxf(bf_lo(u3) * s0 + b0, 0.f));
    ay += (fmaxf(bf_hi(u0) * s1 + b1, 0.f) + fmaxf(bf_hi(u1) * s1 + b1, 0.f)) +
          (fmaxf(bf_hi(u2) * s1 + b1, 0.f) + fmaxf(bf_hi(u3) * s1 + b1, 0.f));
  }
  for (; e < end; e++) {
    uint_t u = Pu[(size_t)col[e] * 64 + lane];
    ax += fmaxf(bf_lo(u) * s0 + b0, 0.f);
    ay += fmaxf(bf_hi(u) * s1 + b1, 0.f);
  }
  float inv = invdeg[node];
  uint_t packed = (uint_t)f2bf(ax * inv) | ((uint_t)f2bf(ay * inv) << 16);
  ((uint_t*)agg)[(size_t)node * 64 + lane] = packed;
}

// ================================================================ MFMA GEMM + BN stats
// P[row][128] (bf16 pre-BN) = Acat[row][0:Kc] @ Wcat, where for BN=true
// Acat = [ agg[row][0:128] | relu(Pin[row]*scale+shift) ]  (BN on the fly)
// and for BN=false Acat = A (row stride Kc). Bias cancelled by BN.
template <int Kc, bool BN>
__global__ __launch_bounds__(256) void gemm_mfma_kernel(
    const ushort_t* __restrict__ A, const ushort_t* __restrict__ Pin,
    const float* __restrict__ sc, const ushort_t* __restrict__ WT,
    ushort_t* __restrict__ P, float* __restrict__ stats) {
  constexpr int KP = Kc + 8;
  __shared__ __align__(16) ushort_t sB[128 * KP];
  __shared__ __align__(16) ushort_t sA[64 * 40];
  __shared__ float ssc[256];
  const int tid = threadIdx.x;
  const int row0 = blockIdx.x * 64;

  if (BN) ssc[tid] = sc[tid];  // covered by first __syncthreads in loop

  for (int idx = tid; idx < 128 * (Kc / 8); idx += 256) {
    int c = idx / (Kc / 8), kc = idx - c * (Kc / 8);
    uint4 w = ((const uint4*)WT)[c * (Kc / 8) + kc];
    *((uint4*)&sB[c * KP + kc * 8]) = w;
  }

  const int w = tid >> 6;
  const int l = tid & 63;
  const int m = l & 15;
  const int quad = l >> 4;
  f32x4 acc[8];
#pragma unroll
  for (int ct = 0; ct < 8; ct++) acc[ct] = (f32x4){0.f, 0.f, 0.f, 0.f};

  for (int kk = 0; kk < Kc; kk += 32) {
    __syncthreads();
    {
      int r = tid >> 2, c = tid & 3;
      int row = row0 + r;
      uint4 v = make_uint4(0, 0, 0, 0);
      if (row < N_NODES) {
        if (!BN) {
          v = ((const uint4*)(A + (size_t)row * Kc))[(kk >> 3) + c];
        } else if (kk < 128) {
          v = ((const uint4*)(A + (size_t)row * 128))[(kk >> 3) + c];
        } else {
          int pcol = kk - 128 + c * 8;
          uint4 u = *(const uint4*)(Pin + (size_t)row * 128 + pcol);
          uint_t in[4] = {u.x, u.y, u.z, u.w};
          uint_t ov[4];
#pragma unroll
          for (int p = 0; p < 4; p++) {
            int cc = pcol + 2 * p;
            float f0 = fmaxf(bf_lo(in[p]) * ssc[cc] + ssc[128 + cc], 0.f);
            float f1 = fmaxf(bf_hi(in[p]) * ssc[cc + 1] + ssc[128 + cc + 1], 0.f);
            ov[p] = (uint_t)f2bf(f0) | ((uint_t)f2bf(f1) << 16);
          }
          v = make_uint4(ov[0], ov[1], ov[2], ov[3]);
        }
      }
      *((uint4*)&sA[r * 40 + c * 8]) = v;
    }
    __syncthreads();
    bf16x8 a = *(const bf16x8*)&sA[(w * 16 + m) * 40 + quad * 8];
#pragma unroll
    for (int ct = 0; ct < 8; ct++) {
      bf16x8 b = *(const bf16x8*)&sB[(ct * 16 + m) * KP + kk + quad * 8];
      acc[ct] = __builtin_amdgcn_mfma_f32_16x16x32_bf16(a, b, acc[ct], 0, 0, 0);
    }
  }

  // store pre-BN result (D layout: row = quad*4+v, col = ct*16+m)
#pragma unroll
  for (int ct = 0; ct < 8; ct++) {
#pragma unroll
    for (int v = 0; v < 4; v++) {
      int row = row0 + w * 16 + quad * 4 + v;
      if (row < N_NODES) P[(size_t)row * 128 + ct * 16 + m] = f2bf(acc[ct][v]);
    }
  }

  // BN stats epilogue (pad rows contribute exact zeros)
  float* red = (float*)sA;
  __syncthreads();
#pragma unroll
  for (int ct = 0; ct < 8; ct++) {
    float s = 0.f, q = 0.f;
#pragma unroll
    for (int v = 0; v < 4; v++) {
      s += acc[ct][v];
      q += acc[ct][v] * acc[ct][v];
    }
    float t;
    t = __shfl_xor(s, 16); s += t;
    t = __shfl_xor(s, 32); s += t;
    t = __shfl_xor(q, 16); q += t;
    t = __shfl_xor(q, 32); q += t;
    if (l < 16) {
      red[w * 256 + ct * 16 + l] = s;
      red[w * 256 + 128 + ct * 16 + l] = q;
    }
  }
  __syncthreads();
  if (tid < 128) {
    float s = 0.f, q = 0.f;
#pragma unroll
    for (int wv = 0; wv < 4; wv++) {
      s += red[wv * 256 + tid];
      q += red[wv * 256 + 128 + tid];
    }
    atomicAdd(&stats[tid], s);
    atomicAdd(&stats[128 + tid], q);
  }
}

// ================================================================ batchnorm finalize
// reads stats -> sc, then zeroes stats for the next layer's gemm.
__global__ void bn_finalize_kernel(float* __restrict__ stats,
                                   const float* __restrict__ gamma,
                                   const float* __restrict__ beta,
                                   float* __restrict__ sc) {
  int c = threadIdx.x;
  const float invN = 1.0f / (float)N_NODES;
  float mean = stats[c] * invN;
  float var = stats[128 + c] * invN - mean * mean;
  float scale = gamma[c] * rsqrtf(var + BN_EPS);
  sc[c] = scale;
  sc[128 + c] = beta[c] - mean * scale;
  stats[c] = 0.f;
  stats[128 + c] = 0.f;
}

// ================================================================ pooling
__global__ void pool_cnt_kernel(const int* __restrict__ batch,
                                float* __restrict__ cnt) {
  int n = blockIdx.x * blockDim.x + threadIdx.x;
  if (n < N_NODES) atomicAdd(&cnt[batch[n]], 1.0f);
}

// fused: pool += relu(scale*P + shift)   (final BN applied inline;
// batch sorted: run-accumulate, atomic only at graph change)
__global__ void pool_sum_fused_kernel(const ushort_t* __restrict__ P,
                                      const float* __restrict__ sc,
                                      const int* __restrict__ batch,
                                      float* __restrict__ pool) {
  const int ROWS = 64;
  int c2 = threadIdx.x & 63;
  int half = threadIdx.x >> 6;
  int r0 = blockIdx.x * ROWS;
  int rend = min(r0 + ROWS, N_NODES);
  const uint_t* Pu = (const uint_t*)P;
  float s0 = sc[2 * c2], s1 = sc[2 * c2 + 1];
  float b0 = sc[128 + 2 * c2], b1 = sc[128 + 2 * c2 + 1];
  float ax = 0.f, ay = 0.f;
  int curg = -1;
  for (int r = r0 + half; r < rend; r += 4) {
    int g = batch[r];
    if (g != curg) {
      if (curg >= 0) {
        atomicAdd(&pool[(size_t)curg * 128 + 2 * c2], ax);
        atomicAdd(&pool[(size_t)curg * 128 + 2 * c2 + 1], ay);
      }
      ax = ay = 0.f;
      curg = g;
    }
    uint_t u = Pu[(size_t)r * 64 + c2];
    ax += fmaxf(bf_lo(u) * s0 + b0, 0.f);
    ay += fmaxf(bf_hi(u) * s1 + b1, 0.f);
  }
  if (curg >= 0) {
    atomicAdd(&pool[(size_t)curg * 128 + 2 * c2], ax);
    atomicAdd(&pool[(size_t)curg * 128 + 2 * c2 + 1], ay);
  }
}

// ================================================================ readout
__global__ void readout_kernel(const float* __restrict__ pool,
                               const float* __restrict__ cnt,
                               const float* __restrict__ rW1,
                               const float* __restrict__ rb1,
                               const float* __restrict__ rW2,
                               const float* __restrict__ rb2,
                               float* __restrict__ out) {
  int g = blockIdx.x;
  int j = threadIdx.x;  // 0..63
  float invc = 1.0f / fmaxf(cnt[g], 1.0f);
  float acc = rb1[j];
  for (int k = 0; k < 128; k++)
    acc += pool[(size_t)g * 128 + k] * invc * rW1[k * 64 + j];
  acc = fmaxf(acc, 0.f) * rW2[j];
#pragma unroll
  for (int off = 32; off > 0; off >>= 1) acc += __shfl_down(acc, off);
  if (j == 0) out[g] = acc + rb2[0];
}

// ================================================================ launch
extern "C" void kernel_launch(void* const* d_in, const int* in_sizes, int n_in,
                              void* d_out, int out_size, void* d_ws, size_t ws_size,
                              hipStream_t stream) {
  const float* x     = (const float*)d_in[0];
  const int*   ei    = (const int*)d_in[1];
  const int*   src   = ei;
  const int*   dst   = ei + N_EDGES;
  const int*   batch = (const int*)d_in[2];
  const float* Wl0   = (const float*)d_in[3];
  const float* Wr0   = (const float*)d_in[4];
  const float* Wl    = (const float*)d_in[6];
  const float* Wr    = (const float*)d_in[7];
  const float* gamma = (const float*)d_in[9];
  const float* beta  = (const float*)d_in[10];
  const float* rW1   = (const float*)d_in[11];
  const float* rb1   = (const float*)d_in[12];
  const float* rW2   = (const float*)d_in[13];
  const float* rb2   = (const float*)d_in[14];
  float* out = (float*)d_out;

  char* ws = (char*)d_ws;
  size_t off = 0;
  auto alloc = [&](size_t bytes) -> void* {
    void* p = ws + off;
    off = (off + bytes + 255) & ~(size_t)255;
    return p;
  };
  ushort_t* A0    = (ushort_t*)alloc((size_t)N_NODES * 96 * 2);
  ushort_t* agg   = (ushort_t*)alloc((size_t)N_NODES * 128 * 2);
  ushort_t* Pa    = (ushort_t*)alloc((size_t)N_NODES * 128 * 2);
  ushort_t* Pb    = (ushort_t*)alloc((size_t)N_NODES * 128 * 2);
  ushort_t* WT0   = (ushort_t*)alloc((size_t)128 * 96 * 2);
  ushort_t* WT1   = (ushort_t*)alloc((size_t)128 * 256 * 2);
  ushort_t* WT2   = (ushort_t*)alloc((size_t)128 * 256 * 2);
  float* invdeg = (float*)alloc((size_t)N_NODES * 4);
  int*   degi   = (int*)alloc((size_t)N_NODES * 4);
  int*   rowptr = (int*)alloc((size_t)(N_NODES + 1) * 4);
  int*   cursor = (int*)alloc((size_t)N_NODES * 4);
  ushort_t* colidx = (ushort_t*)alloc((size_t)N_EDGES * 2);
  int*   partial= (int*)alloc((size_t)N_NODES * 4);
  int*   bsum   = (int*)alloc(256 * 4);
  float* stats  = (float*)alloc(256 * 4);
  float* sc     = (float*)alloc(256 * 4);
  float* pool   = (float*)alloc((size_t)N_GRAPHS * 128 * 4);  // 1,024,000 B
  float* cnt    = (float*)alloc((size_t)N_GRAPHS * 4);        // contiguous after pool

  const int NB_SCAN = (N_NODES + 255) / 256;
  const int gemm_blocks = (N_NODES + 63) / 64;
  const int agg_blocks  = (N_NODES + 3) / 4;

  // ---- CSR build (once)
  hipMemsetAsync(degi, 0, (size_t)N_NODES * 4, stream);
  hist_sharded_kernel<<<2048, 256, 0, stream>>>(dst, degi);
  scan_block_kernel<<<NB_SCAN, 256, 0, stream>>>(degi, partial, bsum, invdeg);
  scan_bsum_kernel<<<1, 256, 0, stream>>>(bsum, NB_SCAN);
  scan_add_kernel<<<NB_SCAN + 1, 256, 0, stream>>>(partial, bsum, rowptr, cursor);
  fill_sharded_kernel<<<2048, 256, 0, stream>>>(src, dst, cursor, colidx);

  // ---- weights -> bf16 transposed-concat (+ stats zero)
  wprep_all_kernel<<<(WP0 + 2 * WP1 + 255) / 256, 256, 0, stream>>>(
      Wl0, Wr0, Wl, Wr, WT0, WT1, WT2, stats);

  // ---- layer 0 (Kc = 96): gather-mean + x pack, GEMM, finalize
  layer0_prep_kernel<<<agg_blocks, 256, 0, stream>>>(x, rowptr, colidx, invdeg, A0);
  gemm_mfma_kernel<96, false><<<gemm_blocks, 256, 0, stream>>>(
      A0, nullptr, nullptr, WT0, Pa, stats);
  bn_finalize_kernel<<<1, 128, 0, stream>>>(stats, gamma, beta, sc);

  // ---- layer 1: consume Pa + sc0, produce Pb
  csr_aggregate_bn_kernel<<<agg_blocks, 256, 0, stream>>>(Pa, sc, rowptr, colidx,
                                                          invdeg, agg);
  gemm_mfma_kernel<256, true><<<gemm_blocks, 256, 0, stream>>>(
      agg, Pa, sc, WT1, Pb, stats);
  bn_finalize_kernel<<<1, 128, 0, stream>>>(stats, gamma + 128, beta + 128, sc);

  // ---- layer 2: consume Pb + sc1, produce Pa
  csr_aggregate_bn_kernel<<<agg_blocks, 256, 0, stream>>>(Pb, sc, rowptr, colidx,
                                                          invdeg, agg);
  gemm_mfma_kernel<256, true><<<gemm_blocks, 256, 0, stream>>>(
      agg, Pb, sc, WT2, Pa, stats);
  bn_finalize_kernel<<<1, 128, 0, stream>>>(stats, gamma + 256, beta + 256, sc);

  // ---- global mean pool (final BN fused) + readout
  hipMemsetAsync(pool, 0, (size_t)(N_GRAPHS * 128 * 4 + N_GRAPHS * 4), stream);
  pool_cnt_kernel<<<NB_SCAN, 256, 0, stream>>>(batch, cnt);
  pool_sum_fused_kernel<<<(N_NODES + 63) / 64, 256, 0, stream>>>(Pa, sc, batch, pool);
  readout_kernel<<<N_GRAPHS, 64, 0, stream>>>(pool, cnt, rW1, rb1, rW2, rb2, out);
}

// Round 8
// 393.087 us; speedup vs baseline: 3.4860x; 1.0596x over previous
//
#include <hip/hip_runtime.h>

#define N_NODES 50000
#define N_EDGES 800000
#define N_GRAPHS 2000
#define BN_EPS 1e-5f
#define SHARD_SZ 6250  // N_NODES / 8

typedef unsigned short ushort_t;
typedef unsigned int uint_t;
using bf16x8 = __attribute__((ext_vector_type(8))) short;
using f32x4  = __attribute__((ext_vector_type(4))) float;

__device__ inline float bf_lo(uint_t u) { return __uint_as_float(u << 16); }
__device__ inline float bf_hi(uint_t u) { return __uint_as_float(u & 0xffff0000u); }
__device__ inline ushort_t f2bf(float f) {  // round-to-nearest-even
  uint_t u = __float_as_uint(f);
  return (ushort_t)((u + 0x7fffu + ((u >> 16) & 1u)) >> 16);
}
__device__ inline uint_t pack2(float a, float b) {
  return (uint_t)f2bf(a) | ((uint_t)f2bf(b) << 16);
}

// ================================================================ CSR build
// XCD-sharded histogram/fill (blockIdx&7 ~ XCD round-robin heuristic;
// correctness independent of mapping): each shard owns a contiguous
// 6250-node dst range so its degi/colidx region stays hot in one XCD L2.
__global__ void hist_sharded_kernel(const int* __restrict__ dst,
                                    int* __restrict__ degi) {
  const int shard = blockIdx.x & 7;
  const int lo = shard * SHARD_SZ, hi = lo + SHARD_SZ;
  const int nb = gridDim.x >> 3, blk = blockIdx.x >> 3;
  for (int e = blk * blockDim.x + threadIdx.x; e < N_EDGES;
       e += nb * blockDim.x) {
    int d = dst[e];
    if (d >= lo && d < hi) atomicAdd(&degi[d], 1);
  }
}

__global__ void fill_sharded_kernel(const int* __restrict__ src,
                                    const int* __restrict__ dst,
                                    int* __restrict__ cursor,
                                    ushort_t* __restrict__ col) {
  const int shard = blockIdx.x & 7;
  const int lo = shard * SHARD_SZ, hi = lo + SHARD_SZ;
  const int nb = gridDim.x >> 3, blk = blockIdx.x >> 3;
  for (int e = blk * blockDim.x + threadIdx.x; e < N_EDGES;
       e += nb * blockDim.x) {
    int d = dst[e];
    if (d >= lo && d < hi) {
      int p = atomicAdd(&cursor[d], 1);
      col[p] = (ushort_t)src[e];
    }
  }
}

// exclusive scan step 1 (+ invdeg fused: reads degi anyway)
__global__ void scan_block_kernel(const int* __restrict__ degi,
                                  int* __restrict__ partial,
                                  int* __restrict__ bsum,
                                  float* __restrict__ invdeg) {
  __shared__ int buf[2][256];
  int i = blockIdx.x * 256 + threadIdx.x;
  int v = (i < N_NODES) ? degi[i] : 0;
  buf[0][threadIdx.x] = v;
  __syncthreads();
  int pi = 0;
  for (int off = 1; off < 256; off <<= 1) {
    int nv = buf[pi][threadIdx.x];
    if (threadIdx.x >= off) nv += buf[pi][threadIdx.x - off];
    buf[pi ^ 1][threadIdx.x] = nv;
    pi ^= 1;
    __syncthreads();
  }
  int incl = buf[pi][threadIdx.x];
  if (i < N_NODES) {
    partial[i] = incl - v;
    invdeg[i] = 1.0f / fmaxf((float)v, 1.0f);
  }
  if (threadIdx.x == 255) bsum[blockIdx.x] = incl;
}

__global__ void scan_bsum_kernel(int* __restrict__ bsum, int nb) {
  __shared__ int buf[2][256];
  int v = (threadIdx.x < nb) ? bsum[threadIdx.x] : 0;
  buf[0][threadIdx.x] = v;
  __syncthreads();
  int pi = 0;
  for (int off = 1; off < 256; off <<= 1) {
    int nv = buf[pi][threadIdx.x];
    if (threadIdx.x >= off) nv += buf[pi][threadIdx.x - off];
    buf[pi ^ 1][threadIdx.x] = nv;
    pi ^= 1;
    __syncthreads();
  }
  int incl = buf[pi][threadIdx.x];
  if (threadIdx.x < nb) bsum[threadIdx.x] = incl - v;
}

__global__ void scan_add_kernel(const int* __restrict__ partial,
                                const int* __restrict__ bsum,
                                int* __restrict__ rowptr,
                                int* __restrict__ cursor) {
  int i = blockIdx.x * 256 + threadIdx.x;
  if (i < N_NODES) {
    int r = partial[i] + bsum[blockIdx.x];
    rowptr[i] = r;
    cursor[i] = r;
  } else if (i == N_NODES) {
    rowptr[N_NODES] = N_EDGES;
  }
}

// ================================================================ weight prep
// WT in PANEL-MAJOR layout: ushort index = (k>>5)*4096 + c*32 + (k&31),
// so each 32-K panel is a contiguous 8 KB block (coalesced LDS staging).
// Also zeroes stats for the layer-0 gemm.
#define WP0 (128 * 96)
#define WP1 (128 * 256)
__global__ void wprep_all_kernel(const float* __restrict__ Wl0,
                                 const float* __restrict__ Wr0,
                                 const float* __restrict__ Wl,
                                 const float* __restrict__ Wr,
                                 ushort_t* __restrict__ WT0,
                                 ushort_t* __restrict__ WT1,
                                 ushort_t* __restrict__ WT2,
                                 float* __restrict__ stats) {
  int idx = blockIdx.x * blockDim.x + threadIdx.x;
  if (idx < 256) stats[idx] = 0.f;
  if (idx < WP0) {
    int c = idx / 96, k = idx - c * 96;
    float v = 0.f;
    if (k < 38) v = Wl0[k * 128 + c];
    else if (k < 76) v = Wr0[(k - 38) * 128 + c];
    WT0[(k >> 5) * 4096 + c * 32 + (k & 31)] = f2bf(v);
  } else if (idx < WP0 + 2 * WP1) {
    int i2 = idx - WP0;
    int layer = i2 / WP1;  // 0 or 1
    int j = i2 - layer * WP1;
    int c = j / 256, k = j - c * 256;
    const float* L = Wl + layer * 16384;
    const float* R = Wr + layer * 16384;
    float v = (k < 128) ? L[k * 128 + c] : R[(k - 128) * 128 + c];
    ushort_t* W = layer ? WT2 : WT1;
    W[(k >> 5) * 4096 + c * 32 + (k & 31)] = f2bf(v);
  }
}

// ================================================================ layer-0 prep
// one wave per node: lanes<38 gather-mean x into A0 cols 0..37;
// lanes 0..57 pack x into cols 38..75, zeros into 76..95.
__global__ __launch_bounds__(256) void layer0_prep_kernel(
    const float* __restrict__ x, const int* __restrict__ rowptr,
    const ushort_t* __restrict__ col, const float* __restrict__ invdeg,
    ushort_t* __restrict__ A0) {
  int node = blockIdx.x * 4 + (threadIdx.x >> 6);
  if (node >= N_NODES) return;
  int lane = threadIdx.x & 63;
  int beg = rowptr[node], end = rowptr[node + 1];
  if (lane < 38) {
    float acc = 0.f;
    int e = beg;
    for (; e + 3 < end; e += 4) {
      int s0 = col[e], s1 = col[e + 1], s2 = col[e + 2], s3 = col[e + 3];
      acc += (x[(size_t)s0 * 38 + lane] + x[(size_t)s1 * 38 + lane]) +
             (x[(size_t)s2 * 38 + lane] + x[(size_t)s3 * 38 + lane]);
    }
    for (; e < end; e++) acc += x[(size_t)col[e] * 38 + lane];
    A0[(size_t)node * 96 + lane] = f2bf(acc * invdeg[node]);
  }
  int c = 38 + lane;
  if (c < 96) {
    float v = (c < 76) ? x[(size_t)node * 38 + (c - 38)] : 0.f;
    A0[(size_t)node * 96 + c] = f2bf(v);
  }
}

// ================================================================ aggregate + BN
// agg[node][0:128] = invdeg * sum_{src} relu(P[src]*scale + shift)
// 2 nodes per wave: 32 lanes x uint2 (4 bf16 cols each) -> half the gather
// instructions per edge, 2 edge streams in flight per wave.
__global__ __launch_bounds__(256) void csr_aggregate_bn_kernel(
    const ushort_t* __restrict__ Pin, const float* __restrict__ sc,
    const int* __restrict__ rowptr, const ushort_t* __restrict__ col,
    const float* __restrict__ invdeg, ushort_t* __restrict__ agg) {
  int node = blockIdx.x * 8 + (threadIdx.x >> 5);
  if (node >= N_NODES) return;
  int hl = threadIdx.x & 31;
  const uint2* Pu = (const uint2*)Pin;  // row stride 32 uint2s
  int c0 = 4 * hl;
  float s0 = sc[c0], s1 = sc[c0 + 1], s2 = sc[c0 + 2], s3 = sc[c0 + 3];
  float b0 = sc[128 + c0], b1 = sc[128 + c0 + 1];
  float b2 = sc[128 + c0 + 2], b3 = sc[128 + c0 + 3];
  int beg = rowptr[node], end = rowptr[node + 1];
  float a0 = 0.f, a1 = 0.f, a2 = 0.f, a3 = 0.f;
  int e = beg;
  for (; e + 3 < end; e += 4) {
    uint2 u0 = Pu[(size_t)col[e] * 32 + hl];
    uint2 u1 = Pu[(size_t)col[e + 1] * 32 + hl];
    uint2 u2 = Pu[(size_t)col[e + 2] * 32 + hl];
    uint2 u3 = Pu[(size_t)col[e + 3] * 32 + hl];
    a0 += (fmaxf(bf_lo(u0.x) * s0 + b0, 0.f) + fmaxf(bf_lo(u1.x) * s0 + b0, 0.f)) +
          (fmaxf(bf_lo(u2.x) * s0 + b0, 0.f) + fmaxf(bf_lo(u3.x) * s0 + b0, 0.f));
    a1 += (fmaxf(bf_hi(u0.x) * s1 + b1, 0.f) + fmaxf(bf_hi(u1.x) * s1 + b1, 0.f)) +
          (fmaxf(bf_hi(u2.x) * s1 + b1, 0.f) + fmaxf(bf_hi(u3.x) * s1 + b1, 0.f));
    a2 += (fmaxf(bf_lo(u0.y) * s2 + b2, 0.f) + fmaxf(bf_lo(u1.y) * s2 + b2, 0.f)) +
          (fmaxf(bf_lo(u2.y) * s2 + b2, 0.f) + fmaxf(bf_lo(u3.y) * s2 + b2, 0.f));
    a3 += (fmaxf(bf_hi(u0.y) * s3 + b3, 0.f) + fmaxf(bf_hi(u1.y) * s3 + b3, 0.f)) +
          (fmaxf(bf_hi(u2.y) * s3 + b3, 0.f) + fmaxf(bf_hi(u3.y) * s3 + b3, 0.f));
  }
  for (; e < end; e++) {
    uint2 u = Pu[(size_t)col[e] * 32 + hl];
    a0 += fmaxf(bf_lo(u.x) * s0 + b0, 0.f);
    a1 += fmaxf(bf_hi(u.x) * s1 + b1, 0.f);
    a2 += fmaxf(bf_lo(u.y) * s2 + b2, 0.f);
    a3 += fmaxf(bf_hi(u.y) * s3 + b3, 0.f);
  }
  float inv = invdeg[node];
  uint2 o;
  o.x = pack2(a0 * inv, a1 * inv);
  o.y = pack2(a2 * inv, a3 * inv);
  ((uint2*)agg)[(size_t)node * 32 + hl] = o;
}

// ================================================================ MFMA GEMM + BN stats
// P[row][128] (bf16 pre-BN) = Acat[row][0:Kc] @ Wcat, where for BN=true
// Acat = [ agg[row][0:128] | relu(Pin[row]*scale+shift) ] (BN on the fly).
// B staged per 32-K panel (8 KB) -> ~16 KB LDS -> ~6 blocks/CU occupancy.
template <int Kc, bool BN>
__global__ __launch_bounds__(256, 6) void gemm_mfma_kernel(
    const ushort_t* __restrict__ A, const ushort_t* __restrict__ Pin,
    const float* __restrict__ sc, const ushort_t* __restrict__ WT,
    ushort_t* __restrict__ P, float* __restrict__ stats) {
  __shared__ __align__(16) ushort_t sA[64 * 40];
  __shared__ __align__(16) ushort_t sB[128 * 40];
  __shared__ float ssc[256];
  const int tid = threadIdx.x;
  const int row0 = blockIdx.x * 64;
  if (BN) ssc[tid] = sc[tid];  // covered by first __syncthreads in loop

  const int w = tid >> 6;
  const int l = tid & 63;
  const int m = l & 15;
  const int quad = l >> 4;
  f32x4 acc[8];
#pragma unroll
  for (int ct = 0; ct < 8; ct++) acc[ct] = (f32x4){0.f, 0.f, 0.f, 0.f};

  for (int kk = 0; kk < Kc; kk += 32) {
    __syncthreads();
    // ---- stage B panel (contiguous 8 KB, fully coalesced)
    {
      const uint4* wp = (const uint4*)(WT + (kk >> 5) * 4096);
      uint4 v0 = wp[tid];
      uint4 v1 = wp[tid + 256];
      *((uint4*)&sB[(tid >> 2) * 40 + (tid & 3) * 8]) = v0;
      int t2 = tid + 256;
      *((uint4*)&sB[(t2 >> 2) * 40 + (t2 & 3) * 8]) = v1;
    }
    // ---- stage A panel
    {
      int r = tid >> 2, c = tid & 3;
      int row = row0 + r;
      uint4 v = make_uint4(0, 0, 0, 0);
      if (row < N_NODES) {
        if (!BN) {
          v = ((const uint4*)(A + (size_t)row * Kc))[(kk >> 3) + c];
        } else if (kk < 128) {
          v = ((const uint4*)(A + (size_t)row * 128))[(kk >> 3) + c];
        } else {
          int pcol = kk - 128 + c * 8;
          uint4 u = *(const uint4*)(Pin + (size_t)row * 128 + pcol);
          uint_t in[4] = {u.x, u.y, u.z, u.w};
          uint_t ov[4];
#pragma unroll
          for (int p = 0; p < 4; p++) {
            int cc = pcol + 2 * p;
            float f0 = fmaxf(bf_lo(in[p]) * ssc[cc] + ssc[128 + cc], 0.f);
            float f1 = fmaxf(bf_hi(in[p]) * ssc[cc + 1] + ssc[128 + cc + 1], 0.f);
            ov[p] = pack2(f0, f1);
          }
          v = make_uint4(ov[0], ov[1], ov[2], ov[3]);
        }
      }
      *((uint4*)&sA[r * 40 + c * 8]) = v;
    }
    __syncthreads();
    bf16x8 a = *(const bf16x8*)&sA[(w * 16 + m) * 40 + quad * 8];
#pragma unroll
    for (int ct = 0; ct < 8; ct++) {
      bf16x8 b = *(const bf16x8*)&sB[(ct * 16 + m) * 40 + quad * 8];
      acc[ct] = __builtin_amdgcn_mfma_f32_16x16x32_bf16(a, b, acc[ct], 0, 0, 0);
    }
  }

  // store pre-BN result (D layout: row = quad*4+v, col = ct*16+m)
#pragma unroll
  for (int ct = 0; ct < 8; ct++) {
#pragma unroll
    for (int v = 0; v < 4; v++) {
      int row = row0 + w * 16 + quad * 4 + v;
      if (row < N_NODES) P[(size_t)row * 128 + ct * 16 + m] = f2bf(acc[ct][v]);
    }
  }

  // BN stats epilogue (pad rows contribute exact zeros)
  float* red = (float*)sA;
  __syncthreads();
#pragma unroll
  for (int ct = 0; ct < 8; ct++) {
    float s = 0.f, q = 0.f;
#pragma unroll
    for (int v = 0; v < 4; v++) {
      s += acc[ct][v];
      q += acc[ct][v] * acc[ct][v];
    }
    float t;
    t = __shfl_xor(s, 16); s += t;
    t = __shfl_xor(s, 32); s += t;
    t = __shfl_xor(q, 16); q += t;
    t = __shfl_xor(q, 32); q += t;
    if (l < 16) {
      red[w * 256 + ct * 16 + l] = s;
      red[w * 256 + 128 + ct * 16 + l] = q;
    }
  }
  __syncthreads();
  if (tid < 128) {
    float s = 0.f, q = 0.f;
#pragma unroll
    for (int wv = 0; wv < 4; wv++) {
      s += red[wv * 256 + tid];
      q += red[wv * 256 + 128 + tid];
    }
    atomicAdd(&stats[tid], s);
    atomicAdd(&stats[128 + tid], q);
  }
}

// ================================================================ batchnorm finalize
// reads stats -> sc, then zeroes stats for the next layer's gemm.
__global__ void bn_finalize_kernel(float* __restrict__ stats,
                                   const float* __restrict__ gamma,
                                   const float* __restrict__ beta,
                                   float* __restrict__ sc) {
  int c = threadIdx.x;
  const float invN = 1.0f / (float)N_NODES;
  float mean = stats[c] * invN;
  float var = stats[128 + c] * invN - mean * mean;
  float scale = gamma[c] * rsqrtf(var + BN_EPS);
  sc[c] = scale;
  sc[128 + c] = beta[c] - mean * scale;
  stats[c] = 0.f;
  stats[128 + c] = 0.f;
}

// ================================================================ pooling
// fused: pool += relu(scale*P + shift)   (final BN applied inline;
// batch sorted: run-accumulate, atomic only at graph change)
__global__ void pool_sum_fused_kernel(const ushort_t* __restrict__ P,
                                      const float* __restrict__ sc,
                                      const int* __restrict__ batch,
                                      float* __restrict__ pool) {
  const int ROWS = 64;
  int c2 = threadIdx.x & 63;
  int half = threadIdx.x >> 6;
  int r0 = blockIdx.x * ROWS;
  int rend = min(r0 + ROWS, N_NODES);
  const uint_t* Pu = (const uint_t*)P;
  float s0 = sc[2 * c2], s1 = sc[2 * c2 + 1];
  float b0 = sc[128 + 2 * c2], b1 = sc[128 + 2 * c2 + 1];
  float ax = 0.f, ay = 0.f;
  int curg = -1;
  for (int r = r0 + half; r < rend; r += 4) {
    int g = batch[r];
    if (g != curg) {
      if (curg >= 0) {
        atomicAdd(&pool[(size_t)curg * 128 + 2 * c2], ax);
        atomicAdd(&pool[(size_t)curg * 128 + 2 * c2 + 1], ay);
      }
      ax = ay = 0.f;
      curg = g;
    }
    uint_t u = Pu[(size_t)r * 64 + c2];
    ax += fmaxf(bf_lo(u) * s0 + b0, 0.f);
    ay += fmaxf(bf_hi(u) * s1 + b1, 0.f);
  }
  if (curg >= 0) {
    atomicAdd(&pool[(size_t)curg * 128 + 2 * c2], ax);
    atomicAdd(&pool[(size_t)curg * 128 + 2 * c2 + 1], ay);
  }
}

// ================================================================ readout
// graph node count via binary search on sorted batch (no pool_cnt pass).
__global__ void readout_kernel(const float* __restrict__ pool,
                               const int* __restrict__ batch,
                               const float* __restrict__ rW1,
                               const float* __restrict__ rb1,
                               const float* __restrict__ rW2,
                               const float* __restrict__ rb2,
                               float* __restrict__ out) {
  int g = blockIdx.x;
  int j = threadIdx.x;  // 0..63
  int lo = 0, hi = N_NODES;
  while (lo < hi) { int mid = (lo + hi) >> 1; if (batch[mid] < g) lo = mid + 1; else hi = mid; }
  int lb = lo;
  hi = N_NODES;
  while (lo < hi) { int mid = (lo + hi) >> 1; if (batch[mid] < g + 1) lo = mid + 1; else hi = mid; }
  float invc = 1.0f / fmaxf((float)(lo - lb), 1.0f);
  float acc = rb1[j];
  for (int k = 0; k < 128; k++)
    acc += pool[(size_t)g * 128 + k] * invc * rW1[k * 64 + j];
  acc = fmaxf(acc, 0.f) * rW2[j];
#pragma unroll
  for (int off = 32; off > 0; off >>= 1) acc += __shfl_down(acc, off);
  if (j == 0) out[g] = acc + rb2[0];
}

// ================================================================ launch
extern "C" void kernel_launch(void* const* d_in, const int* in_sizes, int n_in,
                              void* d_out, int out_size, void* d_ws, size_t ws_size,
                              hipStream_t stream) {
  const float* x     = (const float*)d_in[0];
  const int*   ei    = (const int*)d_in[1];
  const int*   src   = ei;
  const int*   dst   = ei + N_EDGES;
  const int*   batch = (const int*)d_in[2];
  const float* Wl0   = (const float*)d_in[3];
  const float* Wr0   = (const float*)d_in[4];
  const float* Wl    = (const float*)d_in[6];
  const float* Wr    = (const float*)d_in[7];
  const float* gamma = (const float*)d_in[9];
  const float* beta  = (const float*)d_in[10];
  const float* rW1   = (const float*)d_in[11];
  const float* rb1   = (const float*)d_in[12];
  const float* rW2   = (const float*)d_in[13];
  const float* rb2   = (const float*)d_in[14];
  float* out = (float*)d_out;

  char* ws = (char*)d_ws;
  size_t off = 0;
  auto alloc = [&](size_t bytes) -> void* {
    void* p = ws + off;
    off = (off + bytes + 255) & ~(size_t)255;
    return p;
  };
  ushort_t* A0    = (ushort_t*)alloc((size_t)N_NODES * 96 * 2);
  ushort_t* agg   = (ushort_t*)alloc((size_t)N_NODES * 128 * 2);
  ushort_t* Pa    = (ushort_t*)alloc((size_t)N_NODES * 128 * 2);
  ushort_t* Pb    = (ushort_t*)alloc((size_t)N_NODES * 128 * 2);
  ushort_t* WT0   = (ushort_t*)alloc((size_t)128 * 96 * 2);
  ushort_t* WT1   = (ushort_t*)alloc((size_t)128 * 256 * 2);
  ushort_t* WT2   = (ushort_t*)alloc((size_t)128 * 256 * 2);
  float* invdeg = (float*)alloc((size_t)N_NODES * 4);
  int*   degi   = (int*)alloc((size_t)N_NODES * 4);
  int*   rowptr = (int*)alloc((size_t)(N_NODES + 1) * 4);
  int*   cursor = (int*)alloc((size_t)N_NODES * 4);
  ushort_t* colidx = (ushort_t*)alloc((size_t)N_EDGES * 2);
  int*   partial= (int*)alloc((size_t)N_NODES * 4);
  int*   bsum   = (int*)alloc(256 * 4);
  float* stats  = (float*)alloc(256 * 4);
  float* sc     = (float*)alloc(256 * 4);
  float* pool   = (float*)alloc((size_t)N_GRAPHS * 128 * 4);

  const int NB_SCAN = (N_NODES + 255) / 256;
  const int gemm_blocks = (N_NODES + 63) / 64;
  const int agg_blocks  = (N_NODES + 7) / 8;
  const int l0_blocks   = (N_NODES + 3) / 4;

  // ---- CSR build (once)
  hipMemsetAsync(degi, 0, (size_t)N_NODES * 4, stream);
  hist_sharded_kernel<<<2048, 256, 0, stream>>>(dst, degi);
  scan_block_kernel<<<NB_SCAN, 256, 0, stream>>>(degi, partial, bsum, invdeg);
  scan_bsum_kernel<<<1, 256, 0, stream>>>(bsum, NB_SCAN);
  scan_add_kernel<<<NB_SCAN + 1, 256, 0, stream>>>(partial, bsum, rowptr, cursor);
  fill_sharded_kernel<<<2048, 256, 0, stream>>>(src, dst, cursor, colidx);

  // ---- weights -> bf16 panel-major transposed-concat (+ stats zero)
  wprep_all_kernel<<<(WP0 + 2 * WP1 + 255) / 256, 256, 0, stream>>>(
      Wl0, Wr0, Wl, Wr, WT0, WT1, WT2, stats);

  // ---- layer 0 (Kc = 96)
  layer0_prep_kernel<<<l0_blocks, 256, 0, stream>>>(x, rowptr, colidx, invdeg, A0);
  gemm_mfma_kernel<96, false><<<gemm_blocks, 256, 0, stream>>>(
      A0, nullptr, nullptr, WT0, Pa, stats);
  bn_finalize_kernel<<<1, 128, 0, stream>>>(stats, gamma, beta, sc);

  // ---- layer 1: consume Pa + sc0, produce Pb
  csr_aggregate_bn_kernel<<<agg_blocks, 256, 0, stream>>>(Pa, sc, rowptr, colidx,
                                                          invdeg, agg);
  gemm_mfma_kernel<256, true><<<gemm_blocks, 256, 0, stream>>>(
      agg, Pa, sc, WT1, Pb, stats);
  bn_finalize_kernel<<<1, 128, 0, stream>>>(stats, gamma + 128, beta + 128, sc);

  // ---- layer 2: consume Pb + sc1, produce Pa
  csr_aggregate_bn_kernel<<<agg_blocks, 256, 0, stream>>>(Pb, sc, rowptr, colidx,
                                                          invdeg, agg);
  gemm_mfma_kernel<256, true><<<gemm_blocks, 256, 0, stream>>>(
      agg, Pb, sc, WT2, Pa, stats);
  bn_finalize_kernel<<<1, 128, 0, stream>>>(stats, gamma + 256, beta + 256, sc);

  // ---- global mean pool (final BN fused) + readout
  hipMemsetAsync(pool, 0, (size_t)N_GRAPHS * 128 * 4, stream);
  pool_sum_fused_kernel<<<(N_NODES + 63) / 64, 256, 0, stream>>>(Pa, sc, batch, pool);
  readout_kernel<<<N_GRAPHS, 64, 0, stream>>>(pool, batch, rW1, rb1, rW2, rb2, out);
}

// Round 10
// 384.251 us; speedup vs baseline: 3.5662x; 1.0230x over previous
//
#include <hip/hip_runtime.h>

#define N_NODES 50000
#define N_EDGES 800000
#define N_GRAPHS 2000
#define BN_EPS 1e-5f
#define SHARD_SZ 6250  // N_NODES / 8

typedef unsigned short ushort_t;
typedef unsigned int uint_t;
using bf16x8 = __attribute__((ext_vector_type(8))) short;
using f32x4  = __attribute__((ext_vector_type(4))) float;

__device__ inline float bf_lo(uint_t u) { return __uint_as_float(u << 16); }
__device__ inline float bf_hi(uint_t u) { return __uint_as_float(u & 0xffff0000u); }
__device__ inline ushort_t f2bf(float f) {  // round-to-nearest-even
  uint_t u = __float_as_uint(f);
  return (ushort_t)((u + 0x7fffu + ((u >> 16) & 1u)) >> 16);
}
__device__ inline uint_t pack2(float a, float b) {
  return (uint_t)f2bf(a) | ((uint_t)f2bf(b) << 16);
}

// ================================================================ CSR build
// XCD-sharded histogram/fill (blockIdx&7 ~ XCD round-robin heuristic;
// correctness independent of mapping): each shard owns a contiguous
// 6250-node dst range so its degi/colidx region stays hot in one XCD L2.
__global__ void hist_sharded_kernel(const int* __restrict__ dst,
                                    int* __restrict__ degi) {
  const int shard = blockIdx.x & 7;
  const int lo = shard * SHARD_SZ, hi = lo + SHARD_SZ;
  const int nb = gridDim.x >> 3, blk = blockIdx.x >> 3;
  for (int e = blk * blockDim.x + threadIdx.x; e < N_EDGES;
       e += nb * blockDim.x) {
    int d = dst[e];
    if (d >= lo && d < hi) atomicAdd(&degi[d], 1);
  }
}

__global__ void fill_sharded_kernel(const int* __restrict__ src,
                                    const int* __restrict__ dst,
                                    int* __restrict__ cursor,
                                    ushort_t* __restrict__ col) {
  const int shard = blockIdx.x & 7;
  const int lo = shard * SHARD_SZ, hi = lo + SHARD_SZ;
  const int nb = gridDim.x >> 3, blk = blockIdx.x >> 3;
  for (int e = blk * blockDim.x + threadIdx.x; e < N_EDGES;
       e += nb * blockDim.x) {
    int d = dst[e];
    if (d >= lo && d < hi) {
      int p = atomicAdd(&cursor[d], 1);
      col[p] = (ushort_t)src[e];
    }
  }
}

// exclusive scan step 1 (+ invdeg fused: reads degi anyway)
__global__ void scan_block_kernel(const int* __restrict__ degi,
                                  int* __restrict__ partial,
                                  int* __restrict__ bsum,
                                  float* __restrict__ invdeg) {
  __shared__ int buf[2][256];
  int i = blockIdx.x * 256 + threadIdx.x;
  int v = (i < N_NODES) ? degi[i] : 0;
  buf[0][threadIdx.x] = v;
  __syncthreads();
  int pi = 0;
  for (int off = 1; off < 256; off <<= 1) {
    int nv = buf[pi][threadIdx.x];
    if (threadIdx.x >= off) nv += buf[pi][threadIdx.x - off];
    buf[pi ^ 1][threadIdx.x] = nv;
    pi ^= 1;
    __syncthreads();
  }
  int incl = buf[pi][threadIdx.x];
  if (i < N_NODES) {
    partial[i] = incl - v;
    invdeg[i] = 1.0f / fmaxf((float)v, 1.0f);
  }
  if (threadIdx.x == 255) bsum[blockIdx.x] = incl;
}

// step 2 fused: every block redundantly scans bsum (196 ints) in LDS,
// then applies its offset. Saves the separate scan_bsum launch.
__global__ void scan_add_fused_kernel(const int* __restrict__ partial,
                                      const int* __restrict__ bsum,
                                      int* __restrict__ rowptr,
                                      int* __restrict__ cursor, int nb) {
  __shared__ int buf[2][256];
  __shared__ int sx[256];
  int t = threadIdx.x;
  int v = (t < nb) ? bsum[t] : 0;
  buf[0][t] = v;
  __syncthreads();
  int pi = 0;
  for (int off = 1; off < 256; off <<= 1) {
    int nv = buf[pi][t];
    if (t >= off) nv += buf[pi][t - off];
    buf[pi ^ 1][t] = nv;
    pi ^= 1;
    __syncthreads();
  }
  sx[t] = buf[pi][t] - v;  // exclusive block offset
  __syncthreads();
  int add = sx[blockIdx.x];
  int i = blockIdx.x * 256 + t;
  if (i < N_NODES) {
    int r = partial[i] + add;
    rowptr[i] = r;
    cursor[i] = r;
  } else if (i == N_NODES) {
    rowptr[N_NODES] = N_EDGES;
  }
}

// ================================================================ weight prep
// WT in PANEL-MAJOR layout: ushort index = (k>>5)*4096 + c*32 + (k&31),
// so each 32-K panel is a contiguous 8 KB block (coalesced LDS staging).
// Also zeroes stats for the layer-0 gemm.
#define WP0 (128 * 96)
#define WP1 (128 * 256)
__global__ void wprep_all_kernel(const float* __restrict__ Wl0,
                                 const float* __restrict__ Wr0,
                                 const float* __restrict__ Wl,
                                 const float* __restrict__ Wr,
                                 ushort_t* __restrict__ WT0,
                                 ushort_t* __restrict__ WT1,
                                 ushort_t* __restrict__ WT2,
                                 float* __restrict__ stats) {
  int idx = blockIdx.x * blockDim.x + threadIdx.x;
  if (idx < 256) stats[idx] = 0.f;
  if (idx < WP0) {
    int c = idx / 96, k = idx - c * 96;
    float v = 0.f;
    if (k < 38) v = Wl0[k * 128 + c];
    else if (k < 76) v = Wr0[(k - 38) * 128 + c];
    WT0[(k >> 5) * 4096 + c * 32 + (k & 31)] = f2bf(v);
  } else if (idx < WP0 + 2 * WP1) {
    int i2 = idx - WP0;
    int layer = i2 / WP1;  // 0 or 1
    int j = i2 - layer * WP1;
    int c = j / 256, k = j - c * 256;
    const float* L = Wl + layer * 16384;
    const float* R = Wr + layer * 16384;
    float v = (k < 128) ? L[k * 128 + c] : R[(k - 128) * 128 + c];
    ushort_t* W = layer ? WT2 : WT1;
    W[(k >> 5) * 4096 + c * 32 + (k & 31)] = f2bf(v);
  }
}

// ================================================================ x -> bf16 pack
// xb[node][40] bf16 (cols 0..37 = x, 38..39 = 0); indexed as uint[20]/row.
__global__ void xb_cvt_kernel(const float* __restrict__ x,
                              uint_t* __restrict__ xb) {
  int idx = blockIdx.x * blockDim.x + threadIdx.x;
  if (idx >= N_NODES * 20) return;
  int row = idx / 20, c2 = (idx - row * 20) * 2;
  float v0 = (c2 < 38) ? x[row * 38 + c2] : 0.f;
  float v1 = (c2 + 1 < 38) ? x[row * 38 + c2 + 1] : 0.f;
  xb[idx] = pack2(v0, v1);
}

// ================================================================ layer-0 prep
// one wave per node, bf16 gather (80B/row):
// lanes 0..18 gather-mean xb col-pairs -> A0 uints 0..18 (cols 0..37);
// lanes 19..37 copy xb uints 0..18 -> A0 uints 19..37 (cols 38..75);
// lanes 38..47 zero A0 uints 38..47 (cols 76..95).
__global__ __launch_bounds__(256) void layer0_prep_kernel(
    const uint_t* __restrict__ xb, const int* __restrict__ rowptr,
    const ushort_t* __restrict__ col, const float* __restrict__ invdeg,
    uint_t* __restrict__ A0u) {
  int node = blockIdx.x * 4 + (threadIdx.x >> 6);
  if (node >= N_NODES) return;
  int lane = threadIdx.x & 63;
  int beg = rowptr[node], end = rowptr[node + 1];
  if (lane < 19) {
    float a0 = 0.f, a1 = 0.f;
    int e = beg;
    for (; e + 3 < end; e += 4) {
      uint_t u0 = xb[(size_t)col[e] * 20 + lane];
      uint_t u1 = xb[(size_t)col[e + 1] * 20 + lane];
      uint_t u2 = xb[(size_t)col[e + 2] * 20 + lane];
      uint_t u3 = xb[(size_t)col[e + 3] * 20 + lane];
      a0 += (bf_lo(u0) + bf_lo(u1)) + (bf_lo(u2) + bf_lo(u3));
      a1 += (bf_hi(u0) + bf_hi(u1)) + (bf_hi(u2) + bf_hi(u3));
    }
    for (; e < end; e++) {
      uint_t u = xb[(size_t)col[e] * 20 + lane];
      a0 += bf_lo(u);
      a1 += bf_hi(u);
    }
    float inv = invdeg[node];
    A0u[(size_t)node * 48 + lane] = pack2(a0 * inv, a1 * inv);
  } else if (lane < 38) {
    A0u[(size_t)node * 48 + lane] = xb[(size_t)node * 20 + (lane - 19)];
  } else if (lane < 48) {
    A0u[(size_t)node * 48 + lane] = 0u;
  }
}

// ================================================================ aggregate + BN
// agg[node][0:128] = invdeg * sum_{src} relu(P[src]*scale + shift)
// 4 nodes per wave: 16 lanes x uint4 (8 bf16 cols each), 4-deep unroll.
// P row = 128 bf16 = 16 uint4 (stride 16!).
__global__ __launch_bounds__(256) void csr_aggregate_bn_kernel(
    const ushort_t* __restrict__ Pin, const float* __restrict__ sc,
    const int* __restrict__ rowptr, const ushort_t* __restrict__ col,
    const float* __restrict__ invdeg, ushort_t* __restrict__ agg) {
  int node = blockIdx.x * 16 + (threadIdx.x >> 4);
  if (node >= N_NODES) return;
  int h = threadIdx.x & 15;
  const uint4* Pu = (const uint4*)Pin;  // row stride 16 uint4s
  int c0 = h * 8;
  float s[8], b[8];
#pragma unroll
  for (int j = 0; j < 8; j++) {
    s[j] = sc[c0 + j];
    b[j] = sc[128 + c0 + j];
  }
  int beg = rowptr[node], end = rowptr[node + 1];
  float a[8];
#pragma unroll
  for (int j = 0; j < 8; j++) a[j] = 0.f;
  int e = beg;
  for (; e + 3 < end; e += 4) {
    uint4 u0 = Pu[(size_t)col[e] * 16 + h];
    uint4 u1 = Pu[(size_t)col[e + 1] * 16 + h];
    uint4 u2 = Pu[(size_t)col[e + 2] * 16 + h];
    uint4 u3 = Pu[(size_t)col[e + 3] * 16 + h];
    uint_t w0[4] = {u0.x, u0.y, u0.z, u0.w};
    uint_t w1[4] = {u1.x, u1.y, u1.z, u1.w};
    uint_t w2[4] = {u2.x, u2.y, u2.z, u2.w};
    uint_t w3[4] = {u3.x, u3.y, u3.z, u3.w};
#pragma unroll
    for (int p = 0; p < 4; p++) {
      a[2 * p]     += (fmaxf(bf_lo(w0[p]) * s[2 * p] + b[2 * p], 0.f) +
                       fmaxf(bf_lo(w1[p]) * s[2 * p] + b[2 * p], 0.f)) +
                      (fmaxf(bf_lo(w2[p]) * s[2 * p] + b[2 * p], 0.f) +
                       fmaxf(bf_lo(w3[p]) * s[2 * p] + b[2 * p], 0.f));
      a[2 * p + 1] += (fmaxf(bf_hi(w0[p]) * s[2 * p + 1] + b[2 * p + 1], 0.f) +
                       fmaxf(bf_hi(w1[p]) * s[2 * p + 1] + b[2 * p + 1], 0.f)) +
                      (fmaxf(bf_hi(w2[p]) * s[2 * p + 1] + b[2 * p + 1], 0.f) +
                       fmaxf(bf_hi(w3[p]) * s[2 * p + 1] + b[2 * p + 1], 0.f));
    }
  }
  for (; e < end; e++) {
    uint4 u = Pu[(size_t)col[e] * 16 + h];
    uint_t w[4] = {u.x, u.y, u.z, u.w};
#pragma unroll
    for (int p = 0; p < 4; p++) {
      a[2 * p]     += fmaxf(bf_lo(w[p]) * s[2 * p] + b[2 * p], 0.f);
      a[2 * p + 1] += fmaxf(bf_hi(w[p]) * s[2 * p + 1] + b[2 * p + 1], 0.f);
    }
  }
  float inv = invdeg[node];
  uint4 o;
  o.x = pack2(a[0] * inv, a[1] * inv);
  o.y = pack2(a[2] * inv, a[3] * inv);
  o.z = pack2(a[4] * inv, a[5] * inv);
  o.w = pack2(a[6] * inv, a[7] * inv);
  ((uint4*)agg)[(size_t)node * 16 + h] = o;
}

// ================================================================ MFMA GEMM + BN stats
// P[row][128] (bf16 pre-BN) = Acat[row][0:Kc] @ Wcat, where for BN=true
// Acat = [ agg[row][0:128] | relu(Pin[row]*scale+shift) ] (BN on the fly).
// B staged per 32-K panel (8 KB) -> ~16 KB LDS -> ~6 blocks/CU occupancy.
template <int Kc, bool BN>
__global__ __launch_bounds__(256, 6) void gemm_mfma_kernel(
    const ushort_t* __restrict__ A, const ushort_t* __restrict__ Pin,
    const float* __restrict__ sc, const ushort_t* __restrict__ WT,
    ushort_t* __restrict__ P, float* __restrict__ stats) {
  __shared__ __align__(16) ushort_t sA[64 * 40];
  __shared__ __align__(16) ushort_t sB[128 * 40];
  __shared__ float ssc[256];
  const int tid = threadIdx.x;
  const int row0 = blockIdx.x * 64;
  if (BN) ssc[tid] = sc[tid];  // covered by first __syncthreads in loop

  const int w = tid >> 6;
  const int l = tid & 63;
  const int m = l & 15;
  const int quad = l >> 4;
  f32x4 acc[8];
#pragma unroll
  for (int ct = 0; ct < 8; ct++) acc[ct] = (f32x4){0.f, 0.f, 0.f, 0.f};

  for (int kk = 0; kk < Kc; kk += 32) {
    __syncthreads();
    // ---- stage B panel (contiguous 8 KB, fully coalesced)
    {
      const uint4* wp = (const uint4*)(WT + (kk >> 5) * 4096);
      uint4 v0 = wp[tid];
      uint4 v1 = wp[tid + 256];
      *((uint4*)&sB[(tid >> 2) * 40 + (tid & 3) * 8]) = v0;
      int t2 = tid + 256;
      *((uint4*)&sB[(t2 >> 2) * 40 + (t2 & 3) * 8]) = v1;
    }
    // ---- stage A panel
    {
      int r = tid >> 2, c = tid & 3;
      int row = row0 + r;
      uint4 v = make_uint4(0, 0, 0, 0);
      if (row < N_NODES) {
        if (!BN) {
          v = ((const uint4*)(A + (size_t)row * Kc))[(kk >> 3) + c];
        } else if (kk < 128) {
          v = ((const uint4*)(A + (size_t)row * 128))[(kk >> 3) + c];
        } else {
          int pcol = kk - 128 + c * 8;
          uint4 u = *(const uint4*)(Pin + (size_t)row * 128 + pcol);
          uint_t in[4] = {u.x, u.y, u.z, u.w};
          uint_t ov[4];
#pragma unroll
          for (int p = 0; p < 4; p++) {
            int cc = pcol + 2 * p;
            float f0 = fmaxf(bf_lo(in[p]) * ssc[cc] + ssc[128 + cc], 0.f);
            float f1 = fmaxf(bf_hi(in[p]) * ssc[cc + 1] + ssc[128 + cc + 1], 0.f);
            ov[p] = pack2(f0, f1);
          }
          v = make_uint4(ov[0], ov[1], ov[2], ov[3]);
        }
      }
      *((uint4*)&sA[r * 40 + c * 8]) = v;
    }
    __syncthreads();
    bf16x8 a = *(const bf16x8*)&sA[(w * 16 + m) * 40 + quad * 8];
#pragma unroll
    for (int ct = 0; ct < 8; ct++) {
      bf16x8 b = *(const bf16x8*)&sB[(ct * 16 + m) * 40 + quad * 8];
      acc[ct] = __builtin_amdgcn_mfma_f32_16x16x32_bf16(a, b, acc[ct], 0, 0, 0);
    }
  }

  // store pre-BN result (D layout: row = quad*4+v, col = ct*16+m)
#pragma unroll
  for (int ct = 0; ct < 8; ct++) {
#pragma unroll
    for (int v = 0; v < 4; v++) {
      int row = row0 + w * 16 + quad * 4 + v;
      if (row < N_NODES) P[(size_t)row * 128 + ct * 16 + m] = f2bf(acc[ct][v]);
    }
  }

  // BN stats epilogue (pad rows contribute exact zeros)
  float* red = (float*)sA;
  __syncthreads();
#pragma unroll
  for (int ct = 0; ct < 8; ct++) {
    float s = 0.f, q = 0.f;
#pragma unroll
    for (int v = 0; v < 4; v++) {
      s += acc[ct][v];
      q += acc[ct][v] * acc[ct][v];
    }
    float t;
    t = __shfl_xor(s, 16); s += t;
    t = __shfl_xor(s, 32); s += t;
    t = __shfl_xor(q, 16); q += t;
    t = __shfl_xor(q, 32); q += t;
    if (l < 16) {
      red[w * 256 + ct * 16 + l] = s;
      red[w * 256 + 128 + ct * 16 + l] = q;
    }
  }
  __syncthreads();
  if (tid < 128) {
    float s = 0.f, q = 0.f;
#pragma unroll
    for (int wv = 0; wv < 4; wv++) {
      s += red[wv * 256 + tid];
      q += red[wv * 256 + 128 + tid];
    }
    atomicAdd(&stats[tid], s);
    atomicAdd(&stats[128 + tid], q);
  }
}

// ================================================================ batchnorm finalize
// reads stats -> sc, then zeroes stats for the next layer's gemm.
__global__ void bn_finalize_kernel(float* __restrict__ stats,
                                   const float* __restrict__ gamma,
                                   const float* __restrict__ beta,
                                   float* __restrict__ sc) {
  int c = threadIdx.x;
  const float invN = 1.0f / (float)N_NODES;
  float mean = stats[c] * invN;
  float var = stats[128 + c] * invN - mean * mean;
  float scale = gamma[c] * rsqrtf(var + BN_EPS);
  sc[c] = scale;
  sc[128 + c] = beta[c] - mean * scale;
  stats[c] = 0.f;
  stats[128 + c] = 0.f;
}

// ================================================================ pool + readout (fused)
// one block per graph (128 threads): bounds via binary search on sorted
// batch, pool row reduced directly (no atomics/memset), MLP in-block.
__global__ __launch_bounds__(128) void pool_readout_kernel(
    const ushort_t* __restrict__ P, const float* __restrict__ sc,
    const int* __restrict__ batch, const float* __restrict__ rW1,
    const float* __restrict__ rb1, const float* __restrict__ rW2,
    const float* __restrict__ rb2, float* __restrict__ out) {
  int g = blockIdx.x;
  int t = threadIdx.x;  // 0..127, owns column t
  int lo = 0, hi = N_NODES;
  while (lo < hi) { int mid = (lo + hi) >> 1; if (batch[mid] < g) lo = mid + 1; else hi = mid; }
  int gs = lo;
  hi = N_NODES;
  while (lo < hi) { int mid = (lo + hi) >> 1; if (batch[mid] < g + 1) lo = mid + 1; else hi = mid; }
  int ge = lo;
  float s = sc[t], b = sc[128 + t];
  float acc = 0.f;
  const ushort_t* pr = P + (size_t)gs * 128 + t;
  for (int r = gs; r < ge; r++, pr += 128)
    acc += fmaxf(__uint_as_float(((uint_t)*pr) << 16) * s + b, 0.f);
  __shared__ float pl[128];
  pl[t] = acc / fmaxf((float)(ge - gs), 1.f);
  __syncthreads();
  if (t < 64) {
    float h1 = rb1[t];
    for (int k = 0; k < 128; k++) h1 += pl[k] * rW1[k * 64 + t];
    h1 = fmaxf(h1, 0.f) * rW2[t];
#pragma unroll
    for (int off = 32; off > 0; off >>= 1) h1 += __shfl_down(h1, off);
    if (t == 0) out[g] = h1 + rb2[0];
  }
}

// ================================================================ launch
extern "C" void kernel_launch(void* const* d_in, const int* in_sizes, int n_in,
                              void* d_out, int out_size, void* d_ws, size_t ws_size,
                              hipStream_t stream) {
  const float* x     = (const float*)d_in[0];
  const int*   ei    = (const int*)d_in[1];
  const int*   src   = ei;
  const int*   dst   = ei + N_EDGES;
  const int*   batch = (const int*)d_in[2];
  const float* Wl0   = (const float*)d_in[3];
  const float* Wr0   = (const float*)d_in[4];
  const float* Wl    = (const float*)d_in[6];
  const float* Wr    = (const float*)d_in[7];
  const float* gamma = (const float*)d_in[9];
  const float* beta  = (const float*)d_in[10];
  const float* rW1   = (const float*)d_in[11];
  const float* rb1   = (const float*)d_in[12];
  const float* rW2   = (const float*)d_in[13];
  const float* rb2   = (const float*)d_in[14];
  float* out = (float*)d_out;

  char* ws = (char*)d_ws;
  size_t off = 0;
  auto alloc = [&](size_t bytes) -> void* {
    void* p = ws + off;
    off = (off + bytes + 255) & ~(size_t)255;
    return p;
  };
  uint_t*   A0u   = (uint_t*)alloc((size_t)N_NODES * 48 * 4);
  uint_t*   xb    = (uint_t*)alloc((size_t)N_NODES * 20 * 4);
  ushort_t* agg   = (ushort_t*)alloc((size_t)N_NODES * 128 * 2);
  ushort_t* Pa    = (ushort_t*)alloc((size_t)N_NODES * 128 * 2);
  ushort_t* Pb    = (ushort_t*)alloc((size_t)N_NODES * 128 * 2);
  ushort_t* WT0   = (ushort_t*)alloc((size_t)128 * 96 * 2);
  ushort_t* WT1   = (ushort_t*)alloc((size_t)128 * 256 * 2);
  ushort_t* WT2   = (ushort_t*)alloc((size_t)128 * 256 * 2);
  float* invdeg = (float*)alloc((size_t)N_NODES * 4);
  int*   degi   = (int*)alloc((size_t)N_NODES * 4);
  int*   rowptr = (int*)alloc((size_t)(N_NODES + 1) * 4);
  int*   cursor = (int*)alloc((size_t)N_NODES * 4);
  ushort_t* colidx = (ushort_t*)alloc((size_t)N_EDGES * 2);
  int*   partial= (int*)alloc((size_t)N_NODES * 4);
  int*   bsum   = (int*)alloc(256 * 4);
  float* stats  = (float*)alloc(256 * 4);
  float* sc     = (float*)alloc(256 * 4);

  const int NB_SCAN = (N_NODES + 255) / 256;  // 196
  const int gemm_blocks = (N_NODES + 63) / 64;
  const int agg_blocks  = (N_NODES + 15) / 16;
  const int l0_blocks   = (N_NODES + 3) / 4;

  // ---- CSR build (once)
  hipMemsetAsync(degi, 0, (size_t)N_NODES * 4, stream);
  hist_sharded_kernel<<<2048, 256, 0, stream>>>(dst, degi);
  scan_block_kernel<<<NB_SCAN, 256, 0, stream>>>(degi, partial, bsum, invdeg);
  scan_add_fused_kernel<<<NB_SCAN + 1, 256, 0, stream>>>(partial, bsum, rowptr,
                                                         cursor, NB_SCAN);
  fill_sharded_kernel<<<2048, 256, 0, stream>>>(src, dst, cursor, colidx);

  // ---- weights -> bf16 panel-major (+ stats zero); x -> bf16 pack
  wprep_all_kernel<<<(WP0 + 2 * WP1 + 255) / 256, 256, 0, stream>>>(
      Wl0, Wr0, Wl, Wr, WT0, WT1, WT2, stats);
  xb_cvt_kernel<<<(N_NODES * 20 + 255) / 256, 256, 0, stream>>>(x, xb);

  // ---- layer 0 (Kc = 96)
  layer0_prep_kernel<<<l0_blocks, 256, 0, stream>>>(xb, rowptr, colidx, invdeg, A0u);
  gemm_mfma_kernel<96, false><<<gemm_blocks, 256, 0, stream>>>(
      (const ushort_t*)A0u, nullptr, nullptr, WT0, Pa, stats);
  bn_finalize_kernel<<<1, 128, 0, stream>>>(stats, gamma, beta, sc);

  // ---- layer 1: consume Pa + sc0, produce Pb
  csr_aggregate_bn_kernel<<<agg_blocks, 256, 0, stream>>>(Pa, sc, rowptr, colidx,
                                                          invdeg, agg);
  gemm_mfma_kernel<256, true><<<gemm_blocks, 256, 0, stream>>>(
      agg, Pa, sc, WT1, Pb, stats);
  bn_finalize_kernel<<<1, 128, 0, stream>>>(stats, gamma + 128, beta + 128, sc);

  // ---- layer 2: consume Pb + sc1, produce Pa
  csr_aggregate_bn_kernel<<<agg_blocks, 256, 0, stream>>>(Pb, sc, rowptr, colidx,
                                                          invdeg, agg);
  gemm_mfma_kernel<256, true><<<gemm_blocks, 256, 0, stream>>>(
      agg, Pb, sc, WT2, Pa, stats);
  bn_finalize_kernel<<<1, 128, 0, stream>>>(stats, gamma + 256, beta + 256, sc);

  // ---- fused global mean pool (final BN inline) + readout
  pool_readout_kernel<<<N_GRAPHS, 128, 0, stream>>>(Pa, sc, batch, rW1, rb1,
                                                    rW2, rb2, out);
}

// Round 11
// 367.142 us; speedup vs baseline: 3.7323x; 1.0466x over previous
//
#include <hip/hip_runtime.h>

#define N_NODES 50000
#define N_EDGES 800000
#define N_GRAPHS 2000
#define BN_EPS 1e-5f
#define SHARD_SZ 6250  // N_NODES / 8

typedef unsigned short ushort_t;
typedef unsigned int uint_t;
using bf16x8 = __attribute__((ext_vector_type(8))) short;
using f32x4  = __attribute__((ext_vector_type(4))) float;

__device__ inline float bf_lo(uint_t u) { return __uint_as_float(u << 16); }
__device__ inline float bf_hi(uint_t u) { return __uint_as_float(u & 0xffff0000u); }
__device__ inline ushort_t f2bf(float f) {  // round-to-nearest-even
  uint_t u = __float_as_uint(f);
  return (ushort_t)((u + 0x7fffu + ((u >> 16) & 1u)) >> 16);
}
__device__ inline uint_t pack2(float a, float b) {
  return (uint_t)f2bf(a) | ((uint_t)f2bf(b) << 16);
}

// ================================================================ CSR build
__global__ void hist_sharded_kernel(const int* __restrict__ dst,
                                    int* __restrict__ degi) {
  const int shard = blockIdx.x & 7;
  const int lo = shard * SHARD_SZ, hi = lo + SHARD_SZ;
  const int nb = gridDim.x >> 3, blk = blockIdx.x >> 3;
  for (int e = blk * blockDim.x + threadIdx.x; e < N_EDGES;
       e += nb * blockDim.x) {
    int d = dst[e];
    if (d >= lo && d < hi) atomicAdd(&degi[d], 1);
  }
}

__global__ void fill_sharded_kernel(const int* __restrict__ src,
                                    const int* __restrict__ dst,
                                    int* __restrict__ cursor,
                                    ushort_t* __restrict__ col) {
  const int shard = blockIdx.x & 7;
  const int lo = shard * SHARD_SZ, hi = lo + SHARD_SZ;
  const int nb = gridDim.x >> 3, blk = blockIdx.x >> 3;
  for (int e = blk * blockDim.x + threadIdx.x; e < N_EDGES;
       e += nb * blockDim.x) {
    int d = dst[e];
    if (d >= lo && d < hi) {
      int p = atomicAdd(&cursor[d], 1);
      col[p] = (ushort_t)src[e];
    }
  }
}

__global__ void scan_block_kernel(const int* __restrict__ degi,
                                  int* __restrict__ partial,
                                  int* __restrict__ bsum,
                                  float* __restrict__ invdeg) {
  __shared__ int buf[2][256];
  int i = blockIdx.x * 256 + threadIdx.x;
  int v = (i < N_NODES) ? degi[i] : 0;
  buf[0][threadIdx.x] = v;
  __syncthreads();
  int pi = 0;
  for (int off = 1; off < 256; off <<= 1) {
    int nv = buf[pi][threadIdx.x];
    if (threadIdx.x >= off) nv += buf[pi][threadIdx.x - off];
    buf[pi ^ 1][threadIdx.x] = nv;
    pi ^= 1;
    __syncthreads();
  }
  int incl = buf[pi][threadIdx.x];
  if (i < N_NODES) {
    partial[i] = incl - v;
    invdeg[i] = 1.0f / fmaxf((float)v, 1.0f);
  }
  if (threadIdx.x == 255) bsum[blockIdx.x] = incl;
}

__global__ void scan_add_fused_kernel(const int* __restrict__ partial,
                                      const int* __restrict__ bsum,
                                      int* __restrict__ rowptr,
                                      int* __restrict__ cursor, int nb) {
  __shared__ int buf[2][256];
  __shared__ int sx[256];
  int t = threadIdx.x;
  int v = (t < nb) ? bsum[t] : 0;
  buf[0][t] = v;
  __syncthreads();
  int pi = 0;
  for (int off = 1; off < 256; off <<= 1) {
    int nv = buf[pi][t];
    if (t >= off) nv += buf[pi][t - off];
    buf[pi ^ 1][t] = nv;
    pi ^= 1;
    __syncthreads();
  }
  sx[t] = buf[pi][t] - v;
  __syncthreads();
  int add = sx[blockIdx.x];
  int i = blockIdx.x * 256 + t;
  if (i < N_NODES) {
    int r = partial[i] + add;
    rowptr[i] = r;
    cursor[i] = r;
  } else if (i == N_NODES) {
    rowptr[N_NODES] = N_EDGES;
  }
}

// ================================================================ prep (one launch)
// WT panel-major (idx = (k>>5)*4096 + c*32 + (k&31)); xb bf16 pack of x;
// zero all three stats buffers (768 floats).
#define WP0 (128 * 96)
#define WP1 (128 * 256)
__global__ void prep_all_kernel(const float* __restrict__ Wl0,
                                const float* __restrict__ Wr0,
                                const float* __restrict__ Wl,
                                const float* __restrict__ Wr,
                                const float* __restrict__ x,
                                ushort_t* __restrict__ WT0,
                                ushort_t* __restrict__ WT1,
                                ushort_t* __restrict__ WT2,
                                uint_t* __restrict__ xb,
                                float* __restrict__ stats) {
  int idx = blockIdx.x * blockDim.x + threadIdx.x;
  if (idx < 768) stats[idx] = 0.f;
  if (idx < WP0) {
    int c = idx / 96, k = idx - c * 96;
    float v = 0.f;
    if (k < 38) v = Wl0[k * 128 + c];
    else if (k < 76) v = Wr0[(k - 38) * 128 + c];
    WT0[(k >> 5) * 4096 + c * 32 + (k & 31)] = f2bf(v);
  } else if (idx < WP0 + 2 * WP1) {
    int i2 = idx - WP0;
    int layer = i2 / WP1;
    int j = i2 - layer * WP1;
    int c = j / 256, k = j - c * 256;
    const float* L = Wl + layer * 16384;
    const float* R = Wr + layer * 16384;
    float v = (k < 128) ? L[k * 128 + c] : R[(k - 128) * 128 + c];
    ushort_t* W = layer ? WT2 : WT1;
    W[(k >> 5) * 4096 + c * 32 + (k & 31)] = f2bf(v);
  } else if (idx < WP0 + 2 * WP1 + N_NODES * 20) {
    int j = idx - (WP0 + 2 * WP1);
    int row = j / 20, c2 = (j - row * 20) * 2;
    float v0 = (c2 < 38) ? x[row * 38 + c2] : 0.f;
    float v1 = (c2 + 1 < 38) ? x[row * 38 + c2 + 1] : 0.f;
    xb[j] = pack2(v0, v1);
  }
}

// ================================================================ layer-0 prep
__global__ __launch_bounds__(256) void layer0_prep_kernel(
    const uint_t* __restrict__ xb, const int* __restrict__ rowptr,
    const ushort_t* __restrict__ col, const float* __restrict__ invdeg,
    uint_t* __restrict__ A0u) {
  int node = blockIdx.x * 4 + (threadIdx.x >> 6);
  if (node >= N_NODES) return;
  int lane = threadIdx.x & 63;
  int beg = rowptr[node], end = rowptr[node + 1];
  if (lane < 19) {
    float a0 = 0.f, a1 = 0.f;
    int e = beg;
    for (; e + 3 < end; e += 4) {
      uint_t u0 = xb[(size_t)col[e] * 20 + lane];
      uint_t u1 = xb[(size_t)col[e + 1] * 20 + lane];
      uint_t u2 = xb[(size_t)col[e + 2] * 20 + lane];
      uint_t u3 = xb[(size_t)col[e + 3] * 20 + lane];
      a0 += (bf_lo(u0) + bf_lo(u1)) + (bf_lo(u2) + bf_lo(u3));
      a1 += (bf_hi(u0) + bf_hi(u1)) + (bf_hi(u2) + bf_hi(u3));
    }
    for (; e < end; e++) {
      uint_t u = xb[(size_t)col[e] * 20 + lane];
      a0 += bf_lo(u);
      a1 += bf_hi(u);
    }
    float inv = invdeg[node];
    A0u[(size_t)node * 48 + lane] = pack2(a0 * inv, a1 * inv);
  } else if (lane < 38) {
    A0u[(size_t)node * 48 + lane] = xb[(size_t)node * 20 + (lane - 19)];
  } else if (lane < 48) {
    A0u[(size_t)node * 48 + lane] = 0u;
  }
}

// ================================================================ layer-0 GEMM + stats
// P = A0 @ W0 (Kc=96, no BN input). B staged per 32-K panel.
__global__ __launch_bounds__(256, 6) void gemm0_kernel(
    const ushort_t* __restrict__ A, const ushort_t* __restrict__ WT,
    ushort_t* __restrict__ P, float* __restrict__ stats) {
  __shared__ __align__(16) ushort_t sA[64 * 40];
  __shared__ __align__(16) ushort_t sB[128 * 40];
  const int tid = threadIdx.x;
  const int row0 = blockIdx.x * 64;

  const int w = tid >> 6;
  const int l = tid & 63;
  const int m = l & 15;
  const int quad = l >> 4;
  f32x4 acc[8];
#pragma unroll
  for (int ct = 0; ct < 8; ct++) acc[ct] = (f32x4){0.f, 0.f, 0.f, 0.f};

  for (int kk = 0; kk < 96; kk += 32) {
    __syncthreads();
    {
      const uint4* wp = (const uint4*)(WT + (kk >> 5) * 4096);
      uint4 v0 = wp[tid];
      uint4 v1 = wp[tid + 256];
      *((uint4*)&sB[(tid >> 2) * 40 + (tid & 3) * 8]) = v0;
      int t2 = tid + 256;
      *((uint4*)&sB[(t2 >> 2) * 40 + (t2 & 3) * 8]) = v1;
    }
    {
      int r = tid >> 2, c = tid & 3;
      int row = row0 + r;
      uint4 v = make_uint4(0, 0, 0, 0);
      if (row < N_NODES)
        v = ((const uint4*)(A + (size_t)row * 96))[(kk >> 3) + c];
      *((uint4*)&sA[r * 40 + c * 8]) = v;
    }
    __syncthreads();
    bf16x8 a = *(const bf16x8*)&sA[(w * 16 + m) * 40 + quad * 8];
#pragma unroll
    for (int ct = 0; ct < 8; ct++) {
      bf16x8 b = *(const bf16x8*)&sB[(ct * 16 + m) * 40 + quad * 8];
      acc[ct] = __builtin_amdgcn_mfma_f32_16x16x32_bf16(a, b, acc[ct], 0, 0, 0);
    }
  }

#pragma unroll
  for (int ct = 0; ct < 8; ct++) {
#pragma unroll
    for (int v = 0; v < 4; v++) {
      int row = row0 + w * 16 + quad * 4 + v;
      if (row < N_NODES) P[(size_t)row * 128 + ct * 16 + m] = f2bf(acc[ct][v]);
    }
  }

  float* red = (float*)sA;
  __syncthreads();
#pragma unroll
  for (int ct = 0; ct < 8; ct++) {
    float s = 0.f, q = 0.f;
#pragma unroll
    for (int v = 0; v < 4; v++) {
      s += acc[ct][v];
      q += acc[ct][v] * acc[ct][v];
    }
    float t;
    t = __shfl_xor(s, 16); s += t;
    t = __shfl_xor(s, 32); s += t;
    t = __shfl_xor(q, 16); q += t;
    t = __shfl_xor(q, 32); q += t;
    if (l < 16) {
      red[w * 256 + ct * 16 + l] = s;
      red[w * 256 + 128 + ct * 16 + l] = q;
    }
  }
  __syncthreads();
  if (tid < 128) {
    float s = 0.f, q = 0.f;
#pragma unroll
    for (int wv = 0; wv < 4; wv++) {
      s += red[wv * 256 + tid];
      q += red[wv * 256 + 128 + tid];
    }
    atomicAdd(&stats[tid], s);
    atomicAdd(&stats[128 + tid], q);
  }
}

// ================================================================ fused layer kernel
// For each 64-row block:
//   1. compute BN scale/shift from stats_prev (per-block, redundant)
//   2. gather-aggregate relu(Pin*s+b) of neighbors into LDS (bf16, no
//      global agg round-trip)
//   3. K-loop: k<128 A-frags read directly from aggu LDS; k>=128 stage
//      BN-transformed self rows of Pin; B per 32-K panel
//   4. store pre-BN Pout + accumulate stats_out
__global__ __launch_bounds__(256, 4) void gemm_fused_kernel(
    const ushort_t* __restrict__ Pin, const float* __restrict__ stats_prev,
    const float* __restrict__ gamma, const float* __restrict__ beta,
    const int* __restrict__ rowptr, const ushort_t* __restrict__ col,
    const float* __restrict__ invdeg, const ushort_t* __restrict__ WT,
    ushort_t* __restrict__ Pout, float* __restrict__ stats_out) {
  __shared__ __align__(16) uint_t aggu[64 * 68];  // 64 rows x 128 bf16 + pad
  __shared__ __align__(16) ushort_t sA[64 * 40];
  __shared__ __align__(16) ushort_t sB[128 * 40];
  __shared__ float ssc[256];
  const int tid = threadIdx.x;
  const int row0 = blockIdx.x * 64;

  // ---- BN coefficients (redundant per block; stats_prev is L2-hot)
  if (tid < 128) {
    const float invN = 1.0f / (float)N_NODES;
    float mean = stats_prev[tid] * invN;
    float var = stats_prev[128 + tid] * invN - mean * mean;
    float scale = gamma[tid] * rsqrtf(var + BN_EPS);
    ssc[tid] = scale;
    ssc[128 + tid] = beta[tid] - mean * scale;
  }
  __syncthreads();

  // ---- gather phase: wave w covers rows w*16..w*16+15, 4 nodes per pass
  const int w = tid >> 6;
  const int g2 = (tid >> 4) & 3;
  const int h = tid & 15;
  const uint4* Pu = (const uint4*)Pin;  // row stride 16 uint4
  int c0 = h * 8;
  float s[8], b[8];
#pragma unroll
  for (int j = 0; j < 8; j++) {
    s[j] = ssc[c0 + j];
    b[j] = ssc[128 + c0 + j];
  }
  for (int pass = 0; pass < 4; pass++) {
    int r = w * 16 + pass * 4 + g2;
    int node = row0 + r;
    uint4 o = make_uint4(0, 0, 0, 0);
    if (node < N_NODES) {
      int beg = rowptr[node], end = rowptr[node + 1];
      float a[8];
#pragma unroll
      for (int j = 0; j < 8; j++) a[j] = 0.f;
      int e = beg;
      for (; e + 3 < end; e += 4) {
        uint4 u0 = Pu[(size_t)col[e] * 16 + h];
        uint4 u1 = Pu[(size_t)col[e + 1] * 16 + h];
        uint4 u2 = Pu[(size_t)col[e + 2] * 16 + h];
        uint4 u3 = Pu[(size_t)col[e + 3] * 16 + h];
        uint_t w0[4] = {u0.x, u0.y, u0.z, u0.w};
        uint_t w1[4] = {u1.x, u1.y, u1.z, u1.w};
        uint_t w2[4] = {u2.x, u2.y, u2.z, u2.w};
        uint_t w3[4] = {u3.x, u3.y, u3.z, u3.w};
#pragma unroll
        for (int p = 0; p < 4; p++) {
          a[2 * p]     += (fmaxf(bf_lo(w0[p]) * s[2 * p] + b[2 * p], 0.f) +
                           fmaxf(bf_lo(w1[p]) * s[2 * p] + b[2 * p], 0.f)) +
                          (fmaxf(bf_lo(w2[p]) * s[2 * p] + b[2 * p], 0.f) +
                           fmaxf(bf_lo(w3[p]) * s[2 * p] + b[2 * p], 0.f));
          a[2 * p + 1] += (fmaxf(bf_hi(w0[p]) * s[2 * p + 1] + b[2 * p + 1], 0.f) +
                           fmaxf(bf_hi(w1[p]) * s[2 * p + 1] + b[2 * p + 1], 0.f)) +
                          (fmaxf(bf_hi(w2[p]) * s[2 * p + 1] + b[2 * p + 1], 0.f) +
                           fmaxf(bf_hi(w3[p]) * s[2 * p + 1] + b[2 * p + 1], 0.f));
        }
      }
      for (; e < end; e++) {
        uint4 u = Pu[(size_t)col[e] * 16 + h];
        uint_t ww[4] = {u.x, u.y, u.z, u.w};
#pragma unroll
        for (int p = 0; p < 4; p++) {
          a[2 * p]     += fmaxf(bf_lo(ww[p]) * s[2 * p] + b[2 * p], 0.f);
          a[2 * p + 1] += fmaxf(bf_hi(ww[p]) * s[2 * p + 1] + b[2 * p + 1], 0.f);
        }
      }
      float inv = invdeg[node];
      o.x = pack2(a[0] * inv, a[1] * inv);
      o.y = pack2(a[2] * inv, a[3] * inv);
      o.z = pack2(a[4] * inv, a[5] * inv);
      o.w = pack2(a[6] * inv, a[7] * inv);
    }
    *((uint4*)&aggu[r * 68 + h * 4]) = o;
  }
  __syncthreads();

  // ---- K loop
  const int l = tid & 63;
  const int m = l & 15;
  const int quad = l >> 4;
  f32x4 acc[8];
#pragma unroll
  for (int ct = 0; ct < 8; ct++) acc[ct] = (f32x4){0.f, 0.f, 0.f, 0.f};

  for (int kk = 0; kk < 256; kk += 32) {
    __syncthreads();
    {
      const uint4* wp = (const uint4*)(WT + (kk >> 5) * 4096);
      uint4 v0 = wp[tid];
      uint4 v1 = wp[tid + 256];
      *((uint4*)&sB[(tid >> 2) * 40 + (tid & 3) * 8]) = v0;
      int t2 = tid + 256;
      *((uint4*)&sB[(t2 >> 2) * 40 + (t2 & 3) * 8]) = v1;
    }
    if (kk >= 128) {
      int r = tid >> 2, c = tid & 3;
      int row = row0 + r;
      uint4 v = make_uint4(0, 0, 0, 0);
      if (row < N_NODES) {
        int pcol = kk - 128 + c * 8;
        uint4 u = *(const uint4*)(Pin + (size_t)row * 128 + pcol);
        uint_t in[4] = {u.x, u.y, u.z, u.w};
        uint_t ov[4];
#pragma unroll
        for (int p = 0; p < 4; p++) {
          int cc = pcol + 2 * p;
          float f0 = fmaxf(bf_lo(in[p]) * ssc[cc] + ssc[128 + cc], 0.f);
          float f1 = fmaxf(bf_hi(in[p]) * ssc[cc + 1] + ssc[128 + cc + 1], 0.f);
          ov[p] = pack2(f0, f1);
        }
        v = make_uint4(ov[0], ov[1], ov[2], ov[3]);
      }
      *((uint4*)&sA[r * 40 + c * 8]) = v;
    }
    __syncthreads();
    bf16x8 a;
    if (kk < 128)
      a = *(const bf16x8*)((const ushort_t*)aggu + (w * 16 + m) * 136 + kk + quad * 8);
    else
      a = *(const bf16x8*)&sA[(w * 16 + m) * 40 + quad * 8];
#pragma unroll
    for (int ct = 0; ct < 8; ct++) {
      bf16x8 bb = *(const bf16x8*)&sB[(ct * 16 + m) * 40 + quad * 8];
      acc[ct] = __builtin_amdgcn_mfma_f32_16x16x32_bf16(a, bb, acc[ct], 0, 0, 0);
    }
  }

  // ---- store pre-BN result
#pragma unroll
  for (int ct = 0; ct < 8; ct++) {
#pragma unroll
    for (int v = 0; v < 4; v++) {
      int row = row0 + w * 16 + quad * 4 + v;
      if (row < N_NODES) Pout[(size_t)row * 128 + ct * 16 + m] = f2bf(acc[ct][v]);
    }
  }

  // ---- stats epilogue (pad rows contribute exact zeros)
  float* red = (float*)sA;
  __syncthreads();
#pragma unroll
  for (int ct = 0; ct < 8; ct++) {
    float ss = 0.f, q = 0.f;
#pragma unroll
    for (int v = 0; v < 4; v++) {
      ss += acc[ct][v];
      q += acc[ct][v] * acc[ct][v];
    }
    float t;
    t = __shfl_xor(ss, 16); ss += t;
    t = __shfl_xor(ss, 32); ss += t;
    t = __shfl_xor(q, 16); q += t;
    t = __shfl_xor(q, 32); q += t;
    if (l < 16) {
      red[w * 256 + ct * 16 + l] = ss;
      red[w * 256 + 128 + ct * 16 + l] = q;
    }
  }
  __syncthreads();
  if (tid < 128) {
    float ss = 0.f, q = 0.f;
#pragma unroll
    for (int wv = 0; wv < 4; wv++) {
      ss += red[wv * 256 + tid];
      q += red[wv * 256 + 128 + tid];
    }
    atomicAdd(&stats_out[tid], ss);
    atomicAdd(&stats_out[128 + tid], q);
  }
}

// ================================================================ pool + readout
// one block per graph; final BN coefficients computed inline from stats.
__global__ __launch_bounds__(128) void pool_readout_kernel(
    const ushort_t* __restrict__ P, const float* __restrict__ stats,
    const float* __restrict__ gamma, const float* __restrict__ beta,
    const int* __restrict__ batch, const float* __restrict__ rW1,
    const float* __restrict__ rb1, const float* __restrict__ rW2,
    const float* __restrict__ rb2, float* __restrict__ out) {
  int g = blockIdx.x;
  int t = threadIdx.x;  // 0..127, owns column t
  int lo = 0, hi = N_NODES;
  while (lo < hi) { int mid = (lo + hi) >> 1; if (batch[mid] < g) lo = mid + 1; else hi = mid; }
  int gs = lo;
  hi = N_NODES;
  while (lo < hi) { int mid = (lo + hi) >> 1; if (batch[mid] < g + 1) lo = mid + 1; else hi = mid; }
  int ge = lo;
  const float invN = 1.0f / (float)N_NODES;
  float mean = stats[t] * invN;
  float var = stats[128 + t] * invN - mean * mean;
  float s = gamma[t] * rsqrtf(var + BN_EPS);
  float b = beta[t] - mean * s;
  float acc = 0.f;
  const ushort_t* pr = P + (size_t)gs * 128 + t;
  for (int r = gs; r < ge; r++, pr += 128)
    acc += fmaxf(__uint_as_float(((uint_t)*pr) << 16) * s + b, 0.f);
  __shared__ float pl[128];
  pl[t] = acc / fmaxf((float)(ge - gs), 1.f);
  __syncthreads();
  if (t < 64) {
    float h1 = rb1[t];
    for (int k = 0; k < 128; k++) h1 += pl[k] * rW1[k * 64 + t];
    h1 = fmaxf(h1, 0.f) * rW2[t];
#pragma unroll
    for (int off = 32; off > 0; off >>= 1) h1 += __shfl_down(h1, off);
    if (t == 0) out[g] = h1 + rb2[0];
  }
}

// ================================================================ launch
extern "C" void kernel_launch(void* const* d_in, const int* in_sizes, int n_in,
                              void* d_out, int out_size, void* d_ws, size_t ws_size,
                              hipStream_t stream) {
  const float* x     = (const float*)d_in[0];
  const int*   ei    = (const int*)d_in[1];
  const int*   src   = ei;
  const int*   dst   = ei + N_EDGES;
  const int*   batch = (const int*)d_in[2];
  const float* Wl0   = (const float*)d_in[3];
  const float* Wr0   = (const float*)d_in[4];
  const float* Wl    = (const float*)d_in[6];
  const float* Wr    = (const float*)d_in[7];
  const float* gamma = (const float*)d_in[9];
  const float* beta  = (const float*)d_in[10];
  const float* rW1   = (const float*)d_in[11];
  const float* rb1   = (const float*)d_in[12];
  const float* rW2   = (const float*)d_in[13];
  const float* rb2   = (const float*)d_in[14];
  float* out = (float*)d_out;

  char* ws = (char*)d_ws;
  size_t off = 0;
  auto alloc = [&](size_t bytes) -> void* {
    void* p = ws + off;
    off = (off + bytes + 255) & ~(size_t)255;
    return p;
  };
  uint_t*   A0u   = (uint_t*)alloc((size_t)N_NODES * 48 * 4);
  uint_t*   xb    = (uint_t*)alloc((size_t)N_NODES * 20 * 4);
  ushort_t* Pa    = (ushort_t*)alloc((size_t)N_NODES * 128 * 2);
  ushort_t* Pb    = (ushort_t*)alloc((size_t)N_NODES * 128 * 2);
  ushort_t* WT0   = (ushort_t*)alloc((size_t)128 * 96 * 2);
  ushort_t* WT1   = (ushort_t*)alloc((size_t)128 * 256 * 2);
  ushort_t* WT2   = (ushort_t*)alloc((size_t)128 * 256 * 2);
  float* invdeg = (float*)alloc((size_t)N_NODES * 4);
  int*   degi   = (int*)alloc((size_t)N_NODES * 4);
  int*   rowptr = (int*)alloc((size_t)(N_NODES + 1) * 4);
  int*   cursor = (int*)alloc((size_t)N_NODES * 4);
  ushort_t* colidx = (ushort_t*)alloc((size_t)N_EDGES * 2);
  int*   partial= (int*)alloc((size_t)N_NODES * 4);
  int*   bsum   = (int*)alloc(256 * 4);
  float* stats  = (float*)alloc(768 * 4);  // 3 layers x {sum[128],sumsq[128]}

  const int NB_SCAN = (N_NODES + 255) / 256;  // 196
  const int gemm_blocks = (N_NODES + 63) / 64;
  const int l0_blocks   = (N_NODES + 3) / 4;
  const int PREP_TOTAL = WP0 + 2 * WP1 + N_NODES * 20;

  // ---- CSR build (once)
  hipMemsetAsync(degi, 0, (size_t)N_NODES * 4, stream);
  hist_sharded_kernel<<<2048, 256, 0, stream>>>(dst, degi);
  scan_block_kernel<<<NB_SCAN, 256, 0, stream>>>(degi, partial, bsum, invdeg);
  scan_add_fused_kernel<<<NB_SCAN + 1, 256, 0, stream>>>(partial, bsum, rowptr,
                                                         cursor, NB_SCAN);
  fill_sharded_kernel<<<2048, 256, 0, stream>>>(src, dst, cursor, colidx);

  // ---- weights + xb + stats zero (one launch)
  prep_all_kernel<<<(PREP_TOTAL + 255) / 256, 256, 0, stream>>>(
      Wl0, Wr0, Wl, Wr, x, WT0, WT1, WT2, xb, stats);

  // ---- layer 0
  layer0_prep_kernel<<<l0_blocks, 256, 0, stream>>>(xb, rowptr, colidx, invdeg, A0u);
  gemm0_kernel<<<gemm_blocks, 256, 0, stream>>>((const ushort_t*)A0u, WT0, Pa, stats);

  // ---- layer 1 (fused aggregate+BN+GEMM): Pa -> Pb
  gemm_fused_kernel<<<gemm_blocks, 256, 0, stream>>>(
      Pa, stats, gamma, beta, rowptr, colidx, invdeg, WT1, Pb, stats + 256);

  // ---- layer 2: Pb -> Pa
  gemm_fused_kernel<<<gemm_blocks, 256, 0, stream>>>(
      Pb, stats + 256, gamma + 128, beta + 128, rowptr, colidx, invdeg, WT2,
      Pa, stats + 512);

  // ---- fused global mean pool (final BN inline) + readout
  pool_readout_kernel<<<N_GRAPHS, 128, 0, stream>>>(
      Pa, stats + 512, gamma + 256, beta + 256, batch, rW1, rb1, rW2, rb2, out);
}

// Round 12
// 361.545 us; speedup vs baseline: 3.7901x; 1.0155x over previous
//
#include <hip/hip_runtime.h>

#define N_NODES 50000
#define N_EDGES 800000
#define N_GRAPHS 2000
#define BN_EPS 1e-5f
#define FSHARD 12500  // fill: N_NODES / 4

typedef unsigned short ushort_t;
typedef unsigned int uint_t;
using bf16x8 = __attribute__((ext_vector_type(8))) short;
using f32x4  = __attribute__((ext_vector_type(4))) float;

__device__ inline float bf_lo(uint_t u) { return __uint_as_float(u << 16); }
__device__ inline float bf_hi(uint_t u) { return __uint_as_float(u & 0xffff0000u); }
__device__ inline ushort_t f2bf(float f) {  // round-to-nearest-even
  uint_t u = __float_as_uint(f);
  return (ushort_t)((u + 0x7fffu + ((u >> 16) & 1u)) >> 16);
}
__device__ inline uint_t pack2(float a, float b) {
  return (uint_t)f2bf(a) | ((uint_t)f2bf(b) << 16);
}

// ================================================================ CSR build
// histogram: single pass, int atomics to 200 KB degi (no partial-line WB issue)
__global__ void hist_kernel(const int* __restrict__ dst, int* __restrict__ degi) {
  for (int e = blockIdx.x * blockDim.x + threadIdx.x; e < N_EDGES;
       e += gridDim.x * blockDim.x)
    atomicAdd(&degi[dst[e]], 1);
}

// fill: 4 dst-range shards (blockIdx&3) keep colidx write locality while
// only re-reading dst 4x (8-shard variant paid 205 MB of dst reads).
__global__ void fill_sharded_kernel(const int* __restrict__ src,
                                    const int* __restrict__ dst,
                                    int* __restrict__ cursor,
                                    ushort_t* __restrict__ col) {
  const int shard = blockIdx.x & 3;
  const int lo = shard * FSHARD, hi = lo + FSHARD;
  const int nb = gridDim.x >> 2, blk = blockIdx.x >> 2;
  for (int e = blk * blockDim.x + threadIdx.x; e < N_EDGES;
       e += nb * blockDim.x) {
    int d = dst[e];
    if (d >= lo && d < hi) {
      int p = atomicAdd(&cursor[d], 1);
      col[p] = (ushort_t)src[e];
    }
  }
}

__global__ void scan_block_kernel(const int* __restrict__ degi,
                                  int* __restrict__ partial,
                                  int* __restrict__ bsum,
                                  float* __restrict__ invdeg) {
  __shared__ int buf[2][256];
  int i = blockIdx.x * 256 + threadIdx.x;
  int v = (i < N_NODES) ? degi[i] : 0;
  buf[0][threadIdx.x] = v;
  __syncthreads();
  int pi = 0;
  for (int off = 1; off < 256; off <<= 1) {
    int nv = buf[pi][threadIdx.x];
    if (threadIdx.x >= off) nv += buf[pi][threadIdx.x - off];
    buf[pi ^ 1][threadIdx.x] = nv;
    pi ^= 1;
    __syncthreads();
  }
  int incl = buf[pi][threadIdx.x];
  if (i < N_NODES) {
    partial[i] = incl - v;
    invdeg[i] = 1.0f / fmaxf((float)v, 1.0f);
  }
  if (threadIdx.x == 255) bsum[blockIdx.x] = incl;
}

__global__ void scan_add_fused_kernel(const int* __restrict__ partial,
                                      const int* __restrict__ bsum,
                                      int* __restrict__ rowptr,
                                      int* __restrict__ cursor, int nb) {
  __shared__ int buf[2][256];
  __shared__ int sx[256];
  int t = threadIdx.x;
  int v = (t < nb) ? bsum[t] : 0;
  buf[0][t] = v;
  __syncthreads();
  int pi = 0;
  for (int off = 1; off < 256; off <<= 1) {
    int nv = buf[pi][t];
    if (t >= off) nv += buf[pi][t - off];
    buf[pi ^ 1][t] = nv;
    pi ^= 1;
    __syncthreads();
  }
  sx[t] = buf[pi][t] - v;
  __syncthreads();
  int add = sx[blockIdx.x];
  int i = blockIdx.x * 256 + t;
  if (i < N_NODES) {
    int r = partial[i] + add;
    rowptr[i] = r;
    cursor[i] = r;
  } else if (i == N_NODES) {
    rowptr[N_NODES] = N_EDGES;
  }
}

// ================================================================ prep (one launch)
#define WP0 (128 * 96)
#define WP1 (128 * 256)
__global__ void prep_all_kernel(const float* __restrict__ Wl0,
                                const float* __restrict__ Wr0,
                                const float* __restrict__ Wl,
                                const float* __restrict__ Wr,
                                const float* __restrict__ x,
                                ushort_t* __restrict__ WT0,
                                ushort_t* __restrict__ WT1,
                                ushort_t* __restrict__ WT2,
                                uint_t* __restrict__ xb,
                                float* __restrict__ stats) {
  int idx = blockIdx.x * blockDim.x + threadIdx.x;
  if (idx < 768) stats[idx] = 0.f;
  if (idx < WP0) {
    int c = idx / 96, k = idx - c * 96;
    float v = 0.f;
    if (k < 38) v = Wl0[k * 128 + c];
    else if (k < 76) v = Wr0[(k - 38) * 128 + c];
    WT0[(k >> 5) * 4096 + c * 32 + (k & 31)] = f2bf(v);
  } else if (idx < WP0 + 2 * WP1) {
    int i2 = idx - WP0;
    int layer = i2 / WP1;
    int j = i2 - layer * WP1;
    int c = j / 256, k = j - c * 256;
    const float* L = Wl + layer * 16384;
    const float* R = Wr + layer * 16384;
    float v = (k < 128) ? L[k * 128 + c] : R[(k - 128) * 128 + c];
    ushort_t* W = layer ? WT2 : WT1;
    W[(k >> 5) * 4096 + c * 32 + (k & 31)] = f2bf(v);
  } else if (idx < WP0 + 2 * WP1 + N_NODES * 20) {
    int j = idx - (WP0 + 2 * WP1);
    int row = j / 20, c2 = (j - row * 20) * 2;
    float v0 = (c2 < 38) ? x[row * 38 + c2] : 0.f;
    float v1 = (c2 + 1 < 38) ? x[row * 38 + c2 + 1] : 0.f;
    xb[j] = pack2(v0, v1);
  }
}

// ================================================================ layer-0 fused
// Per 64-row block: gather-mean xb neighborhoods into LDS A (cols 0..37),
// self x (38..75), zeros (76..95); then Kc=96 MFMA GEMM + stats epilogue.
__global__ __launch_bounds__(256, 6) void gemm0_fused_kernel(
    const uint_t* __restrict__ xb, const int* __restrict__ rowptr,
    const ushort_t* __restrict__ col, const float* __restrict__ invdeg,
    const ushort_t* __restrict__ WT, ushort_t* __restrict__ P,
    float* __restrict__ stats) {
  __shared__ __align__(16) uint_t aggA[64 * 52];  // 64 rows x 96 bf16 + pad
  __shared__ __align__(16) ushort_t sB[128 * 40];
  const int tid = threadIdx.x;
  const int row0 = blockIdx.x * 64;
  const int w = tid >> 6;
  const int l = tid & 63;

  // ---- gather phase: 2 nodes per wave (32 lanes each), lanes 0..18 active
  {
    int half = l >> 5;
    int j = l & 31;
    for (int pass = 0; pass < 8; pass++) {
      int r = w * 16 + pass * 2 + half;
      int node = row0 + r;
      if (j < 19) {
        uint_t o = 0;
        if (node < N_NODES) {
          int beg = rowptr[node], end = rowptr[node + 1];
          float a0 = 0.f, a1 = 0.f;
          int e = beg;
          for (; e + 3 < end; e += 4) {
            uint_t u0 = xb[(size_t)col[e] * 20 + j];
            uint_t u1 = xb[(size_t)col[e + 1] * 20 + j];
            uint_t u2 = xb[(size_t)col[e + 2] * 20 + j];
            uint_t u3 = xb[(size_t)col[e + 3] * 20 + j];
            a0 += (bf_lo(u0) + bf_lo(u1)) + (bf_lo(u2) + bf_lo(u3));
            a1 += (bf_hi(u0) + bf_hi(u1)) + (bf_hi(u2) + bf_hi(u3));
          }
          for (; e < end; e++) {
            uint_t u = xb[(size_t)col[e] * 20 + j];
            a0 += bf_lo(u);
            a1 += bf_hi(u);
          }
          float inv = invdeg[node];
          o = pack2(a0 * inv, a1 * inv);
        }
        aggA[r * 52 + j] = o;
      }
    }
  }
  // ---- self + zero fill: uints 19..47 of each row
  for (int idx = tid; idx < 64 * 29; idx += 256) {
    int r = idx / 29;
    int j2 = idx - r * 29 + 19;
    int node = row0 + r;
    uint_t v = 0;
    if (node < N_NODES && j2 < 38) v = xb[(size_t)node * 20 + (j2 - 19)];
    aggA[r * 52 + j2] = v;
  }

  // ---- K loop (Kc = 96)
  const int m = l & 15;
  const int quad = l >> 4;
  f32x4 acc[8];
#pragma unroll
  for (int ct = 0; ct < 8; ct++) acc[ct] = (f32x4){0.f, 0.f, 0.f, 0.f};

  for (int kk = 0; kk < 96; kk += 32) {
    __syncthreads();  // first iter: gather completion; later: sB reuse
    {
      const uint4* wp = (const uint4*)(WT + (kk >> 5) * 4096);
      uint4 v0 = wp[tid];
      uint4 v1 = wp[tid + 256];
      *((uint4*)&sB[(tid >> 2) * 40 + (tid & 3) * 8]) = v0;
      int t2 = tid + 256;
      *((uint4*)&sB[(t2 >> 2) * 40 + (t2 & 3) * 8]) = v1;
    }
    __syncthreads();
    bf16x8 a = *(const bf16x8*)((const ushort_t*)aggA + (w * 16 + m) * 104 +
                                kk + quad * 8);
#pragma unroll
    for (int ct = 0; ct < 8; ct++) {
      bf16x8 b = *(const bf16x8*)&sB[(ct * 16 + m) * 40 + quad * 8];
      acc[ct] = __builtin_amdgcn_mfma_f32_16x16x32_bf16(a, b, acc[ct], 0, 0, 0);
    }
  }

#pragma unroll
  for (int ct = 0; ct < 8; ct++) {
#pragma unroll
    for (int v = 0; v < 4; v++) {
      int row = row0 + w * 16 + quad * 4 + v;
      if (row < N_NODES) P[(size_t)row * 128 + ct * 16 + m] = f2bf(acc[ct][v]);
    }
  }

  float* red = (float*)sB;
  __syncthreads();
#pragma unroll
  for (int ct = 0; ct < 8; ct++) {
    float s = 0.f, q = 0.f;
#pragma unroll
    for (int v = 0; v < 4; v++) {
      s += acc[ct][v];
      q += acc[ct][v] * acc[ct][v];
    }
    float t;
    t = __shfl_xor(s, 16); s += t;
    t = __shfl_xor(s, 32); s += t;
    t = __shfl_xor(q, 16); q += t;
    t = __shfl_xor(q, 32); q += t;
    if (l < 16) {
      red[w * 256 + ct * 16 + l] = s;
      red[w * 256 + 128 + ct * 16 + l] = q;
    }
  }
  __syncthreads();
  if (tid < 128) {
    float s = 0.f, q = 0.f;
#pragma unroll
    for (int wv = 0; wv < 4; wv++) {
      s += red[wv * 256 + tid];
      q += red[wv * 256 + 128 + tid];
    }
    atomicAdd(&stats[tid], s);
    atomicAdd(&stats[128 + tid], q);
  }
}

// ================================================================ fused layer kernel
// gather-aggregate relu(Pin*s+b) into LDS, K-loop (k<128 from LDS agg,
// k>=128 BN-transformed self rows), store pre-BN Pout + stats.
__global__ __launch_bounds__(256, 4) void gemm_fused_kernel(
    const ushort_t* __restrict__ Pin, const float* __restrict__ stats_prev,
    const float* __restrict__ gamma, const float* __restrict__ beta,
    const int* __restrict__ rowptr, const ushort_t* __restrict__ col,
    const float* __restrict__ invdeg, const ushort_t* __restrict__ WT,
    ushort_t* __restrict__ Pout, float* __restrict__ stats_out) {
  __shared__ __align__(16) uint_t aggu[64 * 68];
  __shared__ __align__(16) ushort_t sA[64 * 40];
  __shared__ __align__(16) ushort_t sB[128 * 40];
  __shared__ float ssc[256];
  const int tid = threadIdx.x;
  const int row0 = blockIdx.x * 64;

  if (tid < 128) {
    const float invN = 1.0f / (float)N_NODES;
    float mean = stats_prev[tid] * invN;
    float var = stats_prev[128 + tid] * invN - mean * mean;
    float scale = gamma[tid] * rsqrtf(var + BN_EPS);
    ssc[tid] = scale;
    ssc[128 + tid] = beta[tid] - mean * scale;
  }
  __syncthreads();

  const int w = tid >> 6;
  const int g2 = (tid >> 4) & 3;
  const int h = tid & 15;
  const uint4* Pu = (const uint4*)Pin;  // row stride 16 uint4
  int c0 = h * 8;
  float s[8], b[8];
#pragma unroll
  for (int j = 0; j < 8; j++) {
    s[j] = ssc[c0 + j];
    b[j] = ssc[128 + c0 + j];
  }
  for (int pass = 0; pass < 4; pass++) {
    int r = w * 16 + pass * 4 + g2;
    int node = row0 + r;
    uint4 o = make_uint4(0, 0, 0, 0);
    if (node < N_NODES) {
      int beg = rowptr[node], end = rowptr[node + 1];
      float a[8];
#pragma unroll
      for (int j = 0; j < 8; j++) a[j] = 0.f;
      int e = beg;
      for (; e + 3 < end; e += 4) {
        uint4 u0 = Pu[(size_t)col[e] * 16 + h];
        uint4 u1 = Pu[(size_t)col[e + 1] * 16 + h];
        uint4 u2 = Pu[(size_t)col[e + 2] * 16 + h];
        uint4 u3 = Pu[(size_t)col[e + 3] * 16 + h];
        uint_t w0[4] = {u0.x, u0.y, u0.z, u0.w};
        uint_t w1[4] = {u1.x, u1.y, u1.z, u1.w};
        uint_t w2[4] = {u2.x, u2.y, u2.z, u2.w};
        uint_t w3[4] = {u3.x, u3.y, u3.z, u3.w};
#pragma unroll
        for (int p = 0; p < 4; p++) {
          a[2 * p]     += (fmaxf(bf_lo(w0[p]) * s[2 * p] + b[2 * p], 0.f) +
                           fmaxf(bf_lo(w1[p]) * s[2 * p] + b[2 * p], 0.f)) +
                          (fmaxf(bf_lo(w2[p]) * s[2 * p] + b[2 * p], 0.f) +
                           fmaxf(bf_lo(w3[p]) * s[2 * p] + b[2 * p], 0.f));
          a[2 * p + 1] += (fmaxf(bf_hi(w0[p]) * s[2 * p + 1] + b[2 * p + 1], 0.f) +
                           fmaxf(bf_hi(w1[p]) * s[2 * p + 1] + b[2 * p + 1], 0.f)) +
                          (fmaxf(bf_hi(w2[p]) * s[2 * p + 1] + b[2 * p + 1], 0.f) +
                           fmaxf(bf_hi(w3[p]) * s[2 * p + 1] + b[2 * p + 1], 0.f));
        }
      }
      for (; e < end; e++) {
        uint4 u = Pu[(size_t)col[e] * 16 + h];
        uint_t ww[4] = {u.x, u.y, u.z, u.w};
#pragma unroll
        for (int p = 0; p < 4; p++) {
          a[2 * p]     += fmaxf(bf_lo(ww[p]) * s[2 * p] + b[2 * p], 0.f);
          a[2 * p + 1] += fmaxf(bf_hi(ww[p]) * s[2 * p + 1] + b[2 * p + 1], 0.f);
        }
      }
      float inv = invdeg[node];
      o.x = pack2(a[0] * inv, a[1] * inv);
      o.y = pack2(a[2] * inv, a[3] * inv);
      o.z = pack2(a[4] * inv, a[5] * inv);
      o.w = pack2(a[6] * inv, a[7] * inv);
    }
    *((uint4*)&aggu[r * 68 + h * 4]) = o;
  }
  __syncthreads();

  const int l = tid & 63;
  const int m = l & 15;
  const int quad = l >> 4;
  f32x4 acc[8];
#pragma unroll
  for (int ct = 0; ct < 8; ct++) acc[ct] = (f32x4){0.f, 0.f, 0.f, 0.f};

  for (int kk = 0; kk < 256; kk += 32) {
    __syncthreads();
    {
      const uint4* wp = (const uint4*)(WT + (kk >> 5) * 4096);
      uint4 v0 = wp[tid];
      uint4 v1 = wp[tid + 256];
      *((uint4*)&sB[(tid >> 2) * 40 + (tid & 3) * 8]) = v0;
      int t2 = tid + 256;
      *((uint4*)&sB[(t2 >> 2) * 40 + (t2 & 3) * 8]) = v1;
    }
    if (kk >= 128) {
      int r = tid >> 2, c = tid & 3;
      int row = row0 + r;
      uint4 v = make_uint4(0, 0, 0, 0);
      if (row < N_NODES) {
        int pcol = kk - 128 + c * 8;
        uint4 u = *(const uint4*)(Pin + (size_t)row * 128 + pcol);
        uint_t in[4] = {u.x, u.y, u.z, u.w};
        uint_t ov[4];
#pragma unroll
        for (int p = 0; p < 4; p++) {
          int cc = pcol + 2 * p;
          float f0 = fmaxf(bf_lo(in[p]) * ssc[cc] + ssc[128 + cc], 0.f);
          float f1 = fmaxf(bf_hi(in[p]) * ssc[cc + 1] + ssc[128 + cc + 1], 0.f);
          ov[p] = pack2(f0, f1);
        }
        v = make_uint4(ov[0], ov[1], ov[2], ov[3]);
      }
      *((uint4*)&sA[r * 40 + c * 8]) = v;
    }
    __syncthreads();
    bf16x8 a;
    if (kk < 128)
      a = *(const bf16x8*)((const ushort_t*)aggu + (w * 16 + m) * 136 + kk + quad * 8);
    else
      a = *(const bf16x8*)&sA[(w * 16 + m) * 40 + quad * 8];
#pragma unroll
    for (int ct = 0; ct < 8; ct++) {
      bf16x8 bb = *(const bf16x8*)&sB[(ct * 16 + m) * 40 + quad * 8];
      acc[ct] = __builtin_amdgcn_mfma_f32_16x16x32_bf16(a, bb, acc[ct], 0, 0, 0);
    }
  }

#pragma unroll
  for (int ct = 0; ct < 8; ct++) {
#pragma unroll
    for (int v = 0; v < 4; v++) {
      int row = row0 + w * 16 + quad * 4 + v;
      if (row < N_NODES) Pout[(size_t)row * 128 + ct * 16 + m] = f2bf(acc[ct][v]);
    }
  }

  float* red = (float*)sA;
  __syncthreads();
#pragma unroll
  for (int ct = 0; ct < 8; ct++) {
    float ss = 0.f, q = 0.f;
#pragma unroll
    for (int v = 0; v < 4; v++) {
      ss += acc[ct][v];
      q += acc[ct][v] * acc[ct][v];
    }
    float t;
    t = __shfl_xor(ss, 16); ss += t;
    t = __shfl_xor(ss, 32); ss += t;
    t = __shfl_xor(q, 16); q += t;
    t = __shfl_xor(q, 32); q += t;
    if (l < 16) {
      red[w * 256 + ct * 16 + l] = ss;
      red[w * 256 + 128 + ct * 16 + l] = q;
    }
  }
  __syncthreads();
  if (tid < 128) {
    float ss = 0.f, q = 0.f;
#pragma unroll
    for (int wv = 0; wv < 4; wv++) {
      ss += red[wv * 256 + tid];
      q += red[wv * 256 + 128 + tid];
    }
    atomicAdd(&stats_out[tid], ss);
    atomicAdd(&stats_out[128 + tid], q);
  }
}

// ================================================================ pool + readout
__global__ __launch_bounds__(128) void pool_readout_kernel(
    const ushort_t* __restrict__ P, const float* __restrict__ stats,
    const float* __restrict__ gamma, const float* __restrict__ beta,
    const int* __restrict__ batch, const float* __restrict__ rW1,
    const float* __restrict__ rb1, const float* __restrict__ rW2,
    const float* __restrict__ rb2, float* __restrict__ out) {
  int g = blockIdx.x;
  int t = threadIdx.x;
  int lo = 0, hi = N_NODES;
  while (lo < hi) { int mid = (lo + hi) >> 1; if (batch[mid] < g) lo = mid + 1; else hi = mid; }
  int gs = lo;
  hi = N_NODES;
  while (lo < hi) { int mid = (lo + hi) >> 1; if (batch[mid] < g + 1) lo = mid + 1; else hi = mid; }
  int ge = lo;
  const float invN = 1.0f / (float)N_NODES;
  float mean = stats[t] * invN;
  float var = stats[128 + t] * invN - mean * mean;
  float s = gamma[t] * rsqrtf(var + BN_EPS);
  float b = beta[t] - mean * s;
  float acc = 0.f;
  const ushort_t* pr = P + (size_t)gs * 128 + t;
  for (int r = gs; r < ge; r++, pr += 128)
    acc += fmaxf(__uint_as_float(((uint_t)*pr) << 16) * s + b, 0.f);
  __shared__ float pl[128];
  pl[t] = acc / fmaxf((float)(ge - gs), 1.f);
  __syncthreads();
  if (t < 64) {
    float h1 = rb1[t];
    for (int k = 0; k < 128; k++) h1 += pl[k] * rW1[k * 64 + t];
    h1 = fmaxf(h1, 0.f) * rW2[t];
#pragma unroll
    for (int off = 32; off > 0; off >>= 1) h1 += __shfl_down(h1, off);
    if (t == 0) out[g] = h1 + rb2[0];
  }
}

// ================================================================ launch
extern "C" void kernel_launch(void* const* d_in, const int* in_sizes, int n_in,
                              void* d_out, int out_size, void* d_ws, size_t ws_size,
                              hipStream_t stream) {
  const float* x     = (const float*)d_in[0];
  const int*   ei    = (const int*)d_in[1];
  const int*   src   = ei;
  const int*   dst   = ei + N_EDGES;
  const int*   batch = (const int*)d_in[2];
  const float* Wl0   = (const float*)d_in[3];
  const float* Wr0   = (const float*)d_in[4];
  const float* Wl    = (const float*)d_in[6];
  const float* Wr    = (const float*)d_in[7];
  const float* gamma = (const float*)d_in[9];
  const float* beta  = (const float*)d_in[10];
  const float* rW1   = (const float*)d_in[11];
  const float* rb1   = (const float*)d_in[12];
  const float* rW2   = (const float*)d_in[13];
  const float* rb2   = (const float*)d_in[14];
  float* out = (float*)d_out;

  char* ws = (char*)d_ws;
  size_t off = 0;
  auto alloc = [&](size_t bytes) -> void* {
    void* p = ws + off;
    off = (off + bytes + 255) & ~(size_t)255;
    return p;
  };
  uint_t*   xb    = (uint_t*)alloc((size_t)N_NODES * 20 * 4);
  ushort_t* Pa    = (ushort_t*)alloc((size_t)N_NODES * 128 * 2);
  ushort_t* Pb    = (ushort_t*)alloc((size_t)N_NODES * 128 * 2);
  ushort_t* WT0   = (ushort_t*)alloc((size_t)128 * 96 * 2);
  ushort_t* WT1   = (ushort_t*)alloc((size_t)128 * 256 * 2);
  ushort_t* WT2   = (ushort_t*)alloc((size_t)128 * 256 * 2);
  float* invdeg = (float*)alloc((size_t)N_NODES * 4);
  int*   degi   = (int*)alloc((size_t)N_NODES * 4);
  int*   rowptr = (int*)alloc((size_t)(N_NODES + 1) * 4);
  int*   cursor = (int*)alloc((size_t)N_NODES * 4);
  ushort_t* colidx = (ushort_t*)alloc((size_t)N_EDGES * 2);
  int*   partial= (int*)alloc((size_t)N_NODES * 4);
  int*   bsum   = (int*)alloc(256 * 4);
  float* stats  = (float*)alloc(768 * 4);  // 3 layers x {sum[128],sumsq[128]}

  const int NB_SCAN = (N_NODES + 255) / 256;  // 196
  const int gemm_blocks = (N_NODES + 63) / 64;
  const int PREP_TOTAL = WP0 + 2 * WP1 + N_NODES * 20;

  // ---- CSR build (once)
  hipMemsetAsync(degi, 0, (size_t)N_NODES * 4, stream);
  hist_kernel<<<1024, 256, 0, stream>>>(dst, degi);
  scan_block_kernel<<<NB_SCAN, 256, 0, stream>>>(degi, partial, bsum, invdeg);
  scan_add_fused_kernel<<<NB_SCAN + 1, 256, 0, stream>>>(partial, bsum, rowptr,
                                                         cursor, NB_SCAN);
  fill_sharded_kernel<<<2048, 256, 0, stream>>>(src, dst, cursor, colidx);

  // ---- weights + xb + stats zero (one launch)
  prep_all_kernel<<<(PREP_TOTAL + 255) / 256, 256, 0, stream>>>(
      Wl0, Wr0, Wl, Wr, x, WT0, WT1, WT2, xb, stats);

  // ---- layer 0 (fused gather + GEMM)
  gemm0_fused_kernel<<<gemm_blocks, 256, 0, stream>>>(xb, rowptr, colidx, invdeg,
                                                      WT0, Pa, stats);

  // ---- layer 1: Pa -> Pb
  gemm_fused_kernel<<<gemm_blocks, 256, 0, stream>>>(
      Pa, stats, gamma, beta, rowptr, colidx, invdeg, WT1, Pb, stats + 256);

  // ---- layer 2: Pb -> Pa
  gemm_fused_kernel<<<gemm_blocks, 256, 0, stream>>>(
      Pb, stats + 256, gamma + 128, beta + 128, rowptr, colidx, invdeg, WT2,
      Pa, stats + 512);

  // ---- fused global mean pool (final BN inline) + readout
  pool_readout_kernel<<<N_GRAPHS, 128, 0, stream>>>(
      Pa, stats + 512, gamma + 256, beta + 256, batch, rW1, rb1, rW2, rb2, out);
}